// Round 1
// baseline (3635.746 us; speedup 1.0000x reference)
//
#include <hip/hip_runtime.h>

#define NN 100000
#define EPS 1e-5f

// ---- workspace layout (in floats) ----
// agg1   [0, 3,200,000)            N*32
// cnt    [3,200,000, 3,300,000)    N
// agg2   [3,300,000, 9,700,000)    N*64
// stats1 [9,700,000, 9,700,256)    sum[128], sumsq[128]
// stats2 [9,700,256, 9,700,384)    sum[64], sumsq[64]
// coef1  [9,700,384, 9,700,640)    a[128], c[128]
// coef2  [9,700,640, 9,700,768)    a[64], c[64]
// z1     [9,700,768, 22,500,768)   N*128
// z2     aliases agg1 region: [0, 6,400,000)  (agg1/cnt/agg2 dead by then)
static const size_t OFF_AGG1   = 0;
static const size_t OFF_CNT    = 3200000;
static const size_t OFF_AGG2   = 3300000;
static const size_t OFF_STATS1 = 9700000;
static const size_t OFF_STATS2 = 9700256;
static const size_t OFF_COEF1  = 9700384;
static const size_t OFF_COEF2  = 9700640;
static const size_t OFF_Z1     = 9700768;
static const size_t OFF_Z2     = 0;
static const size_t ZERO_FLOATS = 9700768;  // zero everything up to z1

// ---- scatter: for each edge, gather K feats of x[src], atomic-add into agg[tgt] ----
template<int K>
__global__ __launch_bounds__(256) void scatter_mean(const float* __restrict__ x,
                                                    const int* __restrict__ ei,
                                                    int E,
                                                    float* __restrict__ agg,
                                                    float* __restrict__ cnt) {
  constexpr int TPE = K / 4;               // threads per edge, each does float4
  int g = blockIdx.x * 256 + threadIdx.x;
  if (g >= E * TPE) return;
  int e = g / TPE;
  int f = (g % TPE) * 4;
  int src = ei[e];
  int tgt = ei[E + e];
  if ((unsigned)src >= NN || (unsigned)tgt >= NN) return;  // safety guard
  float4 v = *(const float4*)(x + (size_t)src * K + f);
  float* a = agg + (size_t)tgt * K + f;
  atomicAdd(a + 0, v.x);
  atomicAdd(a + 1, v.y);
  atomicAdd(a + 2, v.z);
  atomicAdd(a + 3, v.w);
  if (cnt && f == 0) atomicAdd(cnt + tgt, 1.0f);
}

// ---- SAGE layer: out[i][j] = relu( (agg[i]/max(cnt,1)) . wl[j] + bl[j] + x[i] . wr[j] ) ----
template<int K>
__global__ __launch_bounds__(256) void sage_layer(const float* __restrict__ x,
                                                  const float* __restrict__ agg,
                                                  const float* __restrict__ cnt,
                                                  const float* __restrict__ wl,
                                                  const float* __restrict__ bl,
                                                  const float* __restrict__ wr,
                                                  float* __restrict__ out) {
  int t = blockIdx.x * 256 + threadIdx.x;
  int i = t >> 6;                           // node
  int j = t & 63;                           // output channel
  if (i >= NN) return;
  float inv = 1.0f / fmaxf(cnt[i], 1.0f);
  const float4* xr  = (const float4*)(x   + (size_t)i * K);
  const float4* ar  = (const float4*)(agg + (size_t)i * K);
  const float4* wlr = (const float4*)(wl  + (size_t)j * K);
  const float4* wrr = (const float4*)(wr  + (size_t)j * K);
  float acc = bl[j];
  #pragma unroll
  for (int k = 0; k < K / 4; ++k) {
    float4 m = ar[k], xv = xr[k], wa = wlr[k], wb = wrr[k];
    acc += (m.x * inv) * wa.x + (m.y * inv) * wa.y + (m.z * inv) * wa.z + (m.w * inv) * wa.w;
    acc += xv.x * wb.x + xv.y * wb.y + xv.z * wb.z + xv.w * wb.w;
  }
  out[(size_t)i * 64 + j] = fmaxf(acc, 0.0f);
}

// ---- dense: out[i][j] = in[i] . w[j] + b[j] ----
template<int KIN, int COUT>
__global__ __launch_bounds__(256) void fc_kernel(const float* __restrict__ in,
                                                 const float* __restrict__ w,
                                                 const float* __restrict__ b,
                                                 float* __restrict__ out) {
  int t = blockIdx.x * 256 + threadIdx.x;
  int i = t / COUT;
  int j = t % COUT;
  if (i >= NN) return;
  const float4* r  = (const float4*)(in + (size_t)i * KIN);
  const float4* wr = (const float4*)(w  + (size_t)j * KIN);
  float acc = b[j];
  #pragma unroll
  for (int k = 0; k < KIN / 4; ++k) {
    float4 a = r[k], wv = wr[k];
    acc += a.x * wv.x + a.y * wv.y + a.z * wv.z + a.w * wv.w;
  }
  out[(size_t)i * COUT + j] = acc;
}

// ---- column sums / sumsq over [NN, C] row-major; stats[0..C)=sum, stats[C..2C)=sumsq ----
template<int C>
__global__ __launch_bounds__(256) void colstats(const float* __restrict__ z,
                                                float* __restrict__ stats) {
  const long long total = (long long)NN * C;
  int t = threadIdx.x;
  long long idx = (long long)blockIdx.x * 256 + t;
  long long stride = (long long)gridDim.x * 256;
  float s = 0.f, q = 0.f;
  for (; idx < total; idx += stride) {
    float v = z[idx];
    s += v;
    q += v * v;
  }
  __shared__ float ls[256], lq[256];
  ls[t] = s; lq[t] = q;
  __syncthreads();
  if (t < C) {
    float ss = 0.f, qq = 0.f;
    #pragma unroll
    for (int r = 0; r < 256 / C; ++r) { ss += ls[t + r * C]; qq += lq[t + r * C]; }
    atomicAdd(&stats[t], ss);
    atomicAdd(&stats[C + t], qq);
  }
}

// ---- turn stats into affine coefs: y = v*a + c ----
__global__ void bncoef(const float* __restrict__ stats, const float* __restrict__ g,
                       const float* __restrict__ b, float* __restrict__ coef, int C) {
  int j = threadIdx.x;
  if (j >= C) return;
  float mu  = stats[j] * (1.0f / NN);
  float var = stats[C + j] * (1.0f / NN) - mu * mu;
  float a = g[j] * rsqrtf(var + EPS);
  coef[j] = a;
  coef[C + j] = b[j] - mu * a;
}

// ---- in-place z = relu(z*a + c), C=128 ----
__global__ __launch_bounds__(256) void bnrelu128(float* __restrict__ z,
                                                 const float* __restrict__ coef) {
  long long t = (long long)blockIdx.x * 256 + threadIdx.x;   // float4 index
  const long long n4 = (long long)NN * 128 / 4;
  if (t >= n4) return;
  int col = (int)(t & 31) * 4;
  float4 v = ((const float4*)z)[t];
  float4 a = *(const float4*)(coef + col);
  float4 c = *(const float4*)(coef + 128 + col);
  v.x = fmaxf(v.x * a.x + c.x, 0.f);
  v.y = fmaxf(v.y * a.y + c.y, 0.f);
  v.z = fmaxf(v.z * a.z + c.z, 0.f);
  v.w = fmaxf(v.w * a.w + c.w, 0.f);
  ((float4*)z)[t] = v;
}

// ---- final: out[i] = sum_j relu(z2[i][j]*a+c) * fc3w[j] + fc3b ----
__global__ __launch_bounds__(256) void final_k(const float* __restrict__ z2,
                                               const float* __restrict__ coef,
                                               const float* __restrict__ fc3w,
                                               const float* __restrict__ fc3b,
                                               float* __restrict__ out) {
  int t = blockIdx.x * 256 + threadIdx.x;
  int i = t >> 6;
  int j = t & 63;                 // == lane id (blockDim multiple of 64)
  if (i >= NN) return;
  float v = z2[(size_t)i * 64 + j];
  float p = fmaxf(v * coef[j] + coef[64 + j], 0.f) * fc3w[j];
  #pragma unroll
  for (int o = 32; o > 0; o >>= 1) p += __shfl_xor(p, o, 64);
  if (j == 0) out[i] = p + fc3b[0];
}

extern "C" void kernel_launch(void* const* d_in, const int* in_sizes, int n_in,
                              void* d_out, int out_size, void* d_ws, size_t ws_size,
                              hipStream_t stream) {
  const float* x     = (const float*)d_in[0];
  const int*   ei    = (const int*)d_in[1];
  const float* w_l1  = (const float*)d_in[2];
  const float* b_l1  = (const float*)d_in[3];
  const float* w_r1  = (const float*)d_in[4];
  const float* w_l2  = (const float*)d_in[5];
  const float* b_l2  = (const float*)d_in[6];
  const float* w_r2  = (const float*)d_in[7];
  const float* fc1_w = (const float*)d_in[8];
  const float* fc1_b = (const float*)d_in[9];
  const float* bn1_g = (const float*)d_in[10];
  const float* bn1_b = (const float*)d_in[11];
  const float* fc2_w = (const float*)d_in[12];
  const float* fc2_b = (const float*)d_in[13];
  const float* bn2_g = (const float*)d_in[14];
  const float* bn2_b = (const float*)d_in[15];
  const float* fc3_w = (const float*)d_in[16];
  const float* fc3_b = (const float*)d_in[17];

  const int E = in_sizes[1] / 2;

  float* ws     = (float*)d_ws;
  float* agg1   = ws + OFF_AGG1;
  float* cnt    = ws + OFF_CNT;
  float* agg2   = ws + OFF_AGG2;
  float* stats1 = ws + OFF_STATS1;
  float* stats2 = ws + OFF_STATS2;
  float* coef1  = ws + OFF_COEF1;
  float* coef2  = ws + OFF_COEF2;
  float* z1     = ws + OFF_Z1;
  float* z2     = ws + OFF_Z2;

  float* outv = (float*)d_out;             // [NN]
  float* h1   = outv + NN;                 // [NN,64]
  float* h2   = h1 + (size_t)NN * 64;      // [NN,64]

  // zero accumulators (agg1, cnt, agg2, stats, coefs)
  hipMemsetAsync(d_ws, 0, ZERO_FLOATS * sizeof(float), stream);

  // layer 1
  scatter_mean<32><<<(E * 8 + 255) / 256, 256, 0, stream>>>(x, ei, E, agg1, cnt);
  sage_layer<32><<<(NN * 64 + 255) / 256, 256, 0, stream>>>(x, agg1, cnt, w_l1, b_l1, w_r1, h1);

  // layer 2
  scatter_mean<64><<<(E * 16 + 255) / 256, 256, 0, stream>>>(h1, ei, E, agg2, nullptr);
  sage_layer<64><<<(NN * 64 + 255) / 256, 256, 0, stream>>>(h1, agg2, cnt, w_l2, b_l2, w_r2, h2);

  // fc1 + bn1 + relu
  fc_kernel<64, 128><<<(NN * 128 + 255) / 256, 256, 0, stream>>>(h2, fc1_w, fc1_b, z1);
  colstats<128><<<512, 256, 0, stream>>>(z1, stats1);
  bncoef<<<1, 128, 0, stream>>>(stats1, bn1_g, bn1_b, coef1, 128);
  bnrelu128<<<(NN * 128 / 4 + 255) / 256, 256, 0, stream>>>(z1, coef1);

  // fc2 + bn2 + relu + fc3 (bn2+relu+fc3 fused into final)
  fc_kernel<128, 64><<<(NN * 64 + 255) / 256, 256, 0, stream>>>(z1, fc2_w, fc2_b, z2);
  colstats<64><<<512, 256, 0, stream>>>(z2, stats2);
  bncoef<<<1, 64, 0, stream>>>(stats2, bn2_g, bn2_b, coef2, 64);
  final_k<<<(NN * 64 + 255) / 256, 256, 0, stream>>>(z2, coef2, fc3_w, fc3_b, outv);
}

// Round 2
// 2155.592 us; speedup vs baseline: 1.6867x; 1.6867x over previous
//
#include <hip/hip_runtime.h>

#define NN 100000
#define EPS 1e-5f

// ---- workspace layout (4-byte units) ----
// rowptr  [0, 100,004)                 N+1 ints
// adj     [100,004, 1,700,008)         E ints (sorted-by-target src list)
// cursor  [1,700,008, 1,800,008)       N ints
// agg1    [1,800,008, 5,000,008)       N*32 f32 (mean, layer1)
// agg2    [5,000,008, 11,400,008)      N*64 f32 (mean, layer2)
// z1      [0, 12,800,000)              N*128 f32 (aliases all CSR+agg: dead by fc1)
// z2      [12,800,000, 19,200,000)     N*64 f32
// deg     [19,200,000, 19,300,000)     N ints        } zeroed every call
// stats1  [19,300,000, 19,300,256)                   }
// stats2  [19,300,256, 19,300,384)                   }
// coef1   [19,300,384, 19,300,640)
// coef2   [19,300,640, 19,300,768)
static const size_t OFF_ROWPTR = 0;
static const size_t OFF_ADJ    = 100004;
static const size_t OFF_CURSOR = 1700008;
static const size_t OFF_AGG1   = 1800008;
static const size_t OFF_AGG2   = 5000008;
static const size_t OFF_Z1     = 0;
static const size_t OFF_Z2     = 12800000;
static const size_t OFF_DEG    = 19200000;
static const size_t OFF_STATS1 = 19300000;
static const size_t OFF_STATS2 = 19300256;
static const size_t OFF_COEF1  = 19300384;
static const size_t OFF_COEF2  = 19300640;
static const size_t ZERO_START = 19200000;         // deg + stats1 + stats2
static const size_t ZERO_FLOATS = 100384;

// ---- CSR build: histogram of targets ----
__global__ __launch_bounds__(256) void hist_k(const int* __restrict__ ei, int E,
                                              int* __restrict__ deg) {
  int e = blockIdx.x * 256 + threadIdx.x;
  if (e >= E) return;
  int t = ei[E + e];
  if ((unsigned)t < NN) atomicAdd(&deg[t], 1);
}

// ---- CSR build: exclusive scan over deg (single block, 1024 threads) ----
__global__ __launch_bounds__(1024) void scan_k(const int* __restrict__ deg,
                                               int* __restrict__ rowptr,
                                               int* __restrict__ cursor) {
  __shared__ int part[1024];
  int t = threadIdx.x;
  const int CH = (NN + 1023) / 1024;   // 98
  int lo = t * CH, hi = min(lo + CH, NN);
  int s = 0;
  for (int i = lo; i < hi; ++i) s += deg[i];
  part[t] = s;
  __syncthreads();
  for (int o = 1; o < 1024; o <<= 1) {
    int v = (t >= o) ? part[t - o] : 0;
    __syncthreads();
    part[t] += v;
    __syncthreads();
  }
  int run = (t > 0) ? part[t - 1] : 0;
  for (int i = lo; i < hi; ++i) {
    rowptr[i] = run;
    cursor[i] = run;
    run += deg[i];
  }
  if (t == 1023) rowptr[NN] = part[1023];
}

// ---- CSR build: fill adjacency (src indices grouped by target) ----
__global__ __launch_bounds__(256) void fill_k(const int* __restrict__ ei, int E,
                                              int* __restrict__ cursor,
                                              int* __restrict__ adj) {
  int e = blockIdx.x * 256 + threadIdx.x;
  if (e >= E) return;
  int s = ei[e], t = ei[E + e];
  if ((unsigned)t >= NN || (unsigned)s >= NN) return;
  int pos = atomicAdd(&cursor[t], 1);
  adj[pos] = s;
}

// ---- gather-side mean aggregation: one K-lane group per node ----
template<int K>
__global__ __launch_bounds__(256) void aggregate_k(const float* __restrict__ x,
                                                   const int* __restrict__ rowptr,
                                                   const int* __restrict__ adj,
                                                   float* __restrict__ agg) {
  constexpr int NPB = 256 / K;
  int lane = threadIdx.x & (K - 1);
  int node = blockIdx.x * NPB + (threadIdx.x / K);
  if (node >= NN) return;
  int s0 = rowptr[node], s1 = rowptr[node + 1];
  float acc0 = 0.f, acc1 = 0.f;
  int e = s0;
  for (; e + 1 < s1; e += 2) {                 // 2 independent chains
    int sa = adj[e], sb = adj[e + 1];
    acc0 += x[(size_t)sa * K + lane];
    acc1 += x[(size_t)sb * K + lane];
  }
  if (e < s1) acc0 += x[(size_t)adj[e] * K + lane];
  float inv = 1.0f / fmaxf((float)(s1 - s0), 1.0f);
  agg[(size_t)node * K + lane] = (acc0 + acc1) * inv;
}

// ---- SAGE dense: out[i][j] = relu( mean[i].wl[j] + bl[j] + x[i].wr[j] ) ----
template<int K>
__global__ __launch_bounds__(256) void sage_layer(const float* __restrict__ x,
                                                  const float* __restrict__ agg,
                                                  const float* __restrict__ wl,
                                                  const float* __restrict__ bl,
                                                  const float* __restrict__ wr,
                                                  float* __restrict__ out) {
  int t = blockIdx.x * 256 + threadIdx.x;
  int i = t >> 6;                           // node
  int j = t & 63;                           // output channel
  if (i >= NN) return;
  const float4* xr  = (const float4*)(x   + (size_t)i * K);
  const float4* ar  = (const float4*)(agg + (size_t)i * K);
  const float4* wlr = (const float4*)(wl  + (size_t)j * K);
  const float4* wrr = (const float4*)(wr  + (size_t)j * K);
  float acc = bl[j];
  #pragma unroll
  for (int k = 0; k < K / 4; ++k) {
    float4 m = ar[k], xv = xr[k], wa = wlr[k], wb = wrr[k];
    acc += m.x * wa.x + m.y * wa.y + m.z * wa.z + m.w * wa.w;
    acc += xv.x * wb.x + xv.y * wb.y + xv.z * wb.z + xv.w * wb.w;
  }
  out[(size_t)i * 64 + j] = fmaxf(acc, 0.0f);
}

// ---- dense: out[i][j] = in[i] . w[j] + b[j] ----
template<int KIN, int COUT>
__global__ __launch_bounds__(256) void fc_kernel(const float* __restrict__ in,
                                                 const float* __restrict__ w,
                                                 const float* __restrict__ b,
                                                 float* __restrict__ out) {
  int t = blockIdx.x * 256 + threadIdx.x;
  int i = t / COUT;
  int j = t % COUT;
  if (i >= NN) return;
  const float4* r  = (const float4*)(in + (size_t)i * KIN);
  const float4* wr = (const float4*)(w  + (size_t)j * KIN);
  float acc = b[j];
  #pragma unroll
  for (int k = 0; k < KIN / 4; ++k) {
    float4 a = r[k], wv = wr[k];
    acc += a.x * wv.x + a.y * wv.y + a.z * wv.z + a.w * wv.w;
  }
  out[(size_t)i * COUT + j] = acc;
}

// ---- column sums / sumsq over [NN, C]; stats[0..C)=sum, stats[C..2C)=sumsq ----
template<int C>
__global__ __launch_bounds__(256) void colstats(const float* __restrict__ z,
                                                float* __restrict__ stats) {
  const long long total = (long long)NN * C;
  int t = threadIdx.x;
  long long idx = (long long)blockIdx.x * 256 + t;
  long long stride = (long long)gridDim.x * 256;
  float s = 0.f, q = 0.f;
  for (; idx < total; idx += stride) {
    float v = z[idx];
    s += v;
    q += v * v;
  }
  __shared__ float ls[256], lq[256];
  ls[t] = s; lq[t] = q;
  __syncthreads();
  if (t < C) {
    float ss = 0.f, qq = 0.f;
    #pragma unroll
    for (int r = 0; r < 256 / C; ++r) { ss += ls[t + r * C]; qq += lq[t + r * C]; }
    atomicAdd(&stats[t], ss);
    atomicAdd(&stats[C + t], qq);
  }
}

// ---- stats -> affine coefs: y = v*a + c ----
__global__ void bncoef(const float* __restrict__ stats, const float* __restrict__ g,
                       const float* __restrict__ b, float* __restrict__ coef, int C) {
  int j = threadIdx.x;
  if (j >= C) return;
  float mu  = stats[j] * (1.0f / NN);
  float var = stats[C + j] * (1.0f / NN) - mu * mu;
  float a = g[j] * rsqrtf(var + EPS);
  coef[j] = a;
  coef[C + j] = b[j] - mu * a;
}

// ---- in-place z = relu(z*a + c), C=128 ----
__global__ __launch_bounds__(256) void bnrelu128(float* __restrict__ z,
                                                 const float* __restrict__ coef) {
  long long t = (long long)blockIdx.x * 256 + threadIdx.x;   // float4 index
  const long long n4 = (long long)NN * 128 / 4;
  if (t >= n4) return;
  int col = (int)(t & 31) * 4;
  float4 v = ((const float4*)z)[t];
  float4 a = *(const float4*)(coef + col);
  float4 c = *(const float4*)(coef + 128 + col);
  v.x = fmaxf(v.x * a.x + c.x, 0.f);
  v.y = fmaxf(v.y * a.y + c.y, 0.f);
  v.z = fmaxf(v.z * a.z + c.z, 0.f);
  v.w = fmaxf(v.w * a.w + c.w, 0.f);
  ((float4*)z)[t] = v;
}

// ---- final: out[i] = sum_j relu(z2[i][j]*a+c) * fc3w[j] + fc3b ----
__global__ __launch_bounds__(256) void final_k(const float* __restrict__ z2,
                                               const float* __restrict__ coef,
                                               const float* __restrict__ fc3w,
                                               const float* __restrict__ fc3b,
                                               float* __restrict__ out) {
  int t = blockIdx.x * 256 + threadIdx.x;
  int i = t >> 6;
  int j = t & 63;                 // lane id
  if (i >= NN) return;
  float v = z2[(size_t)i * 64 + j];
  float p = fmaxf(v * coef[j] + coef[64 + j], 0.f) * fc3w[j];
  #pragma unroll
  for (int o = 32; o > 0; o >>= 1) p += __shfl_xor(p, o, 64);
  if (j == 0) out[i] = p + fc3b[0];
}

extern "C" void kernel_launch(void* const* d_in, const int* in_sizes, int n_in,
                              void* d_out, int out_size, void* d_ws, size_t ws_size,
                              hipStream_t stream) {
  const float* x     = (const float*)d_in[0];
  const int*   ei    = (const int*)d_in[1];
  const float* w_l1  = (const float*)d_in[2];
  const float* b_l1  = (const float*)d_in[3];
  const float* w_r1  = (const float*)d_in[4];
  const float* w_l2  = (const float*)d_in[5];
  const float* b_l2  = (const float*)d_in[6];
  const float* w_r2  = (const float*)d_in[7];
  const float* fc1_w = (const float*)d_in[8];
  const float* fc1_b = (const float*)d_in[9];
  const float* bn1_g = (const float*)d_in[10];
  const float* bn1_b = (const float*)d_in[11];
  const float* fc2_w = (const float*)d_in[12];
  const float* fc2_b = (const float*)d_in[13];
  const float* bn2_g = (const float*)d_in[14];
  const float* bn2_b = (const float*)d_in[15];
  const float* fc3_w = (const float*)d_in[16];
  const float* fc3_b = (const float*)d_in[17];

  const int E = in_sizes[1] / 2;

  float* ws     = (float*)d_ws;
  int*   rowptr = (int*)(ws + OFF_ROWPTR);
  int*   adj    = (int*)(ws + OFF_ADJ);
  int*   cursor = (int*)(ws + OFF_CURSOR);
  float* agg1   = ws + OFF_AGG1;
  float* agg2   = ws + OFF_AGG2;
  float* z1     = ws + OFF_Z1;
  float* z2     = ws + OFF_Z2;
  int*   deg    = (int*)(ws + OFF_DEG);
  float* stats1 = ws + OFF_STATS1;
  float* stats2 = ws + OFF_STATS2;
  float* coef1  = ws + OFF_COEF1;
  float* coef2  = ws + OFF_COEF2;

  float* outv = (float*)d_out;             // [NN]
  float* h1   = outv + NN;                 // [NN,64]
  float* h2   = h1 + (size_t)NN * 64;      // [NN,64]

  // zero deg + stats
  hipMemsetAsync(ws + ZERO_START, 0, ZERO_FLOATS * sizeof(float), stream);

  // CSR build (shared by both layers)
  hist_k<<<(E + 255) / 256, 256, 0, stream>>>(ei, E, deg);
  scan_k<<<1, 1024, 0, stream>>>(deg, rowptr, cursor);
  fill_k<<<(E + 255) / 256, 256, 0, stream>>>(ei, E, cursor, adj);

  // layer 1
  aggregate_k<32><<<(NN * 32 + 255) / 256, 256, 0, stream>>>(x, rowptr, adj, agg1);
  sage_layer<32><<<(NN * 64 + 255) / 256, 256, 0, stream>>>(x, agg1, w_l1, b_l1, w_r1, h1);

  // layer 2
  aggregate_k<64><<<(NN * 64 + 255) / 256, 256, 0, stream>>>(h1, rowptr, adj, agg2);
  sage_layer<64><<<(NN * 64 + 255) / 256, 256, 0, stream>>>(h1, agg2, w_l2, b_l2, w_r2, h2);

  // fc1 + bn1 + relu
  fc_kernel<64, 128><<<(NN * 128 + 255) / 256, 256, 0, stream>>>(h2, fc1_w, fc1_b, z1);
  colstats<128><<<512, 256, 0, stream>>>(z1, stats1);
  bncoef<<<1, 128, 0, stream>>>(stats1, bn1_g, bn1_b, coef1, 128);
  bnrelu128<<<(NN * 128 / 4 + 255) / 256, 256, 0, stream>>>(z1, coef1);

  // fc2 + (bn2+relu+fc3 fused into final)
  fc_kernel<128, 64><<<(NN * 64 + 255) / 256, 256, 0, stream>>>(z1, fc2_w, fc2_b, z2);
  colstats<64><<<512, 256, 0, stream>>>(z2, stats2);
  bncoef<<<1, 64, 0, stream>>>(stats2, bn2_g, bn2_b, coef2, 64);
  final_k<<<(NN * 64 + 255) / 256, 256, 0, stream>>>(z2, coef2, fc3_w, fc3_b, outv);
}

// Round 3
// 970.021 us; speedup vs baseline: 3.7481x; 2.2222x over previous
//
#include <hip/hip_runtime.h>

#define NN 100000
#define EPS 1e-5f

// ---- workspace layout (4-byte units) ----
static const size_t OFF_ROWPTR = 0;
static const size_t OFF_ADJ    = 100004;
static const size_t OFF_CURSOR = 1700008;
static const size_t OFF_AGG1   = 1800008;
static const size_t OFF_AGG2   = 5000008;
static const size_t OFF_Z1     = 0;          // aliases CSR+agg (dead by fc1)
static const size_t OFF_Z2     = 12800000;
static const size_t OFF_DEG    = 19200000;
static const size_t OFF_STATS1 = 19300000;
static const size_t OFF_STATS2 = 19300256;
static const size_t OFF_COEF1  = 19300384;
static const size_t OFF_COEF2  = 19300640;
static const size_t ZERO_START = 19200000;   // deg + stats1 + stats2
static const size_t ZERO_FLOATS = 100384;

// ---- CSR build: histogram of targets ----
__global__ __launch_bounds__(256) void hist_k(const int* __restrict__ ei, int E,
                                              int* __restrict__ deg) {
  int e = blockIdx.x * 256 + threadIdx.x;
  if (e >= E) return;
  int t = ei[E + e];
  if ((unsigned)t < NN) atomicAdd(&deg[t], 1);
}

// ---- CSR build: exclusive scan over deg (single block) ----
__global__ __launch_bounds__(1024) void scan_k(const int* __restrict__ deg,
                                               int* __restrict__ rowptr,
                                               int* __restrict__ cursor) {
  __shared__ int part[1024];
  int t = threadIdx.x;
  const int CH = (NN + 1023) / 1024;
  int lo = t * CH, hi = min(lo + CH, NN);
  int s = 0;
  for (int i = lo; i < hi; ++i) s += deg[i];
  part[t] = s;
  __syncthreads();
  for (int o = 1; o < 1024; o <<= 1) {
    int v = (t >= o) ? part[t - o] : 0;
    __syncthreads();
    part[t] += v;
    __syncthreads();
  }
  int run = (t > 0) ? part[t - 1] : 0;
  for (int i = lo; i < hi; ++i) {
    rowptr[i] = run;
    cursor[i] = run;
    run += deg[i];
  }
  if (t == 1023) rowptr[NN] = part[1023];
}

// ---- CSR build: fill adjacency ----
__global__ __launch_bounds__(256) void fill_k(const int* __restrict__ ei, int E,
                                              int* __restrict__ cursor,
                                              int* __restrict__ adj) {
  int e = blockIdx.x * 256 + threadIdx.x;
  if (e >= E) return;
  int s = ei[e], t = ei[E + e];
  if ((unsigned)t >= NN || (unsigned)s >= NN) return;
  int pos = atomicAdd(&cursor[t], 1);
  adj[pos] = s;
}

// ---- gather-side mean aggregation: K-lane group per node ----
template<int K>
__global__ __launch_bounds__(256) void aggregate_k(const float* __restrict__ x,
                                                   const int* __restrict__ rowptr,
                                                   const int* __restrict__ adj,
                                                   float* __restrict__ agg) {
  constexpr int NPB = 256 / K;
  int lane = threadIdx.x & (K - 1);
  int node = blockIdx.x * NPB + (threadIdx.x / K);
  if (node >= NN) return;
  int s0 = rowptr[node], s1 = rowptr[node + 1];
  float acc0 = 0.f, acc1 = 0.f;
  int e = s0;
  for (; e + 1 < s1; e += 2) {
    int sa = adj[e], sb = adj[e + 1];
    acc0 += x[(size_t)sa * K + lane];
    acc1 += x[(size_t)sb * K + lane];
  }
  if (e < s1) acc0 += x[(size_t)adj[e] * K + lane];
  float inv = 1.0f / fmaxf((float)(s1 - s0), 1.0f);
  agg[(size_t)node * K + lane] = (acc0 + acc1) * inv;
}

// ---- dense layer, one thread per node, wave-uniform weight reads ----
// out[i][j] = act( bias[j] + rowA.wA[j] (+ rowB.wB[j]) ), rowA optionally
// pre-transformed by relu(v*a+c) (fused BN from previous layer).
template<int K, int C, bool SAGE, bool BNIN, bool RELU>
__global__ __launch_bounds__(256) void dense_k(const float* __restrict__ inA,
                                               const float* __restrict__ inB,
                                               const float* __restrict__ wA,
                                               const float* __restrict__ wB,
                                               const float* __restrict__ bias,
                                               const float* __restrict__ coef,
                                               float* __restrict__ out) {
  int node = blockIdx.x * 256 + threadIdx.x;
  if (node >= NN) return;
  float rA[K];
  float rB[SAGE ? K : 4];
  const float4* pa = (const float4*)(inA + (size_t)node * K);
  #pragma unroll
  for (int k = 0; k < K / 4; ++k) {
    float4 v = pa[k];
    rA[4 * k] = v.x; rA[4 * k + 1] = v.y; rA[4 * k + 2] = v.z; rA[4 * k + 3] = v.w;
  }
  if (BNIN) {
    #pragma unroll
    for (int k = 0; k < K; ++k) rA[k] = fmaxf(rA[k] * coef[k] + coef[K + k], 0.f);
  }
  if (SAGE) {
    const float4* pb = (const float4*)(inB + (size_t)node * K);
    #pragma unroll
    for (int k = 0; k < K / 4; ++k) {
      float4 v = pb[k];
      rB[4 * k] = v.x; rB[4 * k + 1] = v.y; rB[4 * k + 2] = v.z; rB[4 * k + 3] = v.w;
    }
  }
  #pragma unroll 1
  for (int jb = 0; jb < C; jb += 4) {
    float acc[4];
    #pragma unroll
    for (int u = 0; u < 4; ++u) acc[u] = bias[jb + u];
    #pragma unroll
    for (int k = 0; k < K; k += 4) {
      #pragma unroll
      for (int u = 0; u < 4; ++u) {
        float4 w4 = *(const float4*)(wA + (size_t)(jb + u) * K + k);
        acc[u] += rA[k] * w4.x + rA[k + 1] * w4.y + rA[k + 2] * w4.z + rA[k + 3] * w4.w;
      }
    }
    if (SAGE) {
      #pragma unroll
      for (int k = 0; k < K; k += 4) {
        #pragma unroll
        for (int u = 0; u < 4; ++u) {
          float4 w4 = *(const float4*)(wB + (size_t)(jb + u) * K + k);
          acc[u] += rB[k] * w4.x + rB[k + 1] * w4.y + rB[k + 2] * w4.z + rB[k + 3] * w4.w;
        }
      }
    }
    float4 o;
    o.x = RELU ? fmaxf(acc[0], 0.f) : acc[0];
    o.y = RELU ? fmaxf(acc[1], 0.f) : acc[1];
    o.z = RELU ? fmaxf(acc[2], 0.f) : acc[2];
    o.w = RELU ? fmaxf(acc[3], 0.f) : acc[3];
    *(float4*)(out + (size_t)node * C + jb) = o;
  }
}

// ---- column sums / sumsq over [NN, C]; stats[0..C)=sum, stats[C..2C)=sumsq ----
template<int C>
__global__ __launch_bounds__(256) void colstats(const float* __restrict__ z,
                                                float* __restrict__ stats) {
  const long long total = (long long)NN * C;
  int t = threadIdx.x;
  long long idx = (long long)blockIdx.x * 256 + t;
  long long stride = (long long)gridDim.x * 256;
  float s = 0.f, q = 0.f;
  for (; idx < total; idx += stride) {
    float v = z[idx];
    s += v;
    q += v * v;
  }
  __shared__ float ls[256], lq[256];
  ls[t] = s; lq[t] = q;
  __syncthreads();
  if (t < C) {
    float ss = 0.f, qq = 0.f;
    #pragma unroll
    for (int r = 0; r < 256 / C; ++r) { ss += ls[t + r * C]; qq += lq[t + r * C]; }
    atomicAdd(&stats[t], ss);
    atomicAdd(&stats[C + t], qq);
  }
}

// ---- stats -> affine coefs: y = v*a + c ----
__global__ void bncoef(const float* __restrict__ stats, const float* __restrict__ g,
                       const float* __restrict__ b, float* __restrict__ coef, int C) {
  int j = threadIdx.x;
  if (j >= C) return;
  float mu  = stats[j] * (1.0f / NN);
  float var = stats[C + j] * (1.0f / NN) - mu * mu;
  float a = g[j] * rsqrtf(var + EPS);
  coef[j] = a;
  coef[C + j] = b[j] - mu * a;
}

// ---- final: out[i] = sum_j relu(z2[i][j]*a+c) * fc3w[j] + fc3b ----
__global__ __launch_bounds__(256) void final_k(const float* __restrict__ z2,
                                               const float* __restrict__ coef,
                                               const float* __restrict__ fc3w,
                                               const float* __restrict__ fc3b,
                                               float* __restrict__ out) {
  int t = blockIdx.x * 256 + threadIdx.x;
  int i = t >> 6;
  int j = t & 63;
  if (i >= NN) return;
  float v = z2[(size_t)i * 64 + j];
  float p = fmaxf(v * coef[j] + coef[64 + j], 0.f) * fc3w[j];
  #pragma unroll
  for (int o = 32; o > 0; o >>= 1) p += __shfl_xor(p, o, 64);
  if (j == 0) out[i] = p + fc3b[0];
}

extern "C" void kernel_launch(void* const* d_in, const int* in_sizes, int n_in,
                              void* d_out, int out_size, void* d_ws, size_t ws_size,
                              hipStream_t stream) {
  const float* x     = (const float*)d_in[0];
  const int*   ei    = (const int*)d_in[1];
  const float* w_l1  = (const float*)d_in[2];
  const float* b_l1  = (const float*)d_in[3];
  const float* w_r1  = (const float*)d_in[4];
  const float* w_l2  = (const float*)d_in[5];
  const float* b_l2  = (const float*)d_in[6];
  const float* w_r2  = (const float*)d_in[7];
  const float* fc1_w = (const float*)d_in[8];
  const float* fc1_b = (const float*)d_in[9];
  const float* bn1_g = (const float*)d_in[10];
  const float* bn1_b = (const float*)d_in[11];
  const float* fc2_w = (const float*)d_in[12];
  const float* fc2_b = (const float*)d_in[13];
  const float* bn2_g = (const float*)d_in[14];
  const float* bn2_b = (const float*)d_in[15];
  const float* fc3_w = (const float*)d_in[16];
  const float* fc3_b = (const float*)d_in[17];

  const int E = in_sizes[1] / 2;

  float* ws     = (float*)d_ws;
  int*   rowptr = (int*)(ws + OFF_ROWPTR);
  int*   adj    = (int*)(ws + OFF_ADJ);
  int*   cursor = (int*)(ws + OFF_CURSOR);
  float* agg1   = ws + OFF_AGG1;
  float* agg2   = ws + OFF_AGG2;
  float* z1     = ws + OFF_Z1;
  float* z2     = ws + OFF_Z2;
  int*   deg    = (int*)(ws + OFF_DEG);
  float* stats1 = ws + OFF_STATS1;
  float* stats2 = ws + OFF_STATS2;
  float* coef1  = ws + OFF_COEF1;
  float* coef2  = ws + OFF_COEF2;

  float* outv = (float*)d_out;             // [NN]
  float* h1   = outv + NN;                 // [NN,64]
  float* h2   = h1 + (size_t)NN * 64;      // [NN,64]

  hipMemsetAsync(ws + ZERO_START, 0, ZERO_FLOATS * sizeof(float), stream);

  // CSR build (shared by both layers)
  hist_k<<<(E + 255) / 256, 256, 0, stream>>>(ei, E, deg);
  scan_k<<<1, 1024, 0, stream>>>(deg, rowptr, cursor);
  fill_k<<<(E + 255) / 256, 256, 0, stream>>>(ei, E, cursor, adj);

  const int NB = (NN + 255) / 256;

  // layer 1
  aggregate_k<32><<<(NN * 32 + 255) / 256, 256, 0, stream>>>(x, rowptr, adj, agg1);
  dense_k<32, 64, true, false, true><<<NB, 256, 0, stream>>>(agg1, x, w_l1, w_r1, b_l1, nullptr, h1);

  // layer 2
  aggregate_k<64><<<(NN * 64 + 255) / 256, 256, 0, stream>>>(h1, rowptr, adj, agg2);
  dense_k<64, 64, true, false, true><<<NB, 256, 0, stream>>>(agg2, h1, w_l2, w_r2, b_l2, nullptr, h2);

  // fc1 -> z1 (raw, pre-BN)
  dense_k<64, 128, false, false, false><<<NB, 256, 0, stream>>>(h2, nullptr, fc1_w, nullptr, fc1_b, nullptr, z1);
  colstats<128><<<512, 256, 0, stream>>>(z1, stats1);
  bncoef<<<1, 128, 0, stream>>>(stats1, bn1_g, bn1_b, coef1, 128);

  // fc2 with fused bn1+relu on input -> z2 (raw, pre-BN)
  dense_k<128, 64, false, true, false><<<NB, 256, 0, stream>>>(z1, nullptr, fc2_w, nullptr, fc2_b, coef1, z2);
  colstats<64><<<512, 256, 0, stream>>>(z2, stats2);
  bncoef<<<1, 64, 0, stream>>>(stats2, bn2_g, bn2_b, coef2, 64);

  // bn2 + relu + fc3 fused
  final_k<<<(NN * 64 + 255) / 256, 256, 0, stream>>>(z2, coef2, fc3_w, fc3_b, outv);
}

// Round 4
// 756.323 us; speedup vs baseline: 4.8071x; 1.2825x over previous
//
#include <hip/hip_runtime.h>

#define NN 100000
#define EPS 1e-5f

// ---- workspace layout (4-byte units) ----
static const size_t OFF_ROWPTR = 0;
static const size_t OFF_ADJ    = 100004;
static const size_t OFF_CURSOR = 1700008;
static const size_t OFF_AGG1   = 1800008;
static const size_t OFF_AGG2   = 5000008;
static const size_t OFF_Z1     = 0;          // aliases CSR+agg (dead by fc1)
static const size_t OFF_Z2     = 12800000;
static const size_t OFF_DEG    = 19200000;
static const size_t OFF_STATS1 = 19300000;
static const size_t OFF_STATS2 = 19300256;
static const size_t OFF_COEF1  = 19300384;
static const size_t OFF_COEF2  = 19300640;
static const size_t OFF_BSUM   = 19300768;   // 128 ints
static const size_t OFF_BOFF   = 19300896;   // 128 ints
static const size_t ZERO_START = 19200000;   // deg + stats1 + stats2
static const size_t ZERO_FLOATS = 100384;

#define SCAN_BS 1024
#define SCAN_NB 98                            // ceil(100000/1024)

// ---- CSR build: histogram of targets ----
__global__ __launch_bounds__(256) void hist_k(const int* __restrict__ ei, int E,
                                              int* __restrict__ deg) {
  int e = blockIdx.x * 256 + threadIdx.x;
  if (e >= E) return;
  int t = ei[E + e];
  if ((unsigned)t < NN) atomicAdd(&deg[t], 1);
}

// ---- scan phase 1: per-block sums of deg ----
__global__ __launch_bounds__(SCAN_BS) void bsum_k(const int* __restrict__ deg,
                                                  int* __restrict__ bsum) {
  __shared__ int sh[SCAN_BS];
  int t = threadIdx.x;
  int i = blockIdx.x * SCAN_BS + t;
  sh[t] = (i < NN) ? deg[i] : 0;
  __syncthreads();
  for (int o = SCAN_BS / 2; o > 0; o >>= 1) {
    if (t < o) sh[t] += sh[t + o];
    __syncthreads();
  }
  if (t == 0) bsum[blockIdx.x] = sh[0];
}

// ---- scan phase 2: exclusive scan of 98 block sums ----
__global__ __launch_bounds__(128) void bscan_k(const int* __restrict__ bsum,
                                               int* __restrict__ boff) {
  __shared__ int sh[128];
  int t = threadIdx.x;
  int v = (t < SCAN_NB) ? bsum[t] : 0;
  sh[t] = v;
  __syncthreads();
  for (int o = 1; o < 128; o <<= 1) {
    int u = (t >= o) ? sh[t - o] : 0;
    __syncthreads();
    sh[t] += u;
    __syncthreads();
  }
  if (t < SCAN_NB) boff[t] = sh[t] - v;
}

// ---- scan phase 3: block-local inclusive scan + offset -> rowptr/cursor ----
__global__ __launch_bounds__(SCAN_BS) void lscan_k(const int* __restrict__ deg,
                                                   const int* __restrict__ boff,
                                                   int* __restrict__ rowptr,
                                                   int* __restrict__ cursor) {
  __shared__ int sh[SCAN_BS];
  int t = threadIdx.x;
  int i = blockIdx.x * SCAN_BS + t;
  int v = (i < NN) ? deg[i] : 0;
  sh[t] = v;
  __syncthreads();
  for (int o = 1; o < SCAN_BS; o <<= 1) {
    int u = (t >= o) ? sh[t - o] : 0;
    __syncthreads();
    sh[t] += u;
    __syncthreads();
  }
  int incl = sh[t] + boff[blockIdx.x];
  if (i < NN) {
    int excl = incl - v;
    rowptr[i] = excl;
    cursor[i] = excl;
    if (i == NN - 1) rowptr[NN] = incl;
  }
}

// ---- CSR build: fill adjacency ----
__global__ __launch_bounds__(256) void fill_k(const int* __restrict__ ei, int E,
                                              int* __restrict__ cursor,
                                              int* __restrict__ adj) {
  int e = blockIdx.x * 256 + threadIdx.x;
  if (e >= E) return;
  int s = ei[e], t = ei[E + e];
  if ((unsigned)t >= NN || (unsigned)s >= NN) return;
  int pos = atomicAdd(&cursor[t], 1);
  adj[pos] = s;
}

// ---- gather-side mean aggregation: K-lane group per node ----
template<int K>
__global__ __launch_bounds__(256) void aggregate_k(const float* __restrict__ x,
                                                   const int* __restrict__ rowptr,
                                                   const int* __restrict__ adj,
                                                   float* __restrict__ agg) {
  constexpr int NPB = 256 / K;
  int lane = threadIdx.x & (K - 1);
  int node = blockIdx.x * NPB + (threadIdx.x / K);
  if (node >= NN) return;
  int s0 = rowptr[node], s1 = rowptr[node + 1];
  float acc0 = 0.f, acc1 = 0.f;
  int e = s0;
  for (; e + 1 < s1; e += 2) {
    int sa = adj[e], sb = adj[e + 1];
    acc0 += x[(size_t)sa * K + lane];
    acc1 += x[(size_t)sb * K + lane];
  }
  if (e < s1) acc0 += x[(size_t)adj[e] * K + lane];
  float inv = 1.0f / fmaxf((float)(s1 - s0), 1.0f);
  agg[(size_t)node * K + lane] = (acc0 + acc1) * inv;
}

// ---- dense layer, one thread per node, wave-uniform weight reads ----
template<int K, int C, bool SAGE, bool BNIN, bool RELU>
__global__ __launch_bounds__(256) void dense_k(const float* __restrict__ inA,
                                               const float* __restrict__ inB,
                                               const float* __restrict__ wA,
                                               const float* __restrict__ wB,
                                               const float* __restrict__ bias,
                                               const float* __restrict__ coef,
                                               float* __restrict__ out) {
  int node = blockIdx.x * 256 + threadIdx.x;
  if (node >= NN) return;
  float rA[K];
  float rB[SAGE ? K : 4];
  const float4* pa = (const float4*)(inA + (size_t)node * K);
  #pragma unroll
  for (int k = 0; k < K / 4; ++k) {
    float4 v = pa[k];
    rA[4 * k] = v.x; rA[4 * k + 1] = v.y; rA[4 * k + 2] = v.z; rA[4 * k + 3] = v.w;
  }
  if (BNIN) {
    #pragma unroll
    for (int k = 0; k < K; ++k) rA[k] = fmaxf(rA[k] * coef[k] + coef[K + k], 0.f);
  }
  if (SAGE) {
    const float4* pb = (const float4*)(inB + (size_t)node * K);
    #pragma unroll
    for (int k = 0; k < K / 4; ++k) {
      float4 v = pb[k];
      rB[4 * k] = v.x; rB[4 * k + 1] = v.y; rB[4 * k + 2] = v.z; rB[4 * k + 3] = v.w;
    }
  }
  #pragma unroll 1
  for (int jb = 0; jb < C; jb += 4) {
    float acc[4];
    #pragma unroll
    for (int u = 0; u < 4; ++u) acc[u] = bias[jb + u];
    #pragma unroll
    for (int k = 0; k < K; k += 4) {
      #pragma unroll
      for (int u = 0; u < 4; ++u) {
        float4 w4 = *(const float4*)(wA + (size_t)(jb + u) * K + k);
        acc[u] += rA[k] * w4.x + rA[k + 1] * w4.y + rA[k + 2] * w4.z + rA[k + 3] * w4.w;
      }
    }
    if (SAGE) {
      #pragma unroll
      for (int k = 0; k < K; k += 4) {
        #pragma unroll
        for (int u = 0; u < 4; ++u) {
          float4 w4 = *(const float4*)(wB + (size_t)(jb + u) * K + k);
          acc[u] += rB[k] * w4.x + rB[k + 1] * w4.y + rB[k + 2] * w4.z + rB[k + 3] * w4.w;
        }
      }
    }
    float4 o;
    o.x = RELU ? fmaxf(acc[0], 0.f) : acc[0];
    o.y = RELU ? fmaxf(acc[1], 0.f) : acc[1];
    o.z = RELU ? fmaxf(acc[2], 0.f) : acc[2];
    o.w = RELU ? fmaxf(acc[3], 0.f) : acc[3];
    *(float4*)(out + (size_t)node * C + jb) = o;
  }
}

// ---- column sums / sumsq over [NN, C] ----
template<int C>
__global__ __launch_bounds__(256) void colstats(const float* __restrict__ z,
                                                float* __restrict__ stats) {
  const long long total = (long long)NN * C;
  int t = threadIdx.x;
  long long idx = (long long)blockIdx.x * 256 + t;
  long long stride = (long long)gridDim.x * 256;
  float s = 0.f, q = 0.f;
  for (; idx < total; idx += stride) {
    float v = z[idx];
    s += v;
    q += v * v;
  }
  __shared__ float ls[256], lq[256];
  ls[t] = s; lq[t] = q;
  __syncthreads();
  if (t < C) {
    float ss = 0.f, qq = 0.f;
    #pragma unroll
    for (int r = 0; r < 256 / C; ++r) { ss += ls[t + r * C]; qq += lq[t + r * C]; }
    atomicAdd(&stats[t], ss);
    atomicAdd(&stats[C + t], qq);
  }
}

// ---- stats -> affine coefs: y = v*a + c ----
__global__ void bncoef(const float* __restrict__ stats, const float* __restrict__ g,
                       const float* __restrict__ b, float* __restrict__ coef, int C) {
  int j = threadIdx.x;
  if (j >= C) return;
  float mu  = stats[j] * (1.0f / NN);
  float var = stats[C + j] * (1.0f / NN) - mu * mu;
  float a = g[j] * rsqrtf(var + EPS);
  coef[j] = a;
  coef[C + j] = b[j] - mu * a;
}

// ---- final: out[i] = sum_j relu(z2[i][j]*a+c) * fc3w[j] + fc3b ----
__global__ __launch_bounds__(256) void final_k(const float* __restrict__ z2,
                                               const float* __restrict__ coef,
                                               const float* __restrict__ fc3w,
                                               const float* __restrict__ fc3b,
                                               float* __restrict__ out) {
  int t = blockIdx.x * 256 + threadIdx.x;
  int i = t >> 6;
  int j = t & 63;
  if (i >= NN) return;
  float v = z2[(size_t)i * 64 + j];
  float p = fmaxf(v * coef[j] + coef[64 + j], 0.f) * fc3w[j];
  #pragma unroll
  for (int o = 32; o > 0; o >>= 1) p += __shfl_xor(p, o, 64);
  if (j == 0) out[i] = p + fc3b[0];
}

extern "C" void kernel_launch(void* const* d_in, const int* in_sizes, int n_in,
                              void* d_out, int out_size, void* d_ws, size_t ws_size,
                              hipStream_t stream) {
  const float* x     = (const float*)d_in[0];
  const int*   ei    = (const int*)d_in[1];
  const float* w_l1  = (const float*)d_in[2];
  const float* b_l1  = (const float*)d_in[3];
  const float* w_r1  = (const float*)d_in[4];
  const float* w_l2  = (const float*)d_in[5];
  const float* b_l2  = (const float*)d_in[6];
  const float* w_r2  = (const float*)d_in[7];
  const float* fc1_w = (const float*)d_in[8];
  const float* fc1_b = (const float*)d_in[9];
  const float* bn1_g = (const float*)d_in[10];
  const float* bn1_b = (const float*)d_in[11];
  const float* fc2_w = (const float*)d_in[12];
  const float* fc2_b = (const float*)d_in[13];
  const float* bn2_g = (const float*)d_in[14];
  const float* bn2_b = (const float*)d_in[15];
  const float* fc3_w = (const float*)d_in[16];
  const float* fc3_b = (const float*)d_in[17];

  const int E = in_sizes[1] / 2;

  float* ws     = (float*)d_ws;
  int*   rowptr = (int*)(ws + OFF_ROWPTR);
  int*   adj    = (int*)(ws + OFF_ADJ);
  int*   cursor = (int*)(ws + OFF_CURSOR);
  float* agg1   = ws + OFF_AGG1;
  float* agg2   = ws + OFF_AGG2;
  float* z1     = ws + OFF_Z1;
  float* z2     = ws + OFF_Z2;
  int*   deg    = (int*)(ws + OFF_DEG);
  float* stats1 = ws + OFF_STATS1;
  float* stats2 = ws + OFF_STATS2;
  float* coef1  = ws + OFF_COEF1;
  float* coef2  = ws + OFF_COEF2;
  int*   bsum   = (int*)(ws + OFF_BSUM);
  int*   boff   = (int*)(ws + OFF_BOFF);

  float* outv = (float*)d_out;             // [NN]
  float* h1   = outv + NN;                 // [NN,64]
  float* h2   = h1 + (size_t)NN * 64;      // [NN,64]

  hipMemsetAsync(ws + ZERO_START, 0, ZERO_FLOATS * sizeof(float), stream);

  // CSR build (shared by both layers) — hierarchical scan
  hist_k<<<(E + 255) / 256, 256, 0, stream>>>(ei, E, deg);
  bsum_k<<<SCAN_NB, SCAN_BS, 0, stream>>>(deg, bsum);
  bscan_k<<<1, 128, 0, stream>>>(bsum, boff);
  lscan_k<<<SCAN_NB, SCAN_BS, 0, stream>>>(deg, boff, rowptr, cursor);
  fill_k<<<(E + 255) / 256, 256, 0, stream>>>(ei, E, cursor, adj);

  const int NB = (NN + 255) / 256;

  // layer 1
  aggregate_k<32><<<(NN * 32 + 255) / 256, 256, 0, stream>>>(x, rowptr, adj, agg1);
  dense_k<32, 64, true, false, true><<<NB, 256, 0, stream>>>(agg1, x, w_l1, w_r1, b_l1, nullptr, h1);

  // layer 2
  aggregate_k<64><<<(NN * 64 + 255) / 256, 256, 0, stream>>>(h1, rowptr, adj, agg2);
  dense_k<64, 64, true, false, true><<<NB, 256, 0, stream>>>(agg2, h1, w_l2, w_r2, b_l2, nullptr, h2);

  // fc1 -> z1 (raw, pre-BN)
  dense_k<64, 128, false, false, false><<<NB, 256, 0, stream>>>(h2, nullptr, fc1_w, nullptr, fc1_b, nullptr, z1);
  colstats<128><<<512, 256, 0, stream>>>(z1, stats1);
  bncoef<<<1, 128, 0, stream>>>(stats1, bn1_g, bn1_b, coef1, 128);

  // fc2 with fused bn1+relu on input -> z2 (raw, pre-BN)
  dense_k<128, 64, false, true, false><<<NB, 256, 0, stream>>>(z1, nullptr, fc2_w, nullptr, fc2_b, coef1, z2);
  colstats<64><<<512, 256, 0, stream>>>(z2, stats2);
  bncoef<<<1, 64, 0, stream>>>(stats2, bn2_g, bn2_b, coef2, 64);

  // bn2 + relu + fc3 fused
  final_k<<<(NN * 64 + 255) / 256, 256, 0, stream>>>(z2, coef2, fc3_w, fc3_b, outv);
}

// Round 5
// 747.280 us; speedup vs baseline: 4.8653x; 1.0121x over previous
//
#include <hip/hip_runtime.h>

#define NN 100000
#define EPS 1e-5f

// ---- workspace layout (4-byte units) ----
static const size_t OFF_ROWPTR = 0;
static const size_t OFF_ADJ    = 100004;
static const size_t OFF_CURSOR = 1700008;
static const size_t OFF_AGG1   = 1800008;
static const size_t OFF_AGG2   = 5000008;
static const size_t OFF_Z1     = 0;          // aliases CSR+agg (dead by fc1)
static const size_t OFF_Z2     = 12800000;
static const size_t OFF_DEG    = 19200000;
static const size_t OFF_STATS1 = 19300000;
static const size_t OFF_STATS2 = 19300256;
static const size_t OFF_COEF1  = 19300384;
static const size_t OFF_COEF2  = 19300640;
static const size_t OFF_BSUM   = 19300768;   // 128 ints
static const size_t OFF_BOFF   = 19300896;   // 128 ints
static const size_t ZERO_START = 19200000;   // deg + stats1 + stats2
static const size_t ZERO_FLOATS = 100384;

#define SCAN_BS 1024
#define SCAN_NB 98                            // ceil(100000/1024)

// ---- CSR build: histogram of targets ----
__global__ __launch_bounds__(256) void hist_k(const int* __restrict__ ei, int E,
                                              int* __restrict__ deg) {
  int e = blockIdx.x * 256 + threadIdx.x;
  if (e >= E) return;
  int t = ei[E + e];
  if ((unsigned)t < NN) atomicAdd(&deg[t], 1);
}

// ---- scan phase 1: per-block sums of deg ----
__global__ __launch_bounds__(SCAN_BS) void bsum_k(const int* __restrict__ deg,
                                                  int* __restrict__ bsum) {
  __shared__ int sh[SCAN_BS];
  int t = threadIdx.x;
  int i = blockIdx.x * SCAN_BS + t;
  sh[t] = (i < NN) ? deg[i] : 0;
  __syncthreads();
  for (int o = SCAN_BS / 2; o > 0; o >>= 1) {
    if (t < o) sh[t] += sh[t + o];
    __syncthreads();
  }
  if (t == 0) bsum[blockIdx.x] = sh[0];
}

// ---- scan phase 2: exclusive scan of 98 block sums ----
__global__ __launch_bounds__(128) void bscan_k(const int* __restrict__ bsum,
                                               int* __restrict__ boff) {
  __shared__ int sh[128];
  int t = threadIdx.x;
  int v = (t < SCAN_NB) ? bsum[t] : 0;
  sh[t] = v;
  __syncthreads();
  for (int o = 1; o < 128; o <<= 1) {
    int u = (t >= o) ? sh[t - o] : 0;
    __syncthreads();
    sh[t] += u;
    __syncthreads();
  }
  if (t < SCAN_NB) boff[t] = sh[t] - v;
}

// ---- scan phase 3: block-local inclusive scan + offset -> rowptr/cursor ----
__global__ __launch_bounds__(SCAN_BS) void lscan_k(const int* __restrict__ deg,
                                                   const int* __restrict__ boff,
                                                   int* __restrict__ rowptr,
                                                   int* __restrict__ cursor) {
  __shared__ int sh[SCAN_BS];
  int t = threadIdx.x;
  int i = blockIdx.x * SCAN_BS + t;
  int v = (i < NN) ? deg[i] : 0;
  sh[t] = v;
  __syncthreads();
  for (int o = 1; o < SCAN_BS; o <<= 1) {
    int u = (t >= o) ? sh[t - o] : 0;
    __syncthreads();
    sh[t] += u;
    __syncthreads();
  }
  int incl = sh[t] + boff[blockIdx.x];
  if (i < NN) {
    int excl = incl - v;
    rowptr[i] = excl;
    cursor[i] = excl;
    if (i == NN - 1) rowptr[NN] = incl;
  }
}

// ---- CSR build: fill adjacency ----
__global__ __launch_bounds__(256) void fill_k(const int* __restrict__ ei, int E,
                                              int* __restrict__ cursor,
                                              int* __restrict__ adj) {
  int e = blockIdx.x * 256 + threadIdx.x;
  if (e >= E) return;
  int s = ei[e], t = ei[E + e];
  if ((unsigned)t >= NN || (unsigned)s >= NN) return;
  int pos = atomicAdd(&cursor[t], 1);
  adj[pos] = s;
}

// ---- gather-side mean aggregation: K-lane group per node ----
template<int K>
__global__ __launch_bounds__(256) void aggregate_k(const float* __restrict__ x,
                                                   const int* __restrict__ rowptr,
                                                   const int* __restrict__ adj,
                                                   float* __restrict__ agg) {
  constexpr int NPB = 256 / K;
  int lane = threadIdx.x & (K - 1);
  int node = blockIdx.x * NPB + (threadIdx.x / K);
  if (node >= NN) return;
  int s0 = rowptr[node], s1 = rowptr[node + 1];
  float acc0 = 0.f, acc1 = 0.f;
  int e = s0;
  for (; e + 1 < s1; e += 2) {
    int sa = adj[e], sb = adj[e + 1];
    acc0 += x[(size_t)sa * K + lane];
    acc1 += x[(size_t)sb * K + lane];
  }
  if (e < s1) acc0 += x[(size_t)adj[e] * K + lane];
  float inv = 1.0f / fmaxf((float)(s1 - s0), 1.0f);
  agg[(size_t)node * K + lane] = (acc0 + acc1) * inv;
}

// ---- dense layer: C-tiled (CT outputs/block), weights staged in LDS ----
// out[i][cbase+j] = act( bias[cbase+j] + rowA.wA[cbase+j] (+ rowB.wB[cbase+j]) )
// rowA optionally pre-transformed by relu(v*a+c) (fused BN of previous layer).
template<int K, int C, int CT, bool SAGE, bool BNIN, bool RELU>
__global__ __launch_bounds__(256) void dense_k(const float* __restrict__ inA,
                                               const float* __restrict__ inB,
                                               const float* __restrict__ wA,
                                               const float* __restrict__ wB,
                                               const float* __restrict__ bias,
                                               const float* __restrict__ coef,
                                               float* __restrict__ out) {
  __shared__ float swA[CT * K];
  __shared__ float swB[SAGE ? CT * K : 4];
  __shared__ float sbias[CT];
  const int cbase = blockIdx.y * CT;

  // cooperative weight-tile load (coalesced float4)
  for (int idx = threadIdx.x; idx < CT * K / 4; idx += 256) {
    ((float4*)swA)[idx] = ((const float4*)(wA + (size_t)cbase * K))[idx];
    if (SAGE) ((float4*)swB)[idx] = ((const float4*)(wB + (size_t)cbase * K))[idx];
  }
  if (threadIdx.x < CT) sbias[threadIdx.x] = bias[cbase + threadIdx.x];
  __syncthreads();

  int node = blockIdx.x * 256 + threadIdx.x;
  if (node >= NN) return;

  float rA[K];
  float rB[SAGE ? K : 4];
  const float4* pa = (const float4*)(inA + (size_t)node * K);
  #pragma unroll
  for (int k = 0; k < K / 4; ++k) {
    float4 v = pa[k];
    rA[4 * k] = v.x; rA[4 * k + 1] = v.y; rA[4 * k + 2] = v.z; rA[4 * k + 3] = v.w;
  }
  if (BNIN) {
    #pragma unroll
    for (int k = 0; k < K; ++k) rA[k] = fmaxf(rA[k] * coef[k] + coef[K + k], 0.f);
  }
  if (SAGE) {
    const float4* pb = (const float4*)(inB + (size_t)node * K);
    #pragma unroll
    for (int k = 0; k < K / 4; ++k) {
      float4 v = pb[k];
      rB[4 * k] = v.x; rB[4 * k + 1] = v.y; rB[4 * k + 2] = v.z; rB[4 * k + 3] = v.w;
    }
  }

  #pragma unroll 1
  for (int jb = 0; jb < CT; jb += 4) {
    float acc[4];
    #pragma unroll
    for (int u = 0; u < 4; ++u) acc[u] = sbias[jb + u];
    #pragma unroll
    for (int k = 0; k < K; k += 4) {
      #pragma unroll
      for (int u = 0; u < 4; ++u) {
        float4 w4 = *(const float4*)(swA + (size_t)(jb + u) * K + k);   // LDS broadcast
        acc[u] += rA[k] * w4.x + rA[k + 1] * w4.y + rA[k + 2] * w4.z + rA[k + 3] * w4.w;
      }
    }
    if (SAGE) {
      #pragma unroll
      for (int k = 0; k < K; k += 4) {
        #pragma unroll
        for (int u = 0; u < 4; ++u) {
          float4 w4 = *(const float4*)(swB + (size_t)(jb + u) * K + k);
          acc[u] += rB[k] * w4.x + rB[k + 1] * w4.y + rB[k + 2] * w4.z + rB[k + 3] * w4.w;
        }
      }
    }
    float4 o;
    o.x = RELU ? fmaxf(acc[0], 0.f) : acc[0];
    o.y = RELU ? fmaxf(acc[1], 0.f) : acc[1];
    o.z = RELU ? fmaxf(acc[2], 0.f) : acc[2];
    o.w = RELU ? fmaxf(acc[3], 0.f) : acc[3];
    *(float4*)(out + (size_t)node * C + cbase + jb) = o;
  }
}

// ---- column sums / sumsq over [NN, C] ----
template<int C>
__global__ __launch_bounds__(256) void colstats(const float* __restrict__ z,
                                                float* __restrict__ stats) {
  const long long total = (long long)NN * C;
  int t = threadIdx.x;
  long long idx = (long long)blockIdx.x * 256 + t;
  long long stride = (long long)gridDim.x * 256;
  float s = 0.f, q = 0.f;
  for (; idx < total; idx += stride) {
    float v = z[idx];
    s += v;
    q += v * v;
  }
  __shared__ float ls[256], lq[256];
  ls[t] = s; lq[t] = q;
  __syncthreads();
  if (t < C) {
    float ss = 0.f, qq = 0.f;
    #pragma unroll
    for (int r = 0; r < 256 / C; ++r) { ss += ls[t + r * C]; qq += lq[t + r * C]; }
    atomicAdd(&stats[t], ss);
    atomicAdd(&stats[C + t], qq);
  }
}

// ---- stats -> affine coefs: y = v*a + c ----
__global__ void bncoef(const float* __restrict__ stats, const float* __restrict__ g,
                       const float* __restrict__ b, float* __restrict__ coef, int C) {
  int j = threadIdx.x;
  if (j >= C) return;
  float mu  = stats[j] * (1.0f / NN);
  float var = stats[C + j] * (1.0f / NN) - mu * mu;
  float a = g[j] * rsqrtf(var + EPS);
  coef[j] = a;
  coef[C + j] = b[j] - mu * a;
}

// ---- final: out[i] = sum_j relu(z2[i][j]*a+c) * fc3w[j] + fc3b ----
__global__ __launch_bounds__(256) void final_k(const float* __restrict__ z2,
                                               const float* __restrict__ coef,
                                               const float* __restrict__ fc3w,
                                               const float* __restrict__ fc3b,
                                               float* __restrict__ out) {
  int t = blockIdx.x * 256 + threadIdx.x;
  int i = t >> 6;
  int j = t & 63;
  if (i >= NN) return;
  float v = z2[(size_t)i * 64 + j];
  float p = fmaxf(v * coef[j] + coef[64 + j], 0.f) * fc3w[j];
  #pragma unroll
  for (int o = 32; o > 0; o >>= 1) p += __shfl_xor(p, o, 64);
  if (j == 0) out[i] = p + fc3b[0];
}

extern "C" void kernel_launch(void* const* d_in, const int* in_sizes, int n_in,
                              void* d_out, int out_size, void* d_ws, size_t ws_size,
                              hipStream_t stream) {
  const float* x     = (const float*)d_in[0];
  const int*   ei    = (const int*)d_in[1];
  const float* w_l1  = (const float*)d_in[2];
  const float* b_l1  = (const float*)d_in[3];
  const float* w_r1  = (const float*)d_in[4];
  const float* w_l2  = (const float*)d_in[5];
  const float* b_l2  = (const float*)d_in[6];
  const float* w_r2  = (const float*)d_in[7];
  const float* fc1_w = (const float*)d_in[8];
  const float* fc1_b = (const float*)d_in[9];
  const float* bn1_g = (const float*)d_in[10];
  const float* bn1_b = (const float*)d_in[11];
  const float* fc2_w = (const float*)d_in[12];
  const float* fc2_b = (const float*)d_in[13];
  const float* bn2_g = (const float*)d_in[14];
  const float* bn2_b = (const float*)d_in[15];
  const float* fc3_w = (const float*)d_in[16];
  const float* fc3_b = (const float*)d_in[17];

  const int E = in_sizes[1] / 2;

  float* ws     = (float*)d_ws;
  int*   rowptr = (int*)(ws + OFF_ROWPTR);
  int*   adj    = (int*)(ws + OFF_ADJ);
  int*   cursor = (int*)(ws + OFF_CURSOR);
  float* agg1   = ws + OFF_AGG1;
  float* agg2   = ws + OFF_AGG2;
  float* z1     = ws + OFF_Z1;
  float* z2     = ws + OFF_Z2;
  int*   deg    = (int*)(ws + OFF_DEG);
  float* stats1 = ws + OFF_STATS1;
  float* stats2 = ws + OFF_STATS2;
  float* coef1  = ws + OFF_COEF1;
  float* coef2  = ws + OFF_COEF2;
  int*   bsum   = (int*)(ws + OFF_BSUM);
  int*   boff   = (int*)(ws + OFF_BOFF);

  float* outv = (float*)d_out;             // [NN]
  float* h1   = outv + NN;                 // [NN,64]
  float* h2   = h1 + (size_t)NN * 64;      // [NN,64]

  hipMemsetAsync(ws + ZERO_START, 0, ZERO_FLOATS * sizeof(float), stream);

  // CSR build (shared by both layers) — hierarchical scan
  hist_k<<<(E + 255) / 256, 256, 0, stream>>>(ei, E, deg);
  bsum_k<<<SCAN_NB, SCAN_BS, 0, stream>>>(deg, bsum);
  bscan_k<<<1, 128, 0, stream>>>(bsum, boff);
  lscan_k<<<SCAN_NB, SCAN_BS, 0, stream>>>(deg, boff, rowptr, cursor);
  fill_k<<<(E + 255) / 256, 256, 0, stream>>>(ei, E, cursor, adj);

  const int NB = (NN + 255) / 256;

  // layer 1: C=64, CT=32 -> grid (NB, 2)
  aggregate_k<32><<<(NN * 32 + 255) / 256, 256, 0, stream>>>(x, rowptr, adj, agg1);
  dense_k<32, 64, 32, true, false, true>
      <<<dim3(NB, 2), 256, 0, stream>>>(agg1, x, w_l1, w_r1, b_l1, nullptr, h1);

  // layer 2
  aggregate_k<64><<<(NN * 64 + 255) / 256, 256, 0, stream>>>(h1, rowptr, adj, agg2);
  dense_k<64, 64, 32, true, false, true>
      <<<dim3(NB, 2), 256, 0, stream>>>(agg2, h1, w_l2, w_r2, b_l2, nullptr, h2);

  // fc1 -> z1 (raw, pre-BN): C=128, CT=32 -> grid (NB, 4)
  dense_k<64, 128, 32, false, false, false>
      <<<dim3(NB, 4), 256, 0, stream>>>(h2, nullptr, fc1_w, nullptr, fc1_b, nullptr, z1);
  colstats<128><<<512, 256, 0, stream>>>(z1, stats1);
  bncoef<<<1, 128, 0, stream>>>(stats1, bn1_g, bn1_b, coef1, 128);

  // fc2 with fused bn1+relu on input -> z2 (raw, pre-BN)
  dense_k<128, 64, 32, false, true, false>
      <<<dim3(NB, 2), 256, 0, stream>>>(z1, nullptr, fc2_w, nullptr, fc2_b, coef1, z2);
  colstats<64><<<512, 256, 0, stream>>>(z2, stats2);
  bncoef<<<1, 64, 0, stream>>>(stats2, bn2_g, bn2_b, coef2, 64);

  // bn2 + relu + fc3 fused
  final_k<<<(NN * 64 + 255) / 256, 256, 0, stream>>>(z2, coef2, fc3_w, fc3_b, outv);
}

// Round 6
// 549.943 us; speedup vs baseline: 6.6111x; 1.3588x over previous
//
#include <hip/hip_runtime.h>

#define NN 100000
#define EPS 1e-5f

// ---- workspace layout (4-byte units) ----
static const size_t OFF_ROWPTR = 0;
static const size_t OFF_ADJ    = 100004;
static const size_t OFF_CURSOR = 1700008;
static const size_t OFF_AGG1   = 1800008;
static const size_t OFF_AGG2   = 5000008;
static const size_t OFF_Z1     = 0;          // aliases CSR+agg (dead by fc1)
static const size_t OFF_Z2     = 12800000;
static const size_t OFF_DEG    = 19200000;
static const size_t OFF_STATS1 = 19300000;
static const size_t OFF_STATS2 = 19300256;
static const size_t OFF_COEF1  = 19300384;
static const size_t OFF_COEF2  = 19300640;
static const size_t OFF_BSUM   = 19300768;   // 128 ints
static const size_t OFF_BOFF   = 19300896;   // 128 ints
static const size_t ZERO_START = 19200000;   // deg + stats1 + stats2
static const size_t ZERO_FLOATS = 100384;

#define SCAN_BS 1024
#define SCAN_NB 98                            // ceil(100000/1024)

typedef __attribute__((ext_vector_type(8))) short short8;
typedef __attribute__((ext_vector_type(4))) float f32x4;

#define MFMA_16x16x32(a, b, c) __builtin_amdgcn_mfma_f32_16x16x32_bf16(a, b, c, 0, 0, 0)

// f32 -> bf16 (RNE) at bit level
__device__ inline unsigned short f2bf(float f) {
  unsigned u = __builtin_bit_cast(unsigned, f);
  unsigned r = (u + 0x7fffu + ((u >> 16) & 1u)) >> 16;
  return (unsigned short)r;
}
__device__ inline float bf2f(unsigned short h) {
  unsigned u = ((unsigned)h) << 16;
  return __builtin_bit_cast(float, u);
}

// load 8 contiguous f32 (optionally BN+relu transformed), split into hi/lo bf16
template<bool BNIN>
__device__ inline void load_split(const float* __restrict__ p,
                                  const float* __restrict__ ca,
                                  const float* __restrict__ cc,
                                  short8& hi, short8& lo) {
  #pragma unroll
  for (int j = 0; j < 8; ++j) {
    float v = p[j];
    if (BNIN) v = fmaxf(v * ca[j] + cc[j], 0.f);
    unsigned short h = f2bf(v);
    hi[j] = (short)h;
    lo[j] = (short)f2bf(v - bf2f(h));
  }
}

// ---- CSR build: histogram of targets ----
__global__ __launch_bounds__(256) void hist_k(const int* __restrict__ ei, int E,
                                              int* __restrict__ deg) {
  int e = blockIdx.x * 256 + threadIdx.x;
  if (e >= E) return;
  int t = ei[E + e];
  if ((unsigned)t < NN) atomicAdd(&deg[t], 1);
}

// ---- scan phase 1: per-block sums of deg ----
__global__ __launch_bounds__(SCAN_BS) void bsum_k(const int* __restrict__ deg,
                                                  int* __restrict__ bsum) {
  __shared__ int sh[SCAN_BS];
  int t = threadIdx.x;
  int i = blockIdx.x * SCAN_BS + t;
  sh[t] = (i < NN) ? deg[i] : 0;
  __syncthreads();
  for (int o = SCAN_BS / 2; o > 0; o >>= 1) {
    if (t < o) sh[t] += sh[t + o];
    __syncthreads();
  }
  if (t == 0) bsum[blockIdx.x] = sh[0];
}

// ---- scan phase 2: exclusive scan of 98 block sums ----
__global__ __launch_bounds__(128) void bscan_k(const int* __restrict__ bsum,
                                               int* __restrict__ boff) {
  __shared__ int sh[128];
  int t = threadIdx.x;
  int v = (t < SCAN_NB) ? bsum[t] : 0;
  sh[t] = v;
  __syncthreads();
  for (int o = 1; o < 128; o <<= 1) {
    int u = (t >= o) ? sh[t - o] : 0;
    __syncthreads();
    sh[t] += u;
    __syncthreads();
  }
  if (t < SCAN_NB) boff[t] = sh[t] - v;
}

// ---- scan phase 3: block-local inclusive scan + offset -> rowptr/cursor ----
__global__ __launch_bounds__(SCAN_BS) void lscan_k(const int* __restrict__ deg,
                                                   const int* __restrict__ boff,
                                                   int* __restrict__ rowptr,
                                                   int* __restrict__ cursor) {
  __shared__ int sh[SCAN_BS];
  int t = threadIdx.x;
  int i = blockIdx.x * SCAN_BS + t;
  int v = (i < NN) ? deg[i] : 0;
  sh[t] = v;
  __syncthreads();
  for (int o = 1; o < SCAN_BS; o <<= 1) {
    int u = (t >= o) ? sh[t - o] : 0;
    __syncthreads();
    sh[t] += u;
    __syncthreads();
  }
  int incl = sh[t] + boff[blockIdx.x];
  if (i < NN) {
    int excl = incl - v;
    rowptr[i] = excl;
    cursor[i] = excl;
    if (i == NN - 1) rowptr[NN] = incl;
  }
}

// ---- CSR build: fill adjacency ----
__global__ __launch_bounds__(256) void fill_k(const int* __restrict__ ei, int E,
                                              int* __restrict__ cursor,
                                              int* __restrict__ adj) {
  int e = blockIdx.x * 256 + threadIdx.x;
  if (e >= E) return;
  int s = ei[e], t = ei[E + e];
  if ((unsigned)t >= NN || (unsigned)s >= NN) return;
  int pos = atomicAdd(&cursor[t], 1);
  adj[pos] = s;
}

// ---- gather-side mean aggregation: K-lane group per node ----
template<int K>
__global__ __launch_bounds__(256) void aggregate_k(const float* __restrict__ x,
                                                   const int* __restrict__ rowptr,
                                                   const int* __restrict__ adj,
                                                   float* __restrict__ agg) {
  constexpr int NPB = 256 / K;
  int lane = threadIdx.x & (K - 1);
  int node = blockIdx.x * NPB + (threadIdx.x / K);
  if (node >= NN) return;
  int s0 = rowptr[node], s1 = rowptr[node + 1];
  float acc0 = 0.f, acc1 = 0.f;
  int e = s0;
  for (; e + 1 < s1; e += 2) {
    int sa = adj[e], sb = adj[e + 1];
    acc0 += x[(size_t)sa * K + lane];
    acc1 += x[(size_t)sb * K + lane];
  }
  if (e < s1) acc0 += x[(size_t)adj[e] * K + lane];
  float inv = 1.0f / fmaxf((float)(s1 - s0), 1.0f);
  agg[(size_t)node * K + lane] = (acc0 + acc1) * inv;
}

// ---- MFMA dense layer (split-bf16, f32-accurate) ----
// out[i][j] = act( bias[j] + inA[i].wA[j] (+ inB[i].wB[j]) )
// inA optionally pre-transformed relu(v*a+c) (fused BN of previous layer).
// One block = 4 waves x 16 rows = 64 rows; each wave computes 16 rows x C cols.
// A-frag: lane holds A[lane&15][8*(lane>>4)+j]; B-frag from row-major w[C,K]
// identically; D: col=lane&15, row=(lane>>4)*4+reg (m89-verified layout).
template<int K, int C, bool SAGE, bool BNIN, bool RELU>
__global__ __launch_bounds__(256) void mfma_dense(const float* __restrict__ inA,
                                                  const float* __restrict__ inB,
                                                  const float* __restrict__ wA,
                                                  const float* __restrict__ wB,
                                                  const float* __restrict__ bias,
                                                  const float* __restrict__ coef,
                                                  float* __restrict__ out) {
  constexpr int KF = K / 32;
  int wid  = threadIdx.x >> 6;
  int lane = threadIdx.x & 63;
  int row0 = blockIdx.x * 64 + wid * 16;
  int r = lane & 15, g = lane >> 4;
  int arow = row0 + r; if (arow > NN - 1) arow = NN - 1;   // clamp tail reads
  int koff = g * 8;

  short8 ahi[KF], alo[KF];
  short8 a2hi[SAGE ? KF : 1], a2lo[SAGE ? KF : 1];
  #pragma unroll
  for (int kf = 0; kf < KF; ++kf) {
    const float* p = inA + (size_t)arow * K + kf * 32 + koff;
    load_split<BNIN>(p, coef + kf * 32 + koff, coef + K + kf * 32 + koff,
                     ahi[kf], alo[kf]);
  }
  if (SAGE) {
    #pragma unroll
    for (int kf = 0; kf < KF; ++kf) {
      const float* p = inB + (size_t)arow * K + kf * 32 + koff;
      load_split<false>(p, nullptr, nullptr, a2hi[kf], a2lo[kf]);
    }
  }

  #pragma unroll 1
  for (int cf = 0; cf < C / 16; ++cf) {
    int col = cf * 16 + r;
    float bv = bias[col];
    f32x4 acc = {bv, bv, bv, bv};
    #pragma unroll
    for (int kf = 0; kf < KF; ++kf) {
      short8 whi, wlo;
      load_split<false>(wA + (size_t)col * K + kf * 32 + koff, nullptr, nullptr, whi, wlo);
      acc = MFMA_16x16x32(ahi[kf], whi, acc);
      acc = MFMA_16x16x32(ahi[kf], wlo, acc);
      acc = MFMA_16x16x32(alo[kf], whi, acc);
      if (SAGE) {
        short8 vhi, vlo;
        load_split<false>(wB + (size_t)col * K + kf * 32 + koff, nullptr, nullptr, vhi, vlo);
        acc = MFMA_16x16x32(a2hi[kf], vhi, acc);
        acc = MFMA_16x16x32(a2hi[kf], vlo, acc);
        acc = MFMA_16x16x32(a2lo[kf], vhi, acc);
      }
    }
    #pragma unroll
    for (int j = 0; j < 4; ++j) {
      int orow = row0 + g * 4 + j;
      if (orow < NN) {
        float v = acc[j];
        if (RELU) v = fmaxf(v, 0.f);
        out[(size_t)orow * C + col] = v;
      }
    }
  }
}

// ---- column sums / sumsq over [NN, C] ----
template<int C>
__global__ __launch_bounds__(256) void colstats(const float* __restrict__ z,
                                                float* __restrict__ stats) {
  const long long total = (long long)NN * C;
  int t = threadIdx.x;
  long long idx = (long long)blockIdx.x * 256 + t;
  long long stride = (long long)gridDim.x * 256;
  float s = 0.f, q = 0.f;
  for (; idx < total; idx += stride) {
    float v = z[idx];
    s += v;
    q += v * v;
  }
  __shared__ float ls[256], lq[256];
  ls[t] = s; lq[t] = q;
  __syncthreads();
  if (t < C) {
    float ss = 0.f, qq = 0.f;
    #pragma unroll
    for (int r = 0; r < 256 / C; ++r) { ss += ls[t + r * C]; qq += lq[t + r * C]; }
    atomicAdd(&stats[t], ss);
    atomicAdd(&stats[C + t], qq);
  }
}

// ---- stats -> affine coefs: y = v*a + c ----
__global__ void bncoef(const float* __restrict__ stats, const float* __restrict__ g,
                       const float* __restrict__ b, float* __restrict__ coef, int C) {
  int j = threadIdx.x;
  if (j >= C) return;
  float mu  = stats[j] * (1.0f / NN);
  float var = stats[C + j] * (1.0f / NN) - mu * mu;
  float a = g[j] * rsqrtf(var + EPS);
  coef[j] = a;
  coef[C + j] = b[j] - mu * a;
}

// ---- final: out[i] = sum_j relu(z2[i][j]*a+c) * fc3w[j] + fc3b ----
__global__ __launch_bounds__(256) void final_k(const float* __restrict__ z2,
                                               const float* __restrict__ coef,
                                               const float* __restrict__ fc3w,
                                               const float* __restrict__ fc3b,
                                               float* __restrict__ out) {
  int t = blockIdx.x * 256 + threadIdx.x;
  int i = t >> 6;
  int j = t & 63;
  if (i >= NN) return;
  float v = z2[(size_t)i * 64 + j];
  float p = fmaxf(v * coef[j] + coef[64 + j], 0.f) * fc3w[j];
  #pragma unroll
  for (int o = 32; o > 0; o >>= 1) p += __shfl_xor(p, o, 64);
  if (j == 0) out[i] = p + fc3b[0];
}

extern "C" void kernel_launch(void* const* d_in, const int* in_sizes, int n_in,
                              void* d_out, int out_size, void* d_ws, size_t ws_size,
                              hipStream_t stream) {
  const float* x     = (const float*)d_in[0];
  const int*   ei    = (const int*)d_in[1];
  const float* w_l1  = (const float*)d_in[2];
  const float* b_l1  = (const float*)d_in[3];
  const float* w_r1  = (const float*)d_in[4];
  const float* w_l2  = (const float*)d_in[5];
  const float* b_l2  = (const float*)d_in[6];
  const float* w_r2  = (const float*)d_in[7];
  const float* fc1_w = (const float*)d_in[8];
  const float* fc1_b = (const float*)d_in[9];
  const float* bn1_g = (const float*)d_in[10];
  const float* bn1_b = (const float*)d_in[11];
  const float* fc2_w = (const float*)d_in[12];
  const float* fc2_b = (const float*)d_in[13];
  const float* bn2_g = (const float*)d_in[14];
  const float* bn2_b = (const float*)d_in[15];
  const float* fc3_w = (const float*)d_in[16];
  const float* fc3_b = (const float*)d_in[17];

  const int E = in_sizes[1] / 2;

  float* ws     = (float*)d_ws;
  int*   rowptr = (int*)(ws + OFF_ROWPTR);
  int*   adj    = (int*)(ws + OFF_ADJ);
  int*   cursor = (int*)(ws + OFF_CURSOR);
  float* agg1   = ws + OFF_AGG1;
  float* agg2   = ws + OFF_AGG2;
  float* z1     = ws + OFF_Z1;
  float* z2     = ws + OFF_Z2;
  int*   deg    = (int*)(ws + OFF_DEG);
  float* stats1 = ws + OFF_STATS1;
  float* stats2 = ws + OFF_STATS2;
  float* coef1  = ws + OFF_COEF1;
  float* coef2  = ws + OFF_COEF2;
  int*   bsum   = (int*)(ws + OFF_BSUM);
  int*   boff   = (int*)(ws + OFF_BOFF);

  float* outv = (float*)d_out;             // [NN]
  float* h1   = outv + NN;                 // [NN,64]
  float* h2   = h1 + (size_t)NN * 64;      // [NN,64]

  hipMemsetAsync(ws + ZERO_START, 0, ZERO_FLOATS * sizeof(float), stream);

  // CSR build (shared by both layers) — hierarchical scan
  hist_k<<<(E + 255) / 256, 256, 0, stream>>>(ei, E, deg);
  bsum_k<<<SCAN_NB, SCAN_BS, 0, stream>>>(deg, bsum);
  bscan_k<<<1, 128, 0, stream>>>(bsum, boff);
  lscan_k<<<SCAN_NB, SCAN_BS, 0, stream>>>(deg, boff, rowptr, cursor);
  fill_k<<<(E + 255) / 256, 256, 0, stream>>>(ei, E, cursor, adj);

  const int MB = (NN + 63) / 64;   // MFMA dense grid: 64 rows per block

  // layer 1
  aggregate_k<32><<<(NN * 32 + 255) / 256, 256, 0, stream>>>(x, rowptr, adj, agg1);
  mfma_dense<32, 64, true, false, true>
      <<<MB, 256, 0, stream>>>(agg1, x, w_l1, w_r1, b_l1, nullptr, h1);

  // layer 2
  aggregate_k<64><<<(NN * 64 + 255) / 256, 256, 0, stream>>>(h1, rowptr, adj, agg2);
  mfma_dense<64, 64, true, false, true>
      <<<MB, 256, 0, stream>>>(agg2, h1, w_l2, w_r2, b_l2, nullptr, h2);

  // fc1 -> z1 (raw, pre-BN)
  mfma_dense<64, 128, false, false, false>
      <<<MB, 256, 0, stream>>>(h2, nullptr, fc1_w, nullptr, fc1_b, nullptr, z1);
  colstats<128><<<512, 256, 0, stream>>>(z1, stats1);
  bncoef<<<1, 128, 0, stream>>>(stats1, bn1_g, bn1_b, coef1, 128);

  // fc2 with fused bn1+relu on input -> z2 (raw, pre-BN)
  mfma_dense<128, 64, false, true, false>
      <<<MB, 256, 0, stream>>>(z1, nullptr, fc2_w, nullptr, fc2_b, coef1, z2);
  colstats<64><<<512, 256, 0, stream>>>(z2, stats2);
  bncoef<<<1, 64, 0, stream>>>(stats2, bn2_g, bn2_b, coef2, 64);

  // bn2 + relu + fc3 fused
  final_k<<<(NN * 64 + 255) / 256, 256, 0, stream>>>(z2, coef2, fc3_w, fc3_b, outv);
}

// Round 7
// 500.426 us; speedup vs baseline: 7.2653x; 1.0989x over previous
//
#include <hip/hip_runtime.h>

#define NN 100000
#define EPS 1e-5f

// ---- workspace layout (4-byte units) ----
static const size_t OFF_ROWPTR = 0;
static const size_t OFF_ADJ    = 100004;
static const size_t OFF_CURSOR = 1700008;
static const size_t OFF_AGG1   = 1800008;
static const size_t OFF_AGG2   = 5000008;
static const size_t OFF_Z1     = 0;          // aliases CSR+agg (dead by fc1)
static const size_t OFF_Z2     = 12800000;
static const size_t OFF_DEG    = 19200000;
static const size_t OFF_STATS1 = 19300000;
static const size_t OFF_STATS2 = 19300256;
static const size_t OFF_COEF1  = 19300384;
static const size_t OFF_COEF2  = 19300640;
static const size_t OFF_BSUM   = 19300768;   // 128 ints
static const size_t OFF_BOFF   = 19300896;   // 128 ints
static const size_t OFF_BUKHIST= 19301024;   // 256 ints
static const size_t OFF_BUKBASE= 19301280;   // 257 ints (pad to 19301552)
static const size_t OFF_BUKCUR = 19301552;   // 256 ints
static const size_t OFF_PAIRS  = 19301888;   // E int2 = 3.2M ints (8B aligned)
static const size_t ZERO_START = 19200000;   // deg + stats + bukhist
static const size_t ZERO_INTS  = 101280;

#define SCAN_BS 1024
#define SCAN_NB 98                            // ceil(100000/1024)
#define NBUK 256
#define BSHIFT 9                              // 512 nodes per bucket
#define CHUNK 8192

typedef __attribute__((ext_vector_type(8))) short short8;
typedef __attribute__((ext_vector_type(4))) float f32x4;

#define MFMA_16x16x32(a, b, c) __builtin_amdgcn_mfma_f32_16x16x32_bf16(a, b, c, 0, 0, 0)

// f32 -> bf16 (RNE) at bit level
__device__ inline unsigned short f2bf(float f) {
  unsigned u = __builtin_bit_cast(unsigned, f);
  unsigned r = (u + 0x7fffu + ((u >> 16) & 1u)) >> 16;
  return (unsigned short)r;
}
__device__ inline float bf2f(unsigned short h) {
  unsigned u = ((unsigned)h) << 16;
  return __builtin_bit_cast(float, u);
}

// load 8 contiguous f32 (optionally BN+relu transformed), split into hi/lo bf16
template<bool BNIN>
__device__ inline void load_split(const float* __restrict__ p,
                                  const float* __restrict__ ca,
                                  const float* __restrict__ cc,
                                  short8& hi, short8& lo) {
  #pragma unroll
  for (int j = 0; j < 8; ++j) {
    float v = p[j];
    if (BNIN) v = fmaxf(v * ca[j] + cc[j], 0.f);
    unsigned short h = f2bf(v);
    hi[j] = (short)h;
    lo[j] = (short)f2bf(v - bf2f(h));
  }
}

// ---- CSR build A1: deg histogram + bucket histogram (LDS-staged) ----
__global__ __launch_bounds__(256) void bhist_k(const int* __restrict__ ei, int E,
                                               int* __restrict__ deg,
                                               int* __restrict__ bukhist) {
  __shared__ int h[NBUK];
  int tid = threadIdx.x;
  h[tid] = 0;
  __syncthreads();
  int lo = blockIdx.x * CHUNK, hi = min(lo + CHUNK, E);
  for (int e = lo + tid; e < hi; e += 256) {
    int t = ei[E + e];
    if ((unsigned)t < NN) {
      atomicAdd(&deg[t], 1);
      atomicAdd(&h[t >> BSHIFT], 1);
    }
  }
  __syncthreads();
  if (h[tid]) atomicAdd(&bukhist[tid], h[tid]);
}

// ---- CSR build A2: exclusive scan of 256 bucket counts ----
__global__ __launch_bounds__(NBUK) void bukscan_k(const int* __restrict__ bukhist,
                                                  int* __restrict__ bukbase,
                                                  int* __restrict__ bukcur) {
  __shared__ int sh[NBUK];
  int t = threadIdx.x;
  int v = bukhist[t];
  sh[t] = v;
  __syncthreads();
  for (int o = 1; o < NBUK; o <<= 1) {
    int u = (t >= o) ? sh[t - o] : 0;
    __syncthreads();
    sh[t] += u;
    __syncthreads();
  }
  int excl = sh[t] - v;
  bukbase[t] = excl;
  bukcur[t] = excl;
  if (t == NBUK - 1) bukbase[NBUK] = sh[t];
}

// ---- CSR build A3: partition edges into per-bucket pair arrays ----
__global__ __launch_bounds__(256) void bpart_k(const int* __restrict__ ei, int E,
                                               int* __restrict__ bukcur,
                                               int2* __restrict__ pairs) {
  __shared__ int h[NBUK], wb[NBUK], cur[NBUK];
  int tid = threadIdx.x;
  h[tid] = 0; cur[tid] = 0;
  __syncthreads();
  int lo = blockIdx.x * CHUNK, hi = min(lo + CHUNK, E);
  for (int e = lo + tid; e < hi; e += 256) {
    int t = ei[E + e];
    if ((unsigned)t < NN) atomicAdd(&h[t >> BSHIFT], 1);
  }
  __syncthreads();
  wb[tid] = h[tid] ? atomicAdd(&bukcur[tid], h[tid]) : 0;
  __syncthreads();
  for (int e = lo + tid; e < hi; e += 256) {
    int s = ei[e], t = ei[E + e];
    if ((unsigned)t >= NN || (unsigned)s >= NN) continue;
    int b = t >> BSHIFT;
    int off = atomicAdd(&cur[b], 1);
    pairs[wb[b] + off] = make_int2(s, t);
  }
}

// ---- CSR build B: fill adj from buckets (one block per bucket; XCD-local) ----
__global__ __launch_bounds__(256) void bfill_k(const int2* __restrict__ pairs,
                                               const int* __restrict__ bukbase,
                                               int* __restrict__ cursor,
                                               int* __restrict__ adj) {
  int b = blockIdx.x;
  int lo = bukbase[b], hi = bukbase[b + 1];
  for (int p = lo + threadIdx.x; p < hi; p += 256) {
    int2 pr = pairs[p];
    int pos = atomicAdd(&cursor[pr.y], 1);
    adj[pos] = pr.x;
  }
}

// ---- scan phase 1: per-block sums of deg ----
__global__ __launch_bounds__(SCAN_BS) void bsum_k(const int* __restrict__ deg,
                                                  int* __restrict__ bsum) {
  __shared__ int sh[SCAN_BS];
  int t = threadIdx.x;
  int i = blockIdx.x * SCAN_BS + t;
  sh[t] = (i < NN) ? deg[i] : 0;
  __syncthreads();
  for (int o = SCAN_BS / 2; o > 0; o >>= 1) {
    if (t < o) sh[t] += sh[t + o];
    __syncthreads();
  }
  if (t == 0) bsum[blockIdx.x] = sh[0];
}

// ---- scan phase 2: exclusive scan of 98 block sums ----
__global__ __launch_bounds__(128) void bscan_k(const int* __restrict__ bsum,
                                               int* __restrict__ boff) {
  __shared__ int sh[128];
  int t = threadIdx.x;
  int v = (t < SCAN_NB) ? bsum[t] : 0;
  sh[t] = v;
  __syncthreads();
  for (int o = 1; o < 128; o <<= 1) {
    int u = (t >= o) ? sh[t - o] : 0;
    __syncthreads();
    sh[t] += u;
    __syncthreads();
  }
  if (t < SCAN_NB) boff[t] = sh[t] - v;
}

// ---- scan phase 3: block-local inclusive scan + offset -> rowptr/cursor ----
__global__ __launch_bounds__(SCAN_BS) void lscan_k(const int* __restrict__ deg,
                                                   const int* __restrict__ boff,
                                                   int* __restrict__ rowptr,
                                                   int* __restrict__ cursor) {
  __shared__ int sh[SCAN_BS];
  int t = threadIdx.x;
  int i = blockIdx.x * SCAN_BS + t;
  int v = (i < NN) ? deg[i] : 0;
  sh[t] = v;
  __syncthreads();
  for (int o = 1; o < SCAN_BS; o <<= 1) {
    int u = (t >= o) ? sh[t - o] : 0;
    __syncthreads();
    sh[t] += u;
    __syncthreads();
  }
  int incl = sh[t] + boff[blockIdx.x];
  if (i < NN) {
    int excl = incl - v;
    rowptr[i] = excl;
    cursor[i] = excl;
    if (i == NN - 1) rowptr[NN] = incl;
  }
}

// ---- gather-side mean aggregation: K-lane group per node ----
template<int K>
__global__ __launch_bounds__(256) void aggregate_k(const float* __restrict__ x,
                                                   const int* __restrict__ rowptr,
                                                   const int* __restrict__ adj,
                                                   float* __restrict__ agg) {
  constexpr int NPB = 256 / K;
  int lane = threadIdx.x & (K - 1);
  int node = blockIdx.x * NPB + (threadIdx.x / K);
  if (node >= NN) return;
  int s0 = rowptr[node], s1 = rowptr[node + 1];
  float acc0 = 0.f, acc1 = 0.f;
  int e = s0;
  for (; e + 1 < s1; e += 2) {
    int sa = adj[e], sb = adj[e + 1];
    acc0 += x[(size_t)sa * K + lane];
    acc1 += x[(size_t)sb * K + lane];
  }
  if (e < s1) acc0 += x[(size_t)adj[e] * K + lane];
  float inv = 1.0f / fmaxf((float)(s1 - s0), 1.0f);
  agg[(size_t)node * K + lane] = (acc0 + acc1) * inv;
}

// ---- MFMA dense layer (split-bf16, f32-accurate) ----
template<int K, int C, bool SAGE, bool BNIN, bool RELU>
__global__ __launch_bounds__(256) void mfma_dense(const float* __restrict__ inA,
                                                  const float* __restrict__ inB,
                                                  const float* __restrict__ wA,
                                                  const float* __restrict__ wB,
                                                  const float* __restrict__ bias,
                                                  const float* __restrict__ coef,
                                                  float* __restrict__ out) {
  constexpr int KF = K / 32;
  int wid  = threadIdx.x >> 6;
  int lane = threadIdx.x & 63;
  int row0 = blockIdx.x * 64 + wid * 16;
  int r = lane & 15, g = lane >> 4;
  int arow = row0 + r; if (arow > NN - 1) arow = NN - 1;   // clamp tail reads
  int koff = g * 8;

  short8 ahi[KF], alo[KF];
  short8 a2hi[SAGE ? KF : 1], a2lo[SAGE ? KF : 1];
  #pragma unroll
  for (int kf = 0; kf < KF; ++kf) {
    const float* p = inA + (size_t)arow * K + kf * 32 + koff;
    load_split<BNIN>(p, coef + kf * 32 + koff, coef + K + kf * 32 + koff,
                     ahi[kf], alo[kf]);
  }
  if (SAGE) {
    #pragma unroll
    for (int kf = 0; kf < KF; ++kf) {
      const float* p = inB + (size_t)arow * K + kf * 32 + koff;
      load_split<false>(p, nullptr, nullptr, a2hi[kf], a2lo[kf]);
    }
  }

  #pragma unroll 1
  for (int cf = 0; cf < C / 16; ++cf) {
    int col = cf * 16 + r;
    float bv = bias[col];
    f32x4 acc = {bv, bv, bv, bv};
    #pragma unroll
    for (int kf = 0; kf < KF; ++kf) {
      short8 whi, wlo;
      load_split<false>(wA + (size_t)col * K + kf * 32 + koff, nullptr, nullptr, whi, wlo);
      acc = MFMA_16x16x32(ahi[kf], whi, acc);
      acc = MFMA_16x16x32(ahi[kf], wlo, acc);
      acc = MFMA_16x16x32(alo[kf], whi, acc);
      if (SAGE) {
        short8 vhi, vlo;
        load_split<false>(wB + (size_t)col * K + kf * 32 + koff, nullptr, nullptr, vhi, vlo);
        acc = MFMA_16x16x32(a2hi[kf], vhi, acc);
        acc = MFMA_16x16x32(a2hi[kf], vlo, acc);
        acc = MFMA_16x16x32(a2lo[kf], vhi, acc);
      }
    }
    #pragma unroll
    for (int j = 0; j < 4; ++j) {
      int orow = row0 + g * 4 + j;
      if (orow < NN) {
        float v = acc[j];
        if (RELU) v = fmaxf(v, 0.f);
        out[(size_t)orow * C + col] = v;
      }
    }
  }
}

// ---- column sums / sumsq over [NN, C] ----
template<int C>
__global__ __launch_bounds__(256) void colstats(const float* __restrict__ z,
                                                float* __restrict__ stats) {
  const long long total = (long long)NN * C;
  int t = threadIdx.x;
  long long idx = (long long)blockIdx.x * 256 + t;
  long long stride = (long long)gridDim.x * 256;
  float s = 0.f, q = 0.f;
  for (; idx < total; idx += stride) {
    float v = z[idx];
    s += v;
    q += v * v;
  }
  __shared__ float ls[256], lq[256];
  ls[t] = s; lq[t] = q;
  __syncthreads();
  if (t < C) {
    float ss = 0.f, qq = 0.f;
    #pragma unroll
    for (int r = 0; r < 256 / C; ++r) { ss += ls[t + r * C]; qq += lq[t + r * C]; }
    atomicAdd(&stats[t], ss);
    atomicAdd(&stats[C + t], qq);
  }
}

// ---- stats -> affine coefs: y = v*a + c ----
__global__ void bncoef(const float* __restrict__ stats, const float* __restrict__ g,
                       const float* __restrict__ b, float* __restrict__ coef, int C) {
  int j = threadIdx.x;
  if (j >= C) return;
  float mu  = stats[j] * (1.0f / NN);
  float var = stats[C + j] * (1.0f / NN) - mu * mu;
  float a = g[j] * rsqrtf(var + EPS);
  coef[j] = a;
  coef[C + j] = b[j] - mu * a;
}

// ---- final: out[i] = sum_j relu(z2[i][j]*a+c) * fc3w[j] + fc3b ----
__global__ __launch_bounds__(256) void final_k(const float* __restrict__ z2,
                                               const float* __restrict__ coef,
                                               const float* __restrict__ fc3w,
                                               const float* __restrict__ fc3b,
                                               float* __restrict__ out) {
  int t = blockIdx.x * 256 + threadIdx.x;
  int i = t >> 6;
  int j = t & 63;
  if (i >= NN) return;
  float v = z2[(size_t)i * 64 + j];
  float p = fmaxf(v * coef[j] + coef[64 + j], 0.f) * fc3w[j];
  #pragma unroll
  for (int o = 32; o > 0; o >>= 1) p += __shfl_xor(p, o, 64);
  if (j == 0) out[i] = p + fc3b[0];
}

extern "C" void kernel_launch(void* const* d_in, const int* in_sizes, int n_in,
                              void* d_out, int out_size, void* d_ws, size_t ws_size,
                              hipStream_t stream) {
  const float* x     = (const float*)d_in[0];
  const int*   ei    = (const int*)d_in[1];
  const float* w_l1  = (const float*)d_in[2];
  const float* b_l1  = (const float*)d_in[3];
  const float* w_r1  = (const float*)d_in[4];
  const float* w_l2  = (const float*)d_in[5];
  const float* b_l2  = (const float*)d_in[6];
  const float* w_r2  = (const float*)d_in[7];
  const float* fc1_w = (const float*)d_in[8];
  const float* fc1_b = (const float*)d_in[9];
  const float* bn1_g = (const float*)d_in[10];
  const float* bn1_b = (const float*)d_in[11];
  const float* fc2_w = (const float*)d_in[12];
  const float* fc2_b = (const float*)d_in[13];
  const float* bn2_g = (const float*)d_in[14];
  const float* bn2_b = (const float*)d_in[15];
  const float* fc3_w = (const float*)d_in[16];
  const float* fc3_b = (const float*)d_in[17];

  const int E = in_sizes[1] / 2;

  float* ws      = (float*)d_ws;
  int*   rowptr  = (int*)(ws + OFF_ROWPTR);
  int*   adj     = (int*)(ws + OFF_ADJ);
  int*   cursor  = (int*)(ws + OFF_CURSOR);
  float* agg1    = ws + OFF_AGG1;
  float* agg2    = ws + OFF_AGG2;
  float* z1      = ws + OFF_Z1;
  float* z2      = ws + OFF_Z2;
  int*   deg     = (int*)(ws + OFF_DEG);
  float* stats1  = ws + OFF_STATS1;
  float* stats2  = ws + OFF_STATS2;
  float* coef1   = ws + OFF_COEF1;
  float* coef2   = ws + OFF_COEF2;
  int*   bsum    = (int*)(ws + OFF_BSUM);
  int*   boff    = (int*)(ws + OFF_BOFF);
  int*   bukhist = (int*)(ws + OFF_BUKHIST);
  int*   bukbase = (int*)(ws + OFF_BUKBASE);
  int*   bukcur  = (int*)(ws + OFF_BUKCUR);
  int2*  pairs   = (int2*)(ws + OFF_PAIRS);

  float* outv = (float*)d_out;             // [NN]
  float* h1   = outv + NN;                 // [NN,64]
  float* h2   = h1 + (size_t)NN * 64;      // [NN,64]

  hipMemsetAsync(ws + ZERO_START, 0, ZERO_INTS * sizeof(float), stream);

  // CSR build — bucket-partitioned to kill partial-line write amplification
  const int NCH = (E + CHUNK - 1) / CHUNK;
  bhist_k<<<NCH, 256, 0, stream>>>(ei, E, deg, bukhist);
  bsum_k<<<SCAN_NB, SCAN_BS, 0, stream>>>(deg, bsum);
  bscan_k<<<1, 128, 0, stream>>>(bsum, boff);
  lscan_k<<<SCAN_NB, SCAN_BS, 0, stream>>>(deg, boff, rowptr, cursor);
  bukscan_k<<<1, NBUK, 0, stream>>>(bukhist, bukbase, bukcur);
  bpart_k<<<NCH, 256, 0, stream>>>(ei, E, bukcur, pairs);
  bfill_k<<<NBUK, 256, 0, stream>>>(pairs, bukbase, cursor, adj);

  const int MB = (NN + 63) / 64;   // MFMA dense grid: 64 rows per block

  // layer 1
  aggregate_k<32><<<(NN * 32 + 255) / 256, 256, 0, stream>>>(x, rowptr, adj, agg1);
  mfma_dense<32, 64, true, false, true>
      <<<MB, 256, 0, stream>>>(agg1, x, w_l1, w_r1, b_l1, nullptr, h1);

  // layer 2
  aggregate_k<64><<<(NN * 64 + 255) / 256, 256, 0, stream>>>(h1, rowptr, adj, agg2);
  mfma_dense<64, 64, true, false, true>
      <<<MB, 256, 0, stream>>>(agg2, h1, w_l2, w_r2, b_l2, nullptr, h2);

  // fc1 -> z1 (raw, pre-BN)
  mfma_dense<64, 128, false, false, false>
      <<<MB, 256, 0, stream>>>(h2, nullptr, fc1_w, nullptr, fc1_b, nullptr, z1);
  colstats<128><<<512, 256, 0, stream>>>(z1, stats1);
  bncoef<<<1, 128, 0, stream>>>(stats1, bn1_g, bn1_b, coef1, 128);

  // fc2 with fused bn1+relu on input -> z2 (raw, pre-BN)
  mfma_dense<128, 64, false, true, false>
      <<<MB, 256, 0, stream>>>(z1, nullptr, fc2_w, nullptr, fc2_b, coef1, z2);
  colstats<64><<<512, 256, 0, stream>>>(z2, stats2);
  bncoef<<<1, 64, 0, stream>>>(stats2, bn2_g, bn2_b, coef2, 64);

  // bn2 + relu + fc3 fused
  final_k<<<(NN * 64 + 255) / 256, 256, 0, stream>>>(z2, coef2, fc3_w, fc3_b, outv);
}

// Round 8
// 462.059 us; speedup vs baseline: 7.8686x; 1.0830x over previous
//
#include <hip/hip_runtime.h>

#define NN 100000
#define EPS 1e-5f

// ---- workspace layout (4-byte units) ----
static const size_t OFF_ROWPTR = 0;
static const size_t OFF_ADJ    = 100004;
static const size_t OFF_CURSOR = 1700008;
static const size_t OFF_AGG1   = 1800008;
static const size_t OFF_AGG2   = 5000008;
static const size_t OFF_XB     = 5000008;    // aliases agg2 head: xb dead before agg2 written
static const size_t OFF_Z1     = 0;          // aliases CSR+agg (dead by fc1)
static const size_t OFF_Z2     = 12800000;
static const size_t OFF_DEG    = 19200000;
static const size_t OFF_STATS1 = 19300000;
static const size_t OFF_STATS2 = 19300256;
static const size_t OFF_COEF1  = 19300384;
static const size_t OFF_COEF2  = 19300640;
static const size_t OFF_BSUM   = 19300768;   // 128 ints
static const size_t OFF_BOFF   = 19300896;   // 128 ints
static const size_t OFF_BUKHIST= 19301024;   // 256 ints
static const size_t OFF_BUKBASE= 19301280;   // 257 ints (pad to 19301552)
static const size_t OFF_BUKCUR = 19301552;   // 256 ints
static const size_t OFF_PAIRS  = 19301888;   // E int2 = 3.2M ints
static const size_t OFF_H1B    = 19301888;   // aliases pairs: h1b written after bfill done
static const size_t ZERO_START = 19200000;   // deg + stats + bukhist
static const size_t ZERO_INTS  = 101280;

#define SCAN_BS 1024
#define SCAN_NB 98                            // ceil(100000/1024)
#define NBUK 256
#define BSHIFT 9                              // 512 nodes per bucket
#define CHUNK 8192

typedef __attribute__((ext_vector_type(8))) short short8;
typedef __attribute__((ext_vector_type(4))) float f32x4;

#define MFMA_16x16x32(a, b, c) __builtin_amdgcn_mfma_f32_16x16x32_bf16(a, b, c, 0, 0, 0)

// f32 -> bf16 (RNE) at bit level
__device__ inline unsigned short f2bf(float f) {
  unsigned u = __builtin_bit_cast(unsigned, f);
  unsigned r = (u + 0x7fffu + ((u >> 16) & 1u)) >> 16;
  return (unsigned short)r;
}
__device__ inline float bf2f(unsigned short h) {
  unsigned u = ((unsigned)h) << 16;
  return __builtin_bit_cast(float, u);
}

// load 8 contiguous f32 (optionally BN+relu transformed), split into hi/lo bf16
template<bool BNIN>
__device__ inline void load_split(const float* __restrict__ p,
                                  const float* __restrict__ ca,
                                  const float* __restrict__ cc,
                                  short8& hi, short8& lo) {
  #pragma unroll
  for (int j = 0; j < 8; ++j) {
    float v = p[j];
    if (BNIN) v = fmaxf(v * ca[j] + cc[j], 0.f);
    unsigned short h = f2bf(v);
    hi[j] = (short)h;
    lo[j] = (short)f2bf(v - bf2f(h));
  }
}

// ---- convert f32 plane -> bf16 plane (for cheap gathers) ----
__global__ __launch_bounds__(256) void cvt_bf_k(const float* __restrict__ in,
                                                unsigned short* __restrict__ out,
                                                int n8) {
  int t = blockIdx.x * 256 + threadIdx.x;
  if (t >= n8) return;
  const float4* p = (const float4*)(in + (size_t)t * 8);
  float4 a = p[0], b = p[1];
  ushort4 u0, u1;
  u0.x = f2bf(a.x); u0.y = f2bf(a.y); u0.z = f2bf(a.z); u0.w = f2bf(a.w);
  u1.x = f2bf(b.x); u1.y = f2bf(b.y); u1.z = f2bf(b.z); u1.w = f2bf(b.w);
  ((ushort4*)(out + (size_t)t * 8))[0] = u0;
  ((ushort4*)(out + (size_t)t * 8))[1] = u1;
}

// ---- CSR build A1: deg histogram + bucket histogram (LDS-staged) ----
__global__ __launch_bounds__(256) void bhist_k(const int* __restrict__ ei, int E,
                                               int* __restrict__ deg,
                                               int* __restrict__ bukhist) {
  __shared__ int h[NBUK];
  int tid = threadIdx.x;
  h[tid] = 0;
  __syncthreads();
  int lo = blockIdx.x * CHUNK, hi = min(lo + CHUNK, E);
  for (int e = lo + tid; e < hi; e += 256) {
    int t = ei[E + e];
    if ((unsigned)t < NN) {
      atomicAdd(&deg[t], 1);
      atomicAdd(&h[t >> BSHIFT], 1);
    }
  }
  __syncthreads();
  if (h[tid]) atomicAdd(&bukhist[tid], h[tid]);
}

// ---- CSR build A2: exclusive scan of 256 bucket counts ----
__global__ __launch_bounds__(NBUK) void bukscan_k(const int* __restrict__ bukhist,
                                                  int* __restrict__ bukbase,
                                                  int* __restrict__ bukcur) {
  __shared__ int sh[NBUK];
  int t = threadIdx.x;
  int v = bukhist[t];
  sh[t] = v;
  __syncthreads();
  for (int o = 1; o < NBUK; o <<= 1) {
    int u = (t >= o) ? sh[t - o] : 0;
    __syncthreads();
    sh[t] += u;
    __syncthreads();
  }
  int excl = sh[t] - v;
  bukbase[t] = excl;
  bukcur[t] = excl;
  if (t == NBUK - 1) bukbase[NBUK] = sh[t];
}

// ---- CSR build A3: partition edges into per-bucket pair arrays ----
__global__ __launch_bounds__(256) void bpart_k(const int* __restrict__ ei, int E,
                                               int* __restrict__ bukcur,
                                               int2* __restrict__ pairs) {
  __shared__ int h[NBUK], wb[NBUK], cur[NBUK];
  int tid = threadIdx.x;
  h[tid] = 0; cur[tid] = 0;
  __syncthreads();
  int lo = blockIdx.x * CHUNK, hi = min(lo + CHUNK, E);
  for (int e = lo + tid; e < hi; e += 256) {
    int t = ei[E + e];
    if ((unsigned)t < NN) atomicAdd(&h[t >> BSHIFT], 1);
  }
  __syncthreads();
  wb[tid] = h[tid] ? atomicAdd(&bukcur[tid], h[tid]) : 0;
  __syncthreads();
  for (int e = lo + tid; e < hi; e += 256) {
    int s = ei[e], t = ei[E + e];
    if ((unsigned)t >= NN || (unsigned)s >= NN) continue;
    int b = t >> BSHIFT;
    int off = atomicAdd(&cur[b], 1);
    pairs[wb[b] + off] = make_int2(s, t);
  }
}

// ---- CSR build B: fill adj from buckets (one block per bucket; XCD-local) ----
__global__ __launch_bounds__(256) void bfill_k(const int2* __restrict__ pairs,
                                               const int* __restrict__ bukbase,
                                               int* __restrict__ cursor,
                                               int* __restrict__ adj) {
  int b = blockIdx.x;
  int lo = bukbase[b], hi = bukbase[b + 1];
  for (int p = lo + threadIdx.x; p < hi; p += 256) {
    int2 pr = pairs[p];
    int pos = atomicAdd(&cursor[pr.y], 1);
    adj[pos] = pr.x;
  }
}

// ---- scan phase 1: per-block sums of deg ----
__global__ __launch_bounds__(SCAN_BS) void bsum_k(const int* __restrict__ deg,
                                                  int* __restrict__ bsum) {
  __shared__ int sh[SCAN_BS];
  int t = threadIdx.x;
  int i = blockIdx.x * SCAN_BS + t;
  sh[t] = (i < NN) ? deg[i] : 0;
  __syncthreads();
  for (int o = SCAN_BS / 2; o > 0; o >>= 1) {
    if (t < o) sh[t] += sh[t + o];
    __syncthreads();
  }
  if (t == 0) bsum[blockIdx.x] = sh[0];
}

// ---- scan phase 2: exclusive scan of 98 block sums ----
__global__ __launch_bounds__(128) void bscan_k(const int* __restrict__ bsum,
                                               int* __restrict__ boff) {
  __shared__ int sh[128];
  int t = threadIdx.x;
  int v = (t < SCAN_NB) ? bsum[t] : 0;
  sh[t] = v;
  __syncthreads();
  for (int o = 1; o < 128; o <<= 1) {
    int u = (t >= o) ? sh[t - o] : 0;
    __syncthreads();
    sh[t] += u;
    __syncthreads();
  }
  if (t < SCAN_NB) boff[t] = sh[t] - v;
}

// ---- scan phase 3: block-local inclusive scan + offset -> rowptr/cursor ----
__global__ __launch_bounds__(SCAN_BS) void lscan_k(const int* __restrict__ deg,
                                                   const int* __restrict__ boff,
                                                   int* __restrict__ rowptr,
                                                   int* __restrict__ cursor) {
  __shared__ int sh[SCAN_BS];
  int t = threadIdx.x;
  int i = blockIdx.x * SCAN_BS + t;
  int v = (i < NN) ? deg[i] : 0;
  sh[t] = v;
  __syncthreads();
  for (int o = 1; o < SCAN_BS; o <<= 1) {
    int u = (t >= o) ? sh[t - o] : 0;
    __syncthreads();
    sh[t] += u;
    __syncthreads();
  }
  int incl = sh[t] + boff[blockIdx.x];
  if (i < NN) {
    int excl = incl - v;
    rowptr[i] = excl;
    cursor[i] = excl;
    if (i == NN - 1) rowptr[NN] = incl;
  }
}

// ---- gather-side mean aggregation over bf16 plane: K-lane group per node ----
template<int K>
__global__ __launch_bounds__(256) void aggregate_bf(const unsigned short* __restrict__ xb,
                                                    const int* __restrict__ rowptr,
                                                    const int* __restrict__ adj,
                                                    float* __restrict__ agg) {
  constexpr int NPB = 256 / K;
  int lane = threadIdx.x & (K - 1);
  int node = blockIdx.x * NPB + (threadIdx.x / K);
  if (node >= NN) return;
  int s0 = rowptr[node], s1 = rowptr[node + 1];
  float a0 = 0.f, a1 = 0.f, a2 = 0.f, a3 = 0.f;
  int e = s0;
  for (; e + 3 < s1; e += 4) {                // 4 independent chains
    int i0 = adj[e], i1 = adj[e + 1], i2 = adj[e + 2], i3 = adj[e + 3];
    a0 += bf2f(xb[(size_t)i0 * K + lane]);
    a1 += bf2f(xb[(size_t)i1 * K + lane]);
    a2 += bf2f(xb[(size_t)i2 * K + lane]);
    a3 += bf2f(xb[(size_t)i3 * K + lane]);
  }
  for (; e < s1; ++e) a0 += bf2f(xb[(size_t)adj[e] * K + lane]);
  float inv = 1.0f / fmaxf((float)(s1 - s0), 1.0f);
  agg[(size_t)node * K + lane] = (a0 + a1 + a2 + a3) * inv;
}

// ---- MFMA dense layer (split-bf16, f32-accurate) ----
// Optionally also emits a bf16 copy of the output plane (for cheap gathers).
template<int K, int C, bool SAGE, bool BNIN, bool RELU, bool BFOUT>
__global__ __launch_bounds__(256) void mfma_dense(const float* __restrict__ inA,
                                                  const float* __restrict__ inB,
                                                  const float* __restrict__ wA,
                                                  const float* __restrict__ wB,
                                                  const float* __restrict__ bias,
                                                  const float* __restrict__ coef,
                                                  float* __restrict__ out,
                                                  unsigned short* __restrict__ outb) {
  constexpr int KF = K / 32;
  int wid  = threadIdx.x >> 6;
  int lane = threadIdx.x & 63;
  int row0 = blockIdx.x * 64 + wid * 16;
  int r = lane & 15, g = lane >> 4;
  int arow = row0 + r; if (arow > NN - 1) arow = NN - 1;   // clamp tail reads
  int koff = g * 8;

  short8 ahi[KF], alo[KF];
  short8 a2hi[SAGE ? KF : 1], a2lo[SAGE ? KF : 1];
  #pragma unroll
  for (int kf = 0; kf < KF; ++kf) {
    const float* p = inA + (size_t)arow * K + kf * 32 + koff;
    load_split<BNIN>(p, coef + kf * 32 + koff, coef + K + kf * 32 + koff,
                     ahi[kf], alo[kf]);
  }
  if (SAGE) {
    #pragma unroll
    for (int kf = 0; kf < KF; ++kf) {
      const float* p = inB + (size_t)arow * K + kf * 32 + koff;
      load_split<false>(p, nullptr, nullptr, a2hi[kf], a2lo[kf]);
    }
  }

  #pragma unroll 1
  for (int cf = 0; cf < C / 16; ++cf) {
    int col = cf * 16 + r;
    float bv = bias[col];
    f32x4 acc = {bv, bv, bv, bv};
    #pragma unroll
    for (int kf = 0; kf < KF; ++kf) {
      short8 whi, wlo;
      load_split<false>(wA + (size_t)col * K + kf * 32 + koff, nullptr, nullptr, whi, wlo);
      acc = MFMA_16x16x32(ahi[kf], whi, acc);
      acc = MFMA_16x16x32(ahi[kf], wlo, acc);
      acc = MFMA_16x16x32(alo[kf], whi, acc);
      if (SAGE) {
        short8 vhi, vlo;
        load_split<false>(wB + (size_t)col * K + kf * 32 + koff, nullptr, nullptr, vhi, vlo);
        acc = MFMA_16x16x32(a2hi[kf], vhi, acc);
        acc = MFMA_16x16x32(a2hi[kf], vlo, acc);
        acc = MFMA_16x16x32(a2lo[kf], vhi, acc);
      }
    }
    #pragma unroll
    for (int j = 0; j < 4; ++j) {
      int orow = row0 + g * 4 + j;
      if (orow < NN) {
        float v = acc[j];
        if (RELU) v = fmaxf(v, 0.f);
        out[(size_t)orow * C + col] = v;
        if (BFOUT) outb[(size_t)orow * C + col] = f2bf(v);
      }
    }
  }
}

// ---- column sums / sumsq over [NN, C] ----
template<int C>
__global__ __launch_bounds__(256) void colstats(const float* __restrict__ z,
                                                float* __restrict__ stats) {
  const long long total = (long long)NN * C;
  int t = threadIdx.x;
  long long idx = (long long)blockIdx.x * 256 + t;
  long long stride = (long long)gridDim.x * 256;
  float s = 0.f, q = 0.f;
  for (; idx < total; idx += stride) {
    float v = z[idx];
    s += v;
    q += v * v;
  }
  __shared__ float ls[256], lq[256];
  ls[t] = s; lq[t] = q;
  __syncthreads();
  if (t < C) {
    float ss = 0.f, qq = 0.f;
    #pragma unroll
    for (int r = 0; r < 256 / C; ++r) { ss += ls[t + r * C]; qq += lq[t + r * C]; }
    atomicAdd(&stats[t], ss);
    atomicAdd(&stats[C + t], qq);
  }
}

// ---- stats -> affine coefs: y = v*a + c ----
__global__ void bncoef(const float* __restrict__ stats, const float* __restrict__ g,
                       const float* __restrict__ b, float* __restrict__ coef, int C) {
  int j = threadIdx.x;
  if (j >= C) return;
  float mu  = stats[j] * (1.0f / NN);
  float var = stats[C + j] * (1.0f / NN) - mu * mu;
  float a = g[j] * rsqrtf(var + EPS);
  coef[j] = a;
  coef[C + j] = b[j] - mu * a;
}

// ---- final: out[i] = sum_j relu(z2[i][j]*a+c) * fc3w[j] + fc3b ----
__global__ __launch_bounds__(256) void final_k(const float* __restrict__ z2,
                                               const float* __restrict__ coef,
                                               const float* __restrict__ fc3w,
                                               const float* __restrict__ fc3b,
                                               float* __restrict__ out) {
  int t = blockIdx.x * 256 + threadIdx.x;
  int i = t >> 6;
  int j = t & 63;
  if (i >= NN) return;
  float v = z2[(size_t)i * 64 + j];
  float p = fmaxf(v * coef[j] + coef[64 + j], 0.f) * fc3w[j];
  #pragma unroll
  for (int o = 32; o > 0; o >>= 1) p += __shfl_xor(p, o, 64);
  if (j == 0) out[i] = p + fc3b[0];
}

extern "C" void kernel_launch(void* const* d_in, const int* in_sizes, int n_in,
                              void* d_out, int out_size, void* d_ws, size_t ws_size,
                              hipStream_t stream) {
  const float* x     = (const float*)d_in[0];
  const int*   ei    = (const int*)d_in[1];
  const float* w_l1  = (const float*)d_in[2];
  const float* b_l1  = (const float*)d_in[3];
  const float* w_r1  = (const float*)d_in[4];
  const float* w_l2  = (const float*)d_in[5];
  const float* b_l2  = (const float*)d_in[6];
  const float* w_r2  = (const float*)d_in[7];
  const float* fc1_w = (const float*)d_in[8];
  const float* fc1_b = (const float*)d_in[9];
  const float* bn1_g = (const float*)d_in[10];
  const float* bn1_b = (const float*)d_in[11];
  const float* fc2_w = (const float*)d_in[12];
  const float* fc2_b = (const float*)d_in[13];
  const float* bn2_g = (const float*)d_in[14];
  const float* bn2_b = (const float*)d_in[15];
  const float* fc3_w = (const float*)d_in[16];
  const float* fc3_b = (const float*)d_in[17];

  const int E = in_sizes[1] / 2;

  float* ws      = (float*)d_ws;
  int*   rowptr  = (int*)(ws + OFF_ROWPTR);
  int*   adj     = (int*)(ws + OFF_ADJ);
  int*   cursor  = (int*)(ws + OFF_CURSOR);
  float* agg1    = ws + OFF_AGG1;
  float* agg2    = ws + OFF_AGG2;
  unsigned short* xb  = (unsigned short*)(ws + OFF_XB);
  unsigned short* h1b = (unsigned short*)(ws + OFF_H1B);
  float* z1      = ws + OFF_Z1;
  float* z2      = ws + OFF_Z2;
  int*   deg     = (int*)(ws + OFF_DEG);
  float* stats1  = ws + OFF_STATS1;
  float* stats2  = ws + OFF_STATS2;
  float* coef1   = ws + OFF_COEF1;
  float* coef2   = ws + OFF_COEF2;
  int*   bsum    = (int*)(ws + OFF_BSUM);
  int*   boff    = (int*)(ws + OFF_BOFF);
  int*   bukhist = (int*)(ws + OFF_BUKHIST);
  int*   bukbase = (int*)(ws + OFF_BUKBASE);
  int*   bukcur  = (int*)(ws + OFF_BUKCUR);
  int2*  pairs   = (int2*)(ws + OFF_PAIRS);

  float* outv = (float*)d_out;             // [NN]
  float* h1   = outv + NN;                 // [NN,64]
  float* h2   = h1 + (size_t)NN * 64;      // [NN,64]

  hipMemsetAsync(ws + ZERO_START, 0, ZERO_INTS * sizeof(float), stream);

  // bf16 copy of x for cheap gathering (xb dead before agg2 is written)
  cvt_bf_k<<<(NN * 32 / 8 + 255) / 256, 256, 0, stream>>>(x, xb, NN * 32 / 8);

  // CSR build — bucket-partitioned to kill partial-line write amplification
  const int NCH = (E + CHUNK - 1) / CHUNK;
  bhist_k<<<NCH, 256, 0, stream>>>(ei, E, deg, bukhist);
  bsum_k<<<SCAN_NB, SCAN_BS, 0, stream>>>(deg, bsum);
  bscan_k<<<1, 128, 0, stream>>>(bsum, boff);
  lscan_k<<<SCAN_NB, SCAN_BS, 0, stream>>>(deg, boff, rowptr, cursor);
  bukscan_k<<<1, NBUK, 0, stream>>>(bukhist, bukbase, bukcur);
  bpart_k<<<NCH, 256, 0, stream>>>(ei, E, bukcur, pairs);
  bfill_k<<<NBUK, 256, 0, stream>>>(pairs, bukbase, cursor, adj);

  const int MB = (NN + 63) / 64;   // MFMA dense grid: 64 rows per block

  // layer 1 (gather bf16 x; dense emits h1 f32 + h1b bf16 for next gather)
  aggregate_bf<32><<<(NN * 32 + 255) / 256, 256, 0, stream>>>(xb, rowptr, adj, agg1);
  mfma_dense<32, 64, true, false, true, true>
      <<<MB, 256, 0, stream>>>(agg1, x, w_l1, w_r1, b_l1, nullptr, h1, h1b);

  // layer 2
  aggregate_bf<64><<<(NN * 64 + 255) / 256, 256, 0, stream>>>(h1b, rowptr, adj, agg2);
  mfma_dense<64, 64, true, false, true, false>
      <<<MB, 256, 0, stream>>>(agg2, h1, w_l2, w_r2, b_l2, nullptr, h2, nullptr);

  // fc1 -> z1 (raw, pre-BN)
  mfma_dense<64, 128, false, false, false, false>
      <<<MB, 256, 0, stream>>>(h2, nullptr, fc1_w, nullptr, fc1_b, nullptr, z1, nullptr);
  colstats<128><<<512, 256, 0, stream>>>(z1, stats1);
  bncoef<<<1, 128, 0, stream>>>(stats1, bn1_g, bn1_b, coef1, 128);

  // fc2 with fused bn1+relu on input -> z2 (raw, pre-BN)
  mfma_dense<128, 64, false, true, false, false>
      <<<MB, 256, 0, stream>>>(z1, nullptr, fc2_w, nullptr, fc2_b, coef1, z2, nullptr);
  colstats<64><<<512, 256, 0, stream>>>(z2, stats2);
  bncoef<<<1, 64, 0, stream>>>(stats2, bn2_g, bn2_b, coef2, 64);

  // bn2 + relu + fc3 fused
  final_k<<<(NN * 64 + 255) / 256, 256, 0, stream>>>(z2, coef2, fc3_w, fc3_b, outv);
}

// Round 9
// 381.921 us; speedup vs baseline: 9.5196x; 1.2098x over previous
//
#include <hip/hip_runtime.h>

#define NN 100000
#define EPS 1e-5f

// ---- workspace layout (4-byte units) ----
static const size_t OFF_ROWPTR = 0;
static const size_t OFF_ADJ    = 100004;
static const size_t OFF_AGG1   = 1800008;
static const size_t OFF_AGG2   = 5000008;
static const size_t OFF_XB     = 5000008;    // aliases agg2 head: xb dead before agg2 written
static const size_t OFF_Z1     = 0;          // aliases CSR+agg (dead by fc1)
static const size_t OFF_Z2     = 12800000;
static const size_t OFF_STATS1 = 19300000;
static const size_t OFF_STATS2 = 19300256;
static const size_t OFF_COEF1  = 19300384;
static const size_t OFF_COEF2  = 19300640;
static const size_t OFF_BUKHIST= 19301024;   // 256 ints
static const size_t OFF_BUKBASE= 19301280;   // 257 ints (pad to 19301552)
static const size_t OFF_BUKCUR = 19301552;   // 256 ints
static const size_t OFF_PAIRS  = 19301888;   // E int2 = 3.2M ints
static const size_t OFF_H1B    = 19301888;   // aliases pairs: h1b written after bfill done
static const size_t ZERO_START = 19300000;   // stats + bukhist
static const size_t ZERO_INTS  = 1280;

#define NBUK 256
#define BSHIFT 9                              // 512 nodes per bucket
#define CHUNK 8192

typedef __attribute__((ext_vector_type(8))) short short8;
typedef __attribute__((ext_vector_type(4))) float f32x4;

#define MFMA_16x16x32(a, b, c) __builtin_amdgcn_mfma_f32_16x16x32_bf16(a, b, c, 0, 0, 0)

// f32 -> bf16 (RNE) at bit level
__device__ inline unsigned short f2bf(float f) {
  unsigned u = __builtin_bit_cast(unsigned, f);
  unsigned r = (u + 0x7fffu + ((u >> 16) & 1u)) >> 16;
  return (unsigned short)r;
}
__device__ inline float bf2f(unsigned short h) {
  unsigned u = ((unsigned)h) << 16;
  return __builtin_bit_cast(float, u);
}

// load 8 contiguous f32 (optionally BN+relu transformed), split into hi/lo bf16
template<bool BNIN>
__device__ inline void load_split(const float* __restrict__ p,
                                  const float* __restrict__ ca,
                                  const float* __restrict__ cc,
                                  short8& hi, short8& lo) {
  #pragma unroll
  for (int j = 0; j < 8; ++j) {
    float v = p[j];
    if (BNIN) v = fmaxf(v * ca[j] + cc[j], 0.f);
    unsigned short h = f2bf(v);
    hi[j] = (short)h;
    lo[j] = (short)f2bf(v - bf2f(h));
  }
}

// ---- convert f32 plane -> bf16 plane (for cheap gathers) ----
__global__ __launch_bounds__(256) void cvt_bf_k(const float* __restrict__ in,
                                                unsigned short* __restrict__ out,
                                                int n8) {
  int t = blockIdx.x * 256 + threadIdx.x;
  if (t >= n8) return;
  const float4* p = (const float4*)(in + (size_t)t * 8);
  float4 a = p[0], b = p[1];
  ushort4 u0, u1;
  u0.x = f2bf(a.x); u0.y = f2bf(a.y); u0.z = f2bf(a.z); u0.w = f2bf(a.w);
  u1.x = f2bf(b.x); u1.y = f2bf(b.y); u1.z = f2bf(b.z); u1.w = f2bf(b.w);
  ((ushort4*)(out + (size_t)t * 8))[0] = u0;
  ((ushort4*)(out + (size_t)t * 8))[1] = u1;
}

// ---- CSR build A1: bucket histogram only (LDS-staged; no global deg!) ----
__global__ __launch_bounds__(256) void bhist_k(const int* __restrict__ ei, int E,
                                               int* __restrict__ bukhist) {
  __shared__ int h[NBUK];
  int tid = threadIdx.x;
  h[tid] = 0;
  __syncthreads();
  int lo = blockIdx.x * CHUNK, hi = min(lo + CHUNK, E);
  for (int e = lo + tid; e < hi; e += 256) {
    int t = ei[E + e];
    if ((unsigned)t < NN) atomicAdd(&h[t >> BSHIFT], 1);
  }
  __syncthreads();
  if (h[tid]) atomicAdd(&bukhist[tid], h[tid]);
}

// ---- CSR build A2: exclusive scan of 256 bucket counts ----
__global__ __launch_bounds__(NBUK) void bukscan_k(const int* __restrict__ bukhist,
                                                  int* __restrict__ bukbase,
                                                  int* __restrict__ bukcur) {
  __shared__ int sh[NBUK];
  int t = threadIdx.x;
  int v = bukhist[t];
  sh[t] = v;
  __syncthreads();
  for (int o = 1; o < NBUK; o <<= 1) {
    int u = (t >= o) ? sh[t - o] : 0;
    __syncthreads();
    sh[t] += u;
    __syncthreads();
  }
  int excl = sh[t] - v;
  bukbase[t] = excl;
  bukcur[t] = excl;
  if (t == NBUK - 1) bukbase[NBUK] = sh[t];
}

// ---- CSR build A3: partition edges into per-bucket pair arrays ----
__global__ __launch_bounds__(256) void bpart_k(const int* __restrict__ ei, int E,
                                               int* __restrict__ bukcur,
                                               int2* __restrict__ pairs) {
  __shared__ int h[NBUK], wb[NBUK], cur[NBUK];
  int tid = threadIdx.x;
  h[tid] = 0; cur[tid] = 0;
  __syncthreads();
  int lo = blockIdx.x * CHUNK, hi = min(lo + CHUNK, E);
  for (int e = lo + tid; e < hi; e += 256) {
    int t = ei[E + e];
    if ((unsigned)t < NN) atomicAdd(&h[t >> BSHIFT], 1);
  }
  __syncthreads();
  wb[tid] = h[tid] ? atomicAdd(&bukcur[tid], h[tid]) : 0;
  __syncthreads();
  for (int e = lo + tid; e < hi; e += 256) {
    int s = ei[e], t = ei[E + e];
    if ((unsigned)t >= NN || (unsigned)s >= NN) continue;
    int b = t >> BSHIFT;
    int off = atomicAdd(&cur[b], 1);
    pairs[wb[b] + off] = make_int2(s, t);
  }
}

// ---- CSR build B: per-bucket LDS histogram + scan + fill (zero global atomics) ----
// One block per bucket. Bucket b covers nodes [b*512, b*512+512). Writes that
// window of rowptr (incl. rowptr[NN]) and its adj segment via LDS cursors.
__global__ __launch_bounds__(256) void bfill_k(const int2* __restrict__ pairs,
                                               const int* __restrict__ bukbase,
                                               int* __restrict__ rowptr,
                                               int* __restrict__ adj) {
  __shared__ int d[512];
  __shared__ int part[256];
  int b = blockIdx.x;
  int t = threadIdx.x;
  int base = bukbase[b], hi = bukbase[b + 1];
  d[t] = 0; d[t + 256] = 0;
  __syncthreads();
  // local histogram
  for (int p = base + t; p < hi; p += 256)
    atomicAdd(&d[pairs[p].y & 511], 1);
  __syncthreads();
  // exclusive scan of 512 entries (2 per thread)
  int d0 = d[2 * t], d1 = d[2 * t + 1];
  part[t] = d0 + d1;
  __syncthreads();
  for (int o = 1; o < 256; o <<= 1) {
    int u = (t >= o) ? part[t - o] : 0;
    __syncthreads();
    part[t] += u;
    __syncthreads();
  }
  int e0 = (t > 0) ? part[t - 1] : 0;
  int e1 = e0 + d0;
  d[2 * t] = e0;            // becomes LDS cursor
  d[2 * t + 1] = e1;
  int n0 = (b << BSHIFT) + 2 * t;
  if (n0 <= NN) rowptr[n0] = base + e0;
  if (n0 + 1 <= NN) rowptr[n0 + 1] = base + e1;
  __syncthreads();
  // fill via LDS cursors
  for (int p = base + t; p < hi; p += 256) {
    int2 pr = pairs[p];
    int pos = atomicAdd(&d[pr.y & 511], 1);
    adj[base + pos] = pr.x;
  }
}

// ---- gather-side mean aggregation over bf16 plane: K-lane group per node ----
template<int K>
__global__ __launch_bounds__(256) void aggregate_bf(const unsigned short* __restrict__ xb,
                                                    const int* __restrict__ rowptr,
                                                    const int* __restrict__ adj,
                                                    float* __restrict__ agg) {
  constexpr int NPB = 256 / K;
  int lane = threadIdx.x & (K - 1);
  int node = blockIdx.x * NPB + (threadIdx.x / K);
  if (node >= NN) return;
  int s0 = rowptr[node], s1 = rowptr[node + 1];
  float a0 = 0.f, a1 = 0.f, a2 = 0.f, a3 = 0.f;
  int e = s0;
  for (; e + 3 < s1; e += 4) {                // 4 independent chains
    int i0 = adj[e], i1 = adj[e + 1], i2 = adj[e + 2], i3 = adj[e + 3];
    a0 += bf2f(xb[(size_t)i0 * K + lane]);
    a1 += bf2f(xb[(size_t)i1 * K + lane]);
    a2 += bf2f(xb[(size_t)i2 * K + lane]);
    a3 += bf2f(xb[(size_t)i3 * K + lane]);
  }
  for (; e < s1; ++e) a0 += bf2f(xb[(size_t)adj[e] * K + lane]);
  float inv = 1.0f / fmaxf((float)(s1 - s0), 1.0f);
  agg[(size_t)node * K + lane] = (a0 + a1 + a2 + a3) * inv;
}

// ---- MFMA dense layer (split-bf16, f32-accurate) ----
// Optionally also emits a bf16 copy of the output plane (for cheap gathers).
template<int K, int C, bool SAGE, bool BNIN, bool RELU, bool BFOUT>
__global__ __launch_bounds__(256) void mfma_dense(const float* __restrict__ inA,
                                                  const float* __restrict__ inB,
                                                  const float* __restrict__ wA,
                                                  const float* __restrict__ wB,
                                                  const float* __restrict__ bias,
                                                  const float* __restrict__ coef,
                                                  float* __restrict__ out,
                                                  unsigned short* __restrict__ outb) {
  constexpr int KF = K / 32;
  int wid  = threadIdx.x >> 6;
  int lane = threadIdx.x & 63;
  int row0 = blockIdx.x * 64 + wid * 16;
  int r = lane & 15, g = lane >> 4;
  int arow = row0 + r; if (arow > NN - 1) arow = NN - 1;   // clamp tail reads
  int koff = g * 8;

  short8 ahi[KF], alo[KF];
  short8 a2hi[SAGE ? KF : 1], a2lo[SAGE ? KF : 1];
  #pragma unroll
  for (int kf = 0; kf < KF; ++kf) {
    const float* p = inA + (size_t)arow * K + kf * 32 + koff;
    load_split<BNIN>(p, coef + kf * 32 + koff, coef + K + kf * 32 + koff,
                     ahi[kf], alo[kf]);
  }
  if (SAGE) {
    #pragma unroll
    for (int kf = 0; kf < KF; ++kf) {
      const float* p = inB + (size_t)arow * K + kf * 32 + koff;
      load_split<false>(p, nullptr, nullptr, a2hi[kf], a2lo[kf]);
    }
  }

  #pragma unroll 1
  for (int cf = 0; cf < C / 16; ++cf) {
    int col = cf * 16 + r;
    float bv = bias[col];
    f32x4 acc = {bv, bv, bv, bv};
    #pragma unroll
    for (int kf = 0; kf < KF; ++kf) {
      short8 whi, wlo;
      load_split<false>(wA + (size_t)col * K + kf * 32 + koff, nullptr, nullptr, whi, wlo);
      acc = MFMA_16x16x32(ahi[kf], whi, acc);
      acc = MFMA_16x16x32(ahi[kf], wlo, acc);
      acc = MFMA_16x16x32(alo[kf], whi, acc);
      if (SAGE) {
        short8 vhi, vlo;
        load_split<false>(wB + (size_t)col * K + kf * 32 + koff, nullptr, nullptr, vhi, vlo);
        acc = MFMA_16x16x32(a2hi[kf], vhi, acc);
        acc = MFMA_16x16x32(a2hi[kf], vlo, acc);
        acc = MFMA_16x16x32(a2lo[kf], vhi, acc);
      }
    }
    #pragma unroll
    for (int j = 0; j < 4; ++j) {
      int orow = row0 + g * 4 + j;
      if (orow < NN) {
        float v = acc[j];
        if (RELU) v = fmaxf(v, 0.f);
        out[(size_t)orow * C + col] = v;
        if (BFOUT) outb[(size_t)orow * C + col] = f2bf(v);
      }
    }
  }
}

// ---- column sums / sumsq over [NN, C] ----
template<int C>
__global__ __launch_bounds__(256) void colstats(const float* __restrict__ z,
                                                float* __restrict__ stats) {
  const long long total = (long long)NN * C;
  int t = threadIdx.x;
  long long idx = (long long)blockIdx.x * 256 + t;
  long long stride = (long long)gridDim.x * 256;
  float s = 0.f, q = 0.f;
  for (; idx < total; idx += stride) {
    float v = z[idx];
    s += v;
    q += v * v;
  }
  __shared__ float ls[256], lq[256];
  ls[t] = s; lq[t] = q;
  __syncthreads();
  if (t < C) {
    float ss = 0.f, qq = 0.f;
    #pragma unroll
    for (int r = 0; r < 256 / C; ++r) { ss += ls[t + r * C]; qq += lq[t + r * C]; }
    atomicAdd(&stats[t], ss);
    atomicAdd(&stats[C + t], qq);
  }
}

// ---- stats -> affine coefs: y = v*a + c ----
__global__ void bncoef(const float* __restrict__ stats, const float* __restrict__ g,
                       const float* __restrict__ b, float* __restrict__ coef, int C) {
  int j = threadIdx.x;
  if (j >= C) return;
  float mu  = stats[j] * (1.0f / NN);
  float var = stats[C + j] * (1.0f / NN) - mu * mu;
  float a = g[j] * rsqrtf(var + EPS);
  coef[j] = a;
  coef[C + j] = b[j] - mu * a;
}

// ---- final: out[i] = sum_j relu(z2[i][j]*a+c) * fc3w[j] + fc3b ----
__global__ __launch_bounds__(256) void final_k(const float* __restrict__ z2,
                                               const float* __restrict__ coef,
                                               const float* __restrict__ fc3w,
                                               const float* __restrict__ fc3b,
                                               float* __restrict__ out) {
  int t = blockIdx.x * 256 + threadIdx.x;
  int i = t >> 6;
  int j = t & 63;
  if (i >= NN) return;
  float v = z2[(size_t)i * 64 + j];
  float p = fmaxf(v * coef[j] + coef[64 + j], 0.f) * fc3w[j];
  #pragma unroll
  for (int o = 32; o > 0; o >>= 1) p += __shfl_xor(p, o, 64);
  if (j == 0) out[i] = p + fc3b[0];
}

extern "C" void kernel_launch(void* const* d_in, const int* in_sizes, int n_in,
                              void* d_out, int out_size, void* d_ws, size_t ws_size,
                              hipStream_t stream) {
  const float* x     = (const float*)d_in[0];
  const int*   ei    = (const int*)d_in[1];
  const float* w_l1  = (const float*)d_in[2];
  const float* b_l1  = (const float*)d_in[3];
  const float* w_r1  = (const float*)d_in[4];
  const float* w_l2  = (const float*)d_in[5];
  const float* b_l2  = (const float*)d_in[6];
  const float* w_r2  = (const float*)d_in[7];
  const float* fc1_w = (const float*)d_in[8];
  const float* fc1_b = (const float*)d_in[9];
  const float* bn1_g = (const float*)d_in[10];
  const float* bn1_b = (const float*)d_in[11];
  const float* fc2_w = (const float*)d_in[12];
  const float* fc2_b = (const float*)d_in[13];
  const float* bn2_g = (const float*)d_in[14];
  const float* bn2_b = (const float*)d_in[15];
  const float* fc3_w = (const float*)d_in[16];
  const float* fc3_b = (const float*)d_in[17];

  const int E = in_sizes[1] / 2;

  float* ws      = (float*)d_ws;
  int*   rowptr  = (int*)(ws + OFF_ROWPTR);
  int*   adj     = (int*)(ws + OFF_ADJ);
  float* agg1    = ws + OFF_AGG1;
  float* agg2    = ws + OFF_AGG2;
  unsigned short* xb  = (unsigned short*)(ws + OFF_XB);
  unsigned short* h1b = (unsigned short*)(ws + OFF_H1B);
  float* z1      = ws + OFF_Z1;
  float* z2      = ws + OFF_Z2;
  float* stats1  = ws + OFF_STATS1;
  float* stats2  = ws + OFF_STATS2;
  float* coef1   = ws + OFF_COEF1;
  float* coef2   = ws + OFF_COEF2;
  int*   bukhist = (int*)(ws + OFF_BUKHIST);
  int*   bukbase = (int*)(ws + OFF_BUKBASE);
  int*   bukcur  = (int*)(ws + OFF_BUKCUR);
  int2*  pairs   = (int2*)(ws + OFF_PAIRS);

  float* outv = (float*)d_out;             // [NN]
  float* h1   = outv + NN;                 // [NN,64]
  float* h2   = h1 + (size_t)NN * 64;      // [NN,64]

  hipMemsetAsync(ws + ZERO_START, 0, ZERO_INTS * sizeof(float), stream);

  // bf16 copy of x for cheap gathering (xb dead before agg2 is written)
  cvt_bf_k<<<(NN * 32 / 8 + 255) / 256, 256, 0, stream>>>(x, xb, NN * 32 / 8);

  // CSR build — bucket-partitioned; per-node work entirely in LDS
  const int NCH = (E + CHUNK - 1) / CHUNK;
  bhist_k<<<NCH, 256, 0, stream>>>(ei, E, bukhist);
  bukscan_k<<<1, NBUK, 0, stream>>>(bukhist, bukbase, bukcur);
  bpart_k<<<NCH, 256, 0, stream>>>(ei, E, bukcur, pairs);
  bfill_k<<<NBUK, 256, 0, stream>>>(pairs, bukbase, rowptr, adj);

  const int MB = (NN + 63) / 64;   // MFMA dense grid: 64 rows per block

  // layer 1 (gather bf16 x; dense emits h1 f32 + h1b bf16 for next gather)
  aggregate_bf<32><<<(NN * 32 + 255) / 256, 256, 0, stream>>>(xb, rowptr, adj, agg1);
  mfma_dense<32, 64, true, false, true, true>
      <<<MB, 256, 0, stream>>>(agg1, x, w_l1, w_r1, b_l1, nullptr, h1, h1b);

  // layer 2
  aggregate_bf<64><<<(NN * 64 + 255) / 256, 256, 0, stream>>>(h1b, rowptr, adj, agg2);
  mfma_dense<64, 64, true, false, true, false>
      <<<MB, 256, 0, stream>>>(agg2, h1, w_l2, w_r2, b_l2, nullptr, h2, nullptr);

  // fc1 -> z1 (raw, pre-BN)
  mfma_dense<64, 128, false, false, false, false>
      <<<MB, 256, 0, stream>>>(h2, nullptr, fc1_w, nullptr, fc1_b, nullptr, z1, nullptr);
  colstats<128><<<512, 256, 0, stream>>>(z1, stats1);
  bncoef<<<1, 128, 0, stream>>>(stats1, bn1_g, bn1_b, coef1, 128);

  // fc2 with fused bn1+relu on input -> z2 (raw, pre-BN)
  mfma_dense<128, 64, false, true, false, false>
      <<<MB, 256, 0, stream>>>(z1, nullptr, fc2_w, nullptr, fc2_b, coef1, z2, nullptr);
  colstats<64><<<512, 256, 0, stream>>>(z2, stats2);
  bncoef<<<1, 64, 0, stream>>>(stats2, bn2_g, bn2_b, coef2, 64);

  // bn2 + relu + fc3 fused
  final_k<<<(NN * 64 + 255) / 256, 256, 0, stream>>>(z2, coef2, fc3_w, fc3_b, outv);
}

// Round 11
// 340.623 us; speedup vs baseline: 10.6738x; 1.1212x over previous
//
#include <hip/hip_runtime.h>

#define NN 100000
#define EPS 1e-5f

// ---- workspace layout (4-byte units), ~82MB total ----
// lifetimes: pairs(build) aliases agg1+agg2(layers); z1 aliases build+agg;
// z2 aliases h1b; xb head overlapped by z1 tail (xb dead by fc1).
static const size_t OFF_ROWST  = 0;           // rowstart [100k]
static const size_t OFF_ROWEN  = 100000;      // rowend   [100k]
static const size_t OFF_ADJ    = 200000;      // adj [256*10496] -> 2,886,976
static const size_t OFF_AGG1   = 2886976;     // N*32 f32 -> 6,086,976
static const size_t OFF_AGG2   = 6086976;     // N*64 f32 -> 12,486,976
static const size_t OFF_PAIRS  = 2886976;     // aliases agg1+agg2 (dead before agg1 written)
static const size_t OFF_XB     = 12486976;    // N*32 bf16 = 1.6M -> 14,086,976
static const size_t OFF_Z1     = 0;           // N*128 f32 [0..12.8M): build+agg+xb-head dead by fc1
static const size_t OFF_H1B    = 14086976;    // N*64 bf16 = 3.2M -> 17,286,976
static const size_t OFF_Z2     = 14086976;    // aliases h1b (dead before z2 written) -> 20,486,976
static const size_t OFF_BUKCNT = 20486976;    // 256 ints
static const size_t OFF_STATS1 = 20487232;    // 256
static const size_t OFF_STATS2 = 20487488;    // 128
static const size_t OFF_COEF1  = 20487616;    // 256
static const size_t OFF_COEF2  = 20487872;    // 128
static const size_t ZERO_START = 20486976;    // bukcnt + stats1 + stats2
static const size_t ZERO_INTS  = 640;

#define NBUK 256
#define BSHIFT 9                              // 512 nodes per bucket
// Only buckets 0..195 carry nodes -> mean load = 1.6M*512/100000 = 8192, sigma~90.
// BCAP = 8192 + 25.5 sigma. (Round-10 bug: BCAP=8192 == mean -> overflow.)
#define BCAP 10496
#define CHUNK 8192

typedef __attribute__((ext_vector_type(8))) short short8;
typedef __attribute__((ext_vector_type(4))) float f32x4;

#define MFMA_16x16x32(a, b, c) __builtin_amdgcn_mfma_f32_16x16x32_bf16(a, b, c, 0, 0, 0)

// f32 -> bf16 (RNE) at bit level
__device__ inline unsigned short f2bf(float f) {
  unsigned u = __builtin_bit_cast(unsigned, f);
  unsigned r = (u + 0x7fffu + ((u >> 16) & 1u)) >> 16;
  return (unsigned short)r;
}
__device__ inline float bf2f(unsigned short h) {
  unsigned u = ((unsigned)h) << 16;
  return __builtin_bit_cast(float, u);
}

// load 8 contiguous f32 (optionally BN+relu transformed), split into hi/lo bf16
template<bool BNIN>
__device__ inline void load_split(const float* __restrict__ p,
                                  const float* __restrict__ ca,
                                  const float* __restrict__ cc,
                                  short8& hi, short8& lo) {
  #pragma unroll
  for (int j = 0; j < 8; ++j) {
    float v = p[j];
    if (BNIN) v = fmaxf(v * ca[j] + cc[j], 0.f);
    unsigned short h = f2bf(v);
    hi[j] = (short)h;
    lo[j] = (short)f2bf(v - bf2f(h));
  }
}

// ---- convert f32 plane -> bf16 plane (for cheap gathers) ----
__global__ __launch_bounds__(256) void cvt_bf_k(const float* __restrict__ in,
                                                unsigned short* __restrict__ out,
                                                int n8) {
  int t = blockIdx.x * 256 + threadIdx.x;
  if (t >= n8) return;
  const float4* p = (const float4*)(in + (size_t)t * 8);
  float4 a = p[0], b = p[1];
  ushort4 u0, u1;
  u0.x = f2bf(a.x); u0.y = f2bf(a.y); u0.z = f2bf(a.z); u0.w = f2bf(a.w);
  u1.x = f2bf(b.x); u1.y = f2bf(b.y); u1.z = f2bf(b.z); u1.w = f2bf(b.w);
  ((ushort4*)(out + (size_t)t * 8))[0] = u0;
  ((ushort4*)(out + (size_t)t * 8))[1] = u1;
}

// ---- build 1: partition edges into fixed-capacity bucket pair arrays ----
__global__ __launch_bounds__(256) void bpart2_k(const int* __restrict__ ei, int E,
                                                int* __restrict__ bukcnt,
                                                int2* __restrict__ pairs) {
  __shared__ int h[NBUK], wb[NBUK], cur[NBUK];
  int tid = threadIdx.x;
  h[tid] = 0; cur[tid] = 0;
  __syncthreads();
  int lo = blockIdx.x * CHUNK, hi = min(lo + CHUNK, E);
  for (int e = lo + tid; e < hi; e += 256) {
    int t = ei[E + e];
    if ((unsigned)t < NN) atomicAdd(&h[t >> BSHIFT], 1);
  }
  __syncthreads();
  wb[tid] = h[tid] ? atomicAdd(&bukcnt[tid], h[tid]) : 0;
  __syncthreads();
  for (int e = lo + tid; e < hi; e += 256) {
    int s = ei[e], t = ei[E + e];
    if ((unsigned)t >= NN) continue;
    if ((unsigned)s >= NN) s = 0;            // clamp (keeps count/write in sync)
    int b = t >> BSHIFT;
    int off = atomicAdd(&cur[b], 1);
    pairs[(size_t)b * BCAP + wb[b] + off] = make_int2(s, t);
  }
}

// ---- build 2: per-bucket LDS histogram + scan -> rowstart/rowend + adj fill ----
__global__ __launch_bounds__(256) void bfill2_k(const int2* __restrict__ pairs,
                                                const int* __restrict__ bukcnt,
                                                int* __restrict__ rowstart,
                                                int* __restrict__ rowend,
                                                int* __restrict__ adj) {
  __shared__ int d[512];
  __shared__ int part[256];
  int b = blockIdx.x;
  int t = threadIdx.x;
  int base = b * BCAP, cnt = bukcnt[b];
  d[t] = 0; d[t + 256] = 0;
  __syncthreads();
  for (int p = base + t; p < base + cnt; p += 256)
    atomicAdd(&d[pairs[p].y & 511], 1);
  __syncthreads();
  int d0 = d[2 * t], d1 = d[2 * t + 1];
  part[t] = d0 + d1;
  __syncthreads();
  for (int o = 1; o < 256; o <<= 1) {
    int u = (t >= o) ? part[t - o] : 0;
    __syncthreads();
    part[t] += u;
    __syncthreads();
  }
  int e0 = (t > 0) ? part[t - 1] : 0;
  int e1 = e0 + d0;
  d[2 * t] = e0;            // becomes LDS cursor
  d[2 * t + 1] = e1;
  int n0 = (b << BSHIFT) + 2 * t;
  if (n0 < NN)     { rowstart[n0]     = base + e0; rowend[n0]     = base + e1; }
  if (n0 + 1 < NN) { rowstart[n0 + 1] = base + e1; rowend[n0 + 1] = base + e1 + d1; }
  __syncthreads();
  for (int p = base + t; p < base + cnt; p += 256) {
    int2 pr = pairs[p];
    int pos = atomicAdd(&d[pr.y & 511], 1);
    adj[base + pos] = pr.x;
  }
}

// ---- gather-side mean aggregation, ushort4-vectorized: K/4 lanes per node ----
template<int K>
__global__ __launch_bounds__(256) void aggregate_bf(const unsigned short* __restrict__ xb,
                                                    const int* __restrict__ rowstart,
                                                    const int* __restrict__ rowend,
                                                    const int* __restrict__ adj,
                                                    float* __restrict__ agg) {
  constexpr int GL = K / 4;                   // lanes per node
  constexpr int NPB = 256 / GL;
  int lg = threadIdx.x & (GL - 1);
  int node = blockIdx.x * NPB + (threadIdx.x / GL);
  if (node >= NN) return;
  int s0 = rowstart[node], s1 = rowend[node];
  float4 a0 = {0,0,0,0}, a1 = {0,0,0,0}, a2 = {0,0,0,0}, a3 = {0,0,0,0};
  int e = s0;
  for (; e + 3 < s1; e += 4) {                // 4 independent chains
    int i0 = adj[e], i1 = adj[e+1], i2 = adj[e+2], i3 = adj[e+3];
    ushort4 u0 = *(const ushort4*)(xb + (size_t)i0 * K + lg * 4);
    ushort4 u1 = *(const ushort4*)(xb + (size_t)i1 * K + lg * 4);
    ushort4 u2 = *(const ushort4*)(xb + (size_t)i2 * K + lg * 4);
    ushort4 u3 = *(const ushort4*)(xb + (size_t)i3 * K + lg * 4);
    a0.x += bf2f(u0.x); a0.y += bf2f(u0.y); a0.z += bf2f(u0.z); a0.w += bf2f(u0.w);
    a1.x += bf2f(u1.x); a1.y += bf2f(u1.y); a1.z += bf2f(u1.z); a1.w += bf2f(u1.w);
    a2.x += bf2f(u2.x); a2.y += bf2f(u2.y); a2.z += bf2f(u2.z); a2.w += bf2f(u2.w);
    a3.x += bf2f(u3.x); a3.y += bf2f(u3.y); a3.z += bf2f(u3.z); a3.w += bf2f(u3.w);
  }
  for (; e < s1; ++e) {
    ushort4 u = *(const ushort4*)(xb + (size_t)adj[e] * K + lg * 4);
    a0.x += bf2f(u.x); a0.y += bf2f(u.y); a0.z += bf2f(u.z); a0.w += bf2f(u.w);
  }
  float inv = 1.0f / fmaxf((float)(s1 - s0), 1.0f);
  float4 r;
  r.x = (a0.x + a1.x + a2.x + a3.x) * inv;
  r.y = (a0.y + a1.y + a2.y + a3.y) * inv;
  r.z = (a0.z + a1.z + a2.z + a3.z) * inv;
  r.w = (a0.w + a1.w + a2.w + a3.w) * inv;
  *(float4*)(agg + (size_t)node * K + lg * 4) = r;
}

// ---- MFMA dense layer (split-bf16, f32-accurate) ----
// Optionally also emits a bf16 copy of the output plane (for cheap gathers).
template<int K, int C, bool SAGE, bool BNIN, bool RELU, bool BFOUT>
__global__ __launch_bounds__(256) void mfma_dense(const float* __restrict__ inA,
                                                  const float* __restrict__ inB,
                                                  const float* __restrict__ wA,
                                                  const float* __restrict__ wB,
                                                  const float* __restrict__ bias,
                                                  const float* __restrict__ coef,
                                                  float* __restrict__ out,
                                                  unsigned short* __restrict__ outb) {
  constexpr int KF = K / 32;
  int wid  = threadIdx.x >> 6;
  int lane = threadIdx.x & 63;
  int row0 = blockIdx.x * 64 + wid * 16;
  int r = lane & 15, g = lane >> 4;
  int arow = row0 + r; if (arow > NN - 1) arow = NN - 1;   // clamp tail reads
  int koff = g * 8;

  short8 ahi[KF], alo[KF];
  short8 a2hi[SAGE ? KF : 1], a2lo[SAGE ? KF : 1];
  #pragma unroll
  for (int kf = 0; kf < KF; ++kf) {
    const float* p = inA + (size_t)arow * K + kf * 32 + koff;
    load_split<BNIN>(p, coef + kf * 32 + koff, coef + K + kf * 32 + koff,
                     ahi[kf], alo[kf]);
  }
  if (SAGE) {
    #pragma unroll
    for (int kf = 0; kf < KF; ++kf) {
      const float* p = inB + (size_t)arow * K + kf * 32 + koff;
      load_split<false>(p, nullptr, nullptr, a2hi[kf], a2lo[kf]);
    }
  }

  #pragma unroll 1
  for (int cf = 0; cf < C / 16; ++cf) {
    int col = cf * 16 + r;
    float bv = bias[col];
    f32x4 acc = {bv, bv, bv, bv};
    #pragma unroll
    for (int kf = 0; kf < KF; ++kf) {
      short8 whi, wlo;
      load_split<false>(wA + (size_t)col * K + kf * 32 + koff, nullptr, nullptr, whi, wlo);
      acc = MFMA_16x16x32(ahi[kf], whi, acc);
      acc = MFMA_16x16x32(ahi[kf], wlo, acc);
      acc = MFMA_16x16x32(alo[kf], whi, acc);
      if (SAGE) {
        short8 vhi, vlo;
        load_split<false>(wB + (size_t)col * K + kf * 32 + koff, nullptr, nullptr, vhi, vlo);
        acc = MFMA_16x16x32(a2hi[kf], vhi, acc);
        acc = MFMA_16x16x32(a2hi[kf], vlo, acc);
        acc = MFMA_16x16x32(a2lo[kf], vhi, acc);
      }
    }
    #pragma unroll
    for (int j = 0; j < 4; ++j) {
      int orow = row0 + g * 4 + j;
      if (orow < NN) {
        float v = acc[j];
        if (RELU) v = fmaxf(v, 0.f);
        out[(size_t)orow * C + col] = v;
        if (BFOUT) outb[(size_t)orow * C + col] = f2bf(v);
      }
    }
  }
}

// ---- column sums / sumsq over [NN, C] ----
template<int C>
__global__ __launch_bounds__(256) void colstats(const float* __restrict__ z,
                                                float* __restrict__ stats) {
  const long long total = (long long)NN * C;
  int t = threadIdx.x;
  long long idx = (long long)blockIdx.x * 256 + t;
  long long stride = (long long)gridDim.x * 256;
  float s = 0.f, q = 0.f;
  for (; idx < total; idx += stride) {
    float v = z[idx];
    s += v;
    q += v * v;
  }
  __shared__ float ls[256], lq[256];
  ls[t] = s; lq[t] = q;
  __syncthreads();
  if (t < C) {
    float ss = 0.f, qq = 0.f;
    #pragma unroll
    for (int r = 0; r < 256 / C; ++r) { ss += ls[t + r * C]; qq += lq[t + r * C]; }
    atomicAdd(&stats[t], ss);
    atomicAdd(&stats[C + t], qq);
  }
}

// ---- stats -> affine coefs: y = v*a + c ----
__global__ void bncoef(const float* __restrict__ stats, const float* __restrict__ g,
                       const float* __restrict__ b, float* __restrict__ coef, int C) {
  int j = threadIdx.x;
  if (j >= C) return;
  float mu  = stats[j] * (1.0f / NN);
  float var = stats[C + j] * (1.0f / NN) - mu * mu;
  float a = g[j] * rsqrtf(var + EPS);
  coef[j] = a;
  coef[C + j] = b[j] - mu * a;
}

// ---- final: out[i] = sum_j relu(z2[i][j]*a+c) * fc3w[j] + fc3b ----
__global__ __launch_bounds__(256) void final_k(const float* __restrict__ z2,
                                               const float* __restrict__ coef,
                                               const float* __restrict__ fc3w,
                                               const float* __restrict__ fc3b,
                                               float* __restrict__ out) {
  int t = blockIdx.x * 256 + threadIdx.x;
  int i = t >> 6;
  int j = t & 63;
  if (i >= NN) return;
  float v = z2[(size_t)i * 64 + j];
  float p = fmaxf(v * coef[j] + coef[64 + j], 0.f) * fc3w[j];
  #pragma unroll
  for (int o = 32; o > 0; o >>= 1) p += __shfl_xor(p, o, 64);
  if (j == 0) out[i] = p + fc3b[0];
}

extern "C" void kernel_launch(void* const* d_in, const int* in_sizes, int n_in,
                              void* d_out, int out_size, void* d_ws, size_t ws_size,
                              hipStream_t stream) {
  const float* x     = (const float*)d_in[0];
  const int*   ei    = (const int*)d_in[1];
  const float* w_l1  = (const float*)d_in[2];
  const float* b_l1  = (const float*)d_in[3];
  const float* w_r1  = (const float*)d_in[4];
  const float* w_l2  = (const float*)d_in[5];
  const float* b_l2  = (const float*)d_in[6];
  const float* w_r2  = (const float*)d_in[7];
  const float* fc1_w = (const float*)d_in[8];
  const float* fc1_b = (const float*)d_in[9];
  const float* bn1_g = (const float*)d_in[10];
  const float* bn1_b = (const float*)d_in[11];
  const float* fc2_w = (const float*)d_in[12];
  const float* fc2_b = (const float*)d_in[13];
  const float* bn2_g = (const float*)d_in[14];
  const float* bn2_b = (const float*)d_in[15];
  const float* fc3_w = (const float*)d_in[16];
  const float* fc3_b = (const float*)d_in[17];

  const int E = in_sizes[1] / 2;

  float* ws       = (float*)d_ws;
  int*   rowstart = (int*)(ws + OFF_ROWST);
  int*   rowend   = (int*)(ws + OFF_ROWEN);
  int*   adj      = (int*)(ws + OFF_ADJ);
  float* agg1     = ws + OFF_AGG1;
  float* agg2     = ws + OFF_AGG2;
  unsigned short* xb  = (unsigned short*)(ws + OFF_XB);
  unsigned short* h1b = (unsigned short*)(ws + OFF_H1B);
  float* z1       = ws + OFF_Z1;
  float* z2       = ws + OFF_Z2;
  int*   bukcnt   = (int*)(ws + OFF_BUKCNT);
  float* stats1   = ws + OFF_STATS1;
  float* stats2   = ws + OFF_STATS2;
  float* coef1    = ws + OFF_COEF1;
  float* coef2    = ws + OFF_COEF2;
  int2*  pairs    = (int2*)(ws + OFF_PAIRS);

  float* outv = (float*)d_out;             // [NN]
  float* h1   = outv + NN;                 // [NN,64]
  float* h2   = h1 + (size_t)NN * 64;      // [NN,64]

  hipMemsetAsync(ws + ZERO_START, 0, ZERO_INTS * sizeof(float), stream);

  // bf16 copy of x for cheap gathering
  cvt_bf_k<<<(NN * 32 / 8 + 255) / 256, 256, 0, stream>>>(x, xb, NN * 32 / 8);

  // CSR build — fixed-capacity bucket partition, per-node work in LDS
  const int NCH = (E + CHUNK - 1) / CHUNK;
  bpart2_k<<<NCH, 256, 0, stream>>>(ei, E, bukcnt, pairs);
  bfill2_k<<<NBUK, 256, 0, stream>>>(pairs, bukcnt, rowstart, rowend, adj);

  const int MB = (NN + 63) / 64;   // MFMA dense grid: 64 rows per block

  // layer 1 (gather bf16 x; dense emits h1 f32 + h1b bf16 for next gather)
  aggregate_bf<32><<<(NN + 31) / 32, 256, 0, stream>>>(xb, rowstart, rowend, adj, agg1);
  mfma_dense<32, 64, true, false, true, true>
      <<<MB, 256, 0, stream>>>(agg1, x, w_l1, w_r1, b_l1, nullptr, h1, h1b);

  // layer 2
  aggregate_bf<64><<<(NN + 15) / 16, 256, 0, stream>>>(h1b, rowstart, rowend, adj, agg2);
  mfma_dense<64, 64, true, false, true, false>
      <<<MB, 256, 0, stream>>>(agg2, h1, w_l2, w_r2, b_l2, nullptr, h2, nullptr);

  // fc1 -> z1 (raw, pre-BN)
  mfma_dense<64, 128, false, false, false, false>
      <<<MB, 256, 0, stream>>>(h2, nullptr, fc1_w, nullptr, fc1_b, nullptr, z1, nullptr);
  colstats<128><<<512, 256, 0, stream>>>(z1, stats1);
  bncoef<<<1, 128, 0, stream>>>(stats1, bn1_g, bn1_b, coef1, 128);

  // fc2 with fused bn1+relu on input -> z2 (raw, pre-BN)
  mfma_dense<128, 64, false, true, false, false>
      <<<MB, 256, 0, stream>>>(z1, nullptr, fc2_w, nullptr, fc2_b, coef1, z2, nullptr);
  colstats<64><<<512, 256, 0, stream>>>(z2, stats2);
  bncoef<<<1, 64, 0, stream>>>(stats2, bn2_g, bn2_b, coef2, 64);

  // bn2 + relu + fc3 fused
  final_k<<<(NN * 64 + 255) / 256, 256, 0, stream>>>(z2, coef2, fc3_w, fc3_b, outv);
}

// Round 12
// 334.337 us; speedup vs baseline: 10.8745x; 1.0188x over previous
//
#include <hip/hip_runtime.h>

#define NN 100000
#define EPS 1e-5f

// ---- workspace layout (4-byte units), ~82MB total ----
static const size_t OFF_ROWST  = 0;           // rowstart [100k]
static const size_t OFF_ROWEN  = 100000;      // rowend   [100k]
static const size_t OFF_ADJ    = 200000;      // adj [256*10496] -> 2,886,976
static const size_t OFF_AGG1   = 2886976;     // N*32 f32 -> 6,086,976
static const size_t OFF_AGG2   = 6086976;     // N*64 f32 -> 12,486,976
static const size_t OFF_PAIRS  = 2886976;     // aliases agg1+agg2 (dead before agg1 written)
static const size_t OFF_XB     = 12486976;    // N*32 bf16 -> 14,086,976
static const size_t OFF_Z1     = 0;           // N*128 f32 [0..12.8M): dead by fc1
static const size_t OFF_H1B    = 14086976;    // N*64 bf16 -> 17,286,976
static const size_t OFF_Z2     = 14086976;    // aliases h1b -> 20,486,976
static const size_t OFF_BUKCNT = 20486976;    // 256 ints
static const size_t OFF_STATS1 = 20487232;    // 256
static const size_t OFF_STATS2 = 20487488;    // 128
static const size_t OFF_COEF1  = 20487616;    // 256
static const size_t OFF_COEF2  = 20487872;    // 128
static const size_t OFF_WSPL   = 20488000;    // 57,344 ushorts = 28,672 floats
static const size_t ZERO_START = 20486976;    // bukcnt + stats1 + stats2
static const size_t ZERO_INTS  = 640;

// split-weight plane offsets (ushort units within WSPL)
#define WL1_HI 0
#define WL1_LO 2048
#define WR1_HI 4096
#define WR1_LO 6144
#define WL2_HI 8192
#define WL2_LO 12288
#define WR2_HI 16384
#define WR2_LO 20480
#define F1_HI  24576
#define F1_LO  32768
#define F2_HI  40960
#define F2_LO  49152

#define NBUK 256
#define BSHIFT 9                              // 512 nodes per bucket
#define BCAP 10496                            // mean 8192 + 25 sigma
#define CHUNK 2048                            // 782 blocks (was 8192/196: latency-bound)

typedef __attribute__((ext_vector_type(8))) short short8;
typedef __attribute__((ext_vector_type(4))) float f32x4;

#define MFMA_16x16x32(a, b, c) __builtin_amdgcn_mfma_f32_16x16x32_bf16(a, b, c, 0, 0, 0)

// f32 -> bf16 (RNE) at bit level
__device__ inline unsigned short f2bf(float f) {
  unsigned u = __builtin_bit_cast(unsigned, f);
  unsigned r = (u + 0x7fffu + ((u >> 16) & 1u)) >> 16;
  return (unsigned short)r;
}
__device__ inline float bf2f(unsigned short h) {
  unsigned u = ((unsigned)h) << 16;
  return __builtin_bit_cast(float, u);
}

// load 8 contiguous f32 (optionally BN+relu transformed), split into hi/lo bf16
template<bool BNIN>
__device__ inline void load_split(const float* __restrict__ p,
                                  const float* __restrict__ ca,
                                  const float* __restrict__ cc,
                                  short8& hi, short8& lo) {
  #pragma unroll
  for (int j = 0; j < 8; ++j) {
    float v = p[j];
    if (BNIN) v = fmaxf(v * ca[j] + cc[j], 0.f);
    unsigned short h = f2bf(v);
    hi[j] = (short)h;
    lo[j] = (short)f2bf(v - bf2f(h));
  }
}

// ---- one-shot: split all 6 weight matrices into hi/lo bf16 planes ----
struct WsplitArgs {
  const float* src[6];
  unsigned short* dhi[6];
  unsigned short* dlo[6];
  int n[6];
};
__global__ __launch_bounds__(256) void wsplit_k(WsplitArgs a) {
  int m = blockIdx.y;
  int n = a.n[m];
  for (int i = blockIdx.x * 256 + threadIdx.x; i < n; i += gridDim.x * 256) {
    float v = a.src[m][i];
    unsigned short h = f2bf(v);
    a.dhi[m][i] = h;
    a.dlo[m][i] = f2bf(v - bf2f(h));
  }
}

// ---- convert f32 plane -> bf16 plane (for cheap gathers) ----
__global__ __launch_bounds__(256) void cvt_bf_k(const float* __restrict__ in,
                                                unsigned short* __restrict__ out,
                                                int n8) {
  int t = blockIdx.x * 256 + threadIdx.x;
  if (t >= n8) return;
  const float4* p = (const float4*)(in + (size_t)t * 8);
  float4 a = p[0], b = p[1];
  ushort4 u0, u1;
  u0.x = f2bf(a.x); u0.y = f2bf(a.y); u0.z = f2bf(a.z); u0.w = f2bf(a.w);
  u1.x = f2bf(b.x); u1.y = f2bf(b.y); u1.z = f2bf(b.z); u1.w = f2bf(b.w);
  ((ushort4*)(out + (size_t)t * 8))[0] = u0;
  ((ushort4*)(out + (size_t)t * 8))[1] = u1;
}

// ---- build 1: partition edges into fixed-capacity bucket pair arrays ----
__global__ __launch_bounds__(256) void bpart2_k(const int* __restrict__ ei, int E,
                                                int* __restrict__ bukcnt,
                                                int2* __restrict__ pairs) {
  __shared__ int h[NBUK], wb[NBUK], cur[NBUK];
  int tid = threadIdx.x;
  h[tid] = 0; cur[tid] = 0;
  __syncthreads();
  int lo = blockIdx.x * CHUNK, hi = min(lo + CHUNK, E);
  for (int e = lo + tid; e < hi; e += 256) {
    int t = ei[E + e];
    if ((unsigned)t < NN) atomicAdd(&h[t >> BSHIFT], 1);
  }
  __syncthreads();
  wb[tid] = h[tid] ? atomicAdd(&bukcnt[tid], h[tid]) : 0;
  __syncthreads();
  for (int e = lo + tid; e < hi; e += 256) {
    int s = ei[e], t = ei[E + e];
    if ((unsigned)t >= NN) continue;
    if ((unsigned)s >= NN) s = 0;            // clamp (keeps count/write in sync)
    int b = t >> BSHIFT;
    int off = atomicAdd(&cur[b], 1);
    pairs[(size_t)b * BCAP + wb[b] + off] = make_int2(s, t);
  }
}

// ---- build 2: per-bucket LDS histogram + scan -> rowstart/rowend + adj fill ----
__global__ __launch_bounds__(256) void bfill2_k(const int2* __restrict__ pairs,
                                                const int* __restrict__ bukcnt,
                                                int* __restrict__ rowstart,
                                                int* __restrict__ rowend,
                                                int* __restrict__ adj) {
  __shared__ int d[512];
  __shared__ int part[256];
  int b = blockIdx.x;
  int t = threadIdx.x;
  int base = b * BCAP, cnt = bukcnt[b];
  d[t] = 0; d[t + 256] = 0;
  __syncthreads();
  for (int p = base + t; p < base + cnt; p += 256)
    atomicAdd(&d[pairs[p].y & 511], 1);
  __syncthreads();
  int d0 = d[2 * t], d1 = d[2 * t + 1];
  part[t] = d0 + d1;
  __syncthreads();
  for (int o = 1; o < 256; o <<= 1) {
    int u = (t >= o) ? part[t - o] : 0;
    __syncthreads();
    part[t] += u;
    __syncthreads();
  }
  int e0 = (t > 0) ? part[t - 1] : 0;
  int e1 = e0 + d0;
  d[2 * t] = e0;            // becomes LDS cursor
  d[2 * t + 1] = e1;
  int n0 = (b << BSHIFT) + 2 * t;
  if (n0 < NN)     { rowstart[n0]     = base + e0; rowend[n0]     = base + e1; }
  if (n0 + 1 < NN) { rowstart[n0 + 1] = base + e1; rowend[n0 + 1] = base + e1 + d1; }
  __syncthreads();
  for (int p = base + t; p < base + cnt; p += 256) {
    int2 pr = pairs[p];
    int pos = atomicAdd(&d[pr.y & 511], 1);
    adj[base + pos] = pr.x;
  }
}

// ---- gather-side mean aggregation, ushort4-vectorized: K/4 lanes per node ----
template<int K>
__global__ __launch_bounds__(256) void aggregate_bf(const unsigned short* __restrict__ xb,
                                                    const int* __restrict__ rowstart,
                                                    const int* __restrict__ rowend,
                                                    const int* __restrict__ adj,
                                                    float* __restrict__ agg) {
  constexpr int GL = K / 4;                   // lanes per node
  constexpr int NPB = 256 / GL;
  int lg = threadIdx.x & (GL - 1);
  int node = blockIdx.x * NPB + (threadIdx.x / GL);
  if (node >= NN) return;
  int s0 = rowstart[node], s1 = rowend[node];
  float4 a0 = {0,0,0,0}, a1 = {0,0,0,0}, a2 = {0,0,0,0}, a3 = {0,0,0,0};
  int e = s0;
  for (; e + 3 < s1; e += 4) {                // 4 independent chains
    int i0 = adj[e], i1 = adj[e+1], i2 = adj[e+2], i3 = adj[e+3];
    ushort4 u0 = *(const ushort4*)(xb + (size_t)i0 * K + lg * 4);
    ushort4 u1 = *(const ushort4*)(xb + (size_t)i1 * K + lg * 4);
    ushort4 u2 = *(const ushort4*)(xb + (size_t)i2 * K + lg * 4);
    ushort4 u3 = *(const ushort4*)(xb + (size_t)i3 * K + lg * 4);
    a0.x += bf2f(u0.x); a0.y += bf2f(u0.y); a0.z += bf2f(u0.z); a0.w += bf2f(u0.w);
    a1.x += bf2f(u1.x); a1.y += bf2f(u1.y); a1.z += bf2f(u1.z); a1.w += bf2f(u1.w);
    a2.x += bf2f(u2.x); a2.y += bf2f(u2.y); a2.z += bf2f(u2.z); a2.w += bf2f(u2.w);
    a3.x += bf2f(u3.x); a3.y += bf2f(u3.y); a3.z += bf2f(u3.z); a3.w += bf2f(u3.w);
  }
  for (; e < s1; ++e) {
    ushort4 u = *(const ushort4*)(xb + (size_t)adj[e] * K + lg * 4);
    a0.x += bf2f(u.x); a0.y += bf2f(u.y); a0.z += bf2f(u.z); a0.w += bf2f(u.w);
  }
  float inv = 1.0f / fmaxf((float)(s1 - s0), 1.0f);
  float4 r;
  r.x = (a0.x + a1.x + a2.x + a3.x) * inv;
  r.y = (a0.y + a1.y + a2.y + a3.y) * inv;
  r.z = (a0.z + a1.z + a2.z + a3.z) * inv;
  r.w = (a0.w + a1.w + a2.w + a3.w) * inv;
  *(float4*)(agg + (size_t)node * K + lg * 4) = r;
}

// ---- MFMA dense layer (split-bf16, f32-accurate); weights pre-split ----
template<int K, int C, bool SAGE, bool BNIN, bool RELU, bool BFOUT>
__global__ __launch_bounds__(256) void mfma_dense(const float* __restrict__ inA,
                                                  const float* __restrict__ inB,
                                                  const unsigned short* __restrict__ whiA,
                                                  const unsigned short* __restrict__ wloA,
                                                  const unsigned short* __restrict__ whiB,
                                                  const unsigned short* __restrict__ wloB,
                                                  const float* __restrict__ bias,
                                                  const float* __restrict__ coef,
                                                  float* __restrict__ out,
                                                  unsigned short* __restrict__ outb) {
  constexpr int KF = K / 32;
  int wid  = threadIdx.x >> 6;
  int lane = threadIdx.x & 63;
  int row0 = blockIdx.x * 64 + wid * 16;
  int r = lane & 15, g = lane >> 4;
  int arow = row0 + r; if (arow > NN - 1) arow = NN - 1;   // clamp tail reads
  int koff = g * 8;

  short8 ahi[KF], alo[KF];
  short8 a2hi[SAGE ? KF : 1], a2lo[SAGE ? KF : 1];
  #pragma unroll
  for (int kf = 0; kf < KF; ++kf) {
    const float* p = inA + (size_t)arow * K + kf * 32 + koff;
    load_split<BNIN>(p, coef + kf * 32 + koff, coef + K + kf * 32 + koff,
                     ahi[kf], alo[kf]);
  }
  if (SAGE) {
    #pragma unroll
    for (int kf = 0; kf < KF; ++kf) {
      const float* p = inB + (size_t)arow * K + kf * 32 + koff;
      load_split<false>(p, nullptr, nullptr, a2hi[kf], a2lo[kf]);
    }
  }

  #pragma unroll 1
  for (int cf = 0; cf < C / 16; ++cf) {
    int col = cf * 16 + r;
    float bv = bias[col];
    f32x4 acc = {bv, bv, bv, bv};
    #pragma unroll
    for (int kf = 0; kf < KF; ++kf) {
      size_t wo = (size_t)col * K + kf * 32 + koff;
      short8 whi = *(const short8*)(whiA + wo);
      short8 wlo = *(const short8*)(wloA + wo);
      acc = MFMA_16x16x32(ahi[kf], whi, acc);
      acc = MFMA_16x16x32(ahi[kf], wlo, acc);
      acc = MFMA_16x16x32(alo[kf], whi, acc);
      if (SAGE) {
        short8 vhi = *(const short8*)(whiB + wo);
        short8 vlo = *(const short8*)(wloB + wo);
        acc = MFMA_16x16x32(a2hi[kf], vhi, acc);
        acc = MFMA_16x16x32(a2hi[kf], vlo, acc);
        acc = MFMA_16x16x32(a2lo[kf], vhi, acc);
      }
    }
    #pragma unroll
    for (int j = 0; j < 4; ++j) {
      int orow = row0 + g * 4 + j;
      if (orow < NN) {
        float v = acc[j];
        if (RELU) v = fmaxf(v, 0.f);
        out[(size_t)orow * C + col] = v;
        if (BFOUT) outb[(size_t)orow * C + col] = f2bf(v);
      }
    }
  }
}

// ---- column sums / sumsq over [NN, C] ----
template<int C>
__global__ __launch_bounds__(256) void colstats(const float* __restrict__ z,
                                                float* __restrict__ stats) {
  const long long total = (long long)NN * C;
  int t = threadIdx.x;
  long long idx = (long long)blockIdx.x * 256 + t;
  long long stride = (long long)gridDim.x * 256;
  float s = 0.f, q = 0.f;
  for (; idx < total; idx += stride) {
    float v = z[idx];
    s += v;
    q += v * v;
  }
  __shared__ float ls[256], lq[256];
  ls[t] = s; lq[t] = q;
  __syncthreads();
  if (t < C) {
    float ss = 0.f, qq = 0.f;
    #pragma unroll
    for (int r = 0; r < 256 / C; ++r) { ss += ls[t + r * C]; qq += lq[t + r * C]; }
    atomicAdd(&stats[t], ss);
    atomicAdd(&stats[C + t], qq);
  }
}

// ---- stats -> affine coefs: y = v*a + c ----
__global__ void bncoef(const float* __restrict__ stats, const float* __restrict__ g,
                       const float* __restrict__ b, float* __restrict__ coef, int C) {
  int j = threadIdx.x;
  if (j >= C) return;
  float mu  = stats[j] * (1.0f / NN);
  float var = stats[C + j] * (1.0f / NN) - mu * mu;
  float a = g[j] * rsqrtf(var + EPS);
  coef[j] = a;
  coef[C + j] = b[j] - mu * a;
}

// ---- final: out[i] = sum_j relu(z2[i][j]*a+c) * fc3w[j] + fc3b ----
__global__ __launch_bounds__(256) void final_k(const float* __restrict__ z2,
                                               const float* __restrict__ coef,
                                               const float* __restrict__ fc3w,
                                               const float* __restrict__ fc3b,
                                               float* __restrict__ out) {
  int t = blockIdx.x * 256 + threadIdx.x;
  int i = t >> 6;
  int j = t & 63;
  if (i >= NN) return;
  float v = z2[(size_t)i * 64 + j];
  float p = fmaxf(v * coef[j] + coef[64 + j], 0.f) * fc3w[j];
  #pragma unroll
  for (int o = 32; o > 0; o >>= 1) p += __shfl_xor(p, o, 64);
  if (j == 0) out[i] = p + fc3b[0];
}

extern "C" void kernel_launch(void* const* d_in, const int* in_sizes, int n_in,
                              void* d_out, int out_size, void* d_ws, size_t ws_size,
                              hipStream_t stream) {
  const float* x     = (const float*)d_in[0];
  const int*   ei    = (const int*)d_in[1];
  const float* w_l1  = (const float*)d_in[2];
  const float* b_l1  = (const float*)d_in[3];
  const float* w_r1  = (const float*)d_in[4];
  const float* w_l2  = (const float*)d_in[5];
  const float* b_l2  = (const float*)d_in[6];
  const float* w_r2  = (const float*)d_in[7];
  const float* fc1_w = (const float*)d_in[8];
  const float* fc1_b = (const float*)d_in[9];
  const float* bn1_g = (const float*)d_in[10];
  const float* bn1_b = (const float*)d_in[11];
  const float* fc2_w = (const float*)d_in[12];
  const float* fc2_b = (const float*)d_in[13];
  const float* bn2_g = (const float*)d_in[14];
  const float* bn2_b = (const float*)d_in[15];
  const float* fc3_w = (const float*)d_in[16];
  const float* fc3_b = (const float*)d_in[17];

  const int E = in_sizes[1] / 2;

  float* ws       = (float*)d_ws;
  int*   rowstart = (int*)(ws + OFF_ROWST);
  int*   rowend   = (int*)(ws + OFF_ROWEN);
  int*   adj      = (int*)(ws + OFF_ADJ);
  float* agg1     = ws + OFF_AGG1;
  float* agg2     = ws + OFF_AGG2;
  unsigned short* xb  = (unsigned short*)(ws + OFF_XB);
  unsigned short* h1b = (unsigned short*)(ws + OFF_H1B);
  float* z1       = ws + OFF_Z1;
  float* z2       = ws + OFF_Z2;
  int*   bukcnt   = (int*)(ws + OFF_BUKCNT);
  float* stats1   = ws + OFF_STATS1;
  float* stats2   = ws + OFF_STATS2;
  float* coef1    = ws + OFF_COEF1;
  float* coef2    = ws + OFF_COEF2;
  int2*  pairs    = (int2*)(ws + OFF_PAIRS);
  unsigned short* wspl = (unsigned short*)(ws + OFF_WSPL);

  float* outv = (float*)d_out;             // [NN]
  float* h1   = outv + NN;                 // [NN,64]
  float* h2   = h1 + (size_t)NN * 64;      // [NN,64]

  hipMemsetAsync(ws + ZERO_START, 0, ZERO_INTS * sizeof(float), stream);

  // one-shot weight splits (hi/lo bf16 planes)
  WsplitArgs wa;
  wa.src[0] = w_l1;  wa.dhi[0] = wspl + WL1_HI; wa.dlo[0] = wspl + WL1_LO; wa.n[0] = 64 * 32;
  wa.src[1] = w_r1;  wa.dhi[1] = wspl + WR1_HI; wa.dlo[1] = wspl + WR1_LO; wa.n[1] = 64 * 32;
  wa.src[2] = w_l2;  wa.dhi[2] = wspl + WL2_HI; wa.dlo[2] = wspl + WL2_LO; wa.n[2] = 64 * 64;
  wa.src[3] = w_r2;  wa.dhi[3] = wspl + WR2_HI; wa.dlo[3] = wspl + WR2_LO; wa.n[3] = 64 * 64;
  wa.src[4] = fc1_w; wa.dhi[4] = wspl + F1_HI;  wa.dlo[4] = wspl + F1_LO;  wa.n[4] = 128 * 64;
  wa.src[5] = fc2_w; wa.dhi[5] = wspl + F2_HI;  wa.dlo[5] = wspl + F2_LO;  wa.n[5] = 64 * 128;
  wsplit_k<<<dim3(8, 6), 256, 0, stream>>>(wa);

  // bf16 copy of x for cheap gathering
  cvt_bf_k<<<(NN * 32 / 8 + 255) / 256, 256, 0, stream>>>(x, xb, NN * 32 / 8);

  // CSR build — fixed-capacity bucket partition, per-node work in LDS
  const int NCH = (E + CHUNK - 1) / CHUNK;
  bpart2_k<<<NCH, 256, 0, stream>>>(ei, E, bukcnt, pairs);
  bfill2_k<<<NBUK, 256, 0, stream>>>(pairs, bukcnt, rowstart, rowend, adj);

  const int MB = (NN + 63) / 64;   // MFMA dense grid: 64 rows per block

  // layer 1 (gather bf16 x; dense emits h1 f32 + h1b bf16 for next gather)
  aggregate_bf<32><<<(NN + 31) / 32, 256, 0, stream>>>(xb, rowstart, rowend, adj, agg1);
  mfma_dense<32, 64, true, false, true, true><<<MB, 256, 0, stream>>>(
      agg1, x, wspl + WL1_HI, wspl + WL1_LO, wspl + WR1_HI, wspl + WR1_LO,
      b_l1, nullptr, h1, h1b);

  // layer 2
  aggregate_bf<64><<<(NN + 15) / 16, 256, 0, stream>>>(h1b, rowstart, rowend, adj, agg2);
  mfma_dense<64, 64, true, false, true, false><<<MB, 256, 0, stream>>>(
      agg2, h1, wspl + WL2_HI, wspl + WL2_LO, wspl + WR2_HI, wspl + WR2_LO,
      b_l2, nullptr, h2, nullptr);

  // fc1 -> z1 (raw, pre-BN)
  mfma_dense<64, 128, false, false, false, false><<<MB, 256, 0, stream>>>(
      h2, nullptr, wspl + F1_HI, wspl + F1_LO, nullptr, nullptr,
      fc1_b, nullptr, z1, nullptr);
  colstats<128><<<512, 256, 0, stream>>>(z1, stats1);
  bncoef<<<1, 128, 0, stream>>>(stats1, bn1_g, bn1_b, coef1, 128);

  // fc2 with fused bn1+relu on input -> z2 (raw, pre-BN)
  mfma_dense<128, 64, false, true, false, false><<<MB, 256, 0, stream>>>(
      z1, nullptr, wspl + F2_HI, wspl + F2_LO, nullptr, nullptr,
      fc2_b, coef1, z2, nullptr);
  colstats<64><<<512, 256, 0, stream>>>(z2, stats2);
  bncoef<<<1, 64, 0, stream>>>(stats2, bn2_g, bn2_b, coef2, 64);

  // bn2 + relu + fc3 fused
  final_k<<<(NN * 64 + 255) / 256, 256, 0, stream>>>(z2, coef2, fc3_w, fc3_b, outv);
}

// Round 13
// 282.314 us; speedup vs baseline: 12.8784x; 1.1843x over previous
//
#include <hip/hip_runtime.h>

#define NN 100000
#define EPS 1e-5f

// ---- workspace layout (4-byte units), ~82MB total ----
static const size_t OFF_ROWST  = 0;           // rowstart [100k]
static const size_t OFF_ROWEN  = 100000;      // rowend   [100k]
static const size_t OFF_ADJ    = 200000;      // adj [256*10496] -> 2,886,976
static const size_t OFF_AGG1   = 2886976;     // N*32 f32 -> 6,086,976
static const size_t OFF_AGG2   = 6086976;     // N*64 f32 -> 12,486,976
static const size_t OFF_PAIRS  = 2886976;     // aliases agg1+agg2 (dead before agg1 written)
static const size_t OFF_XB     = 12486976;    // N*32 bf16 -> 14,086,976
static const size_t OFF_Z1     = 0;           // N*128 f32 [0..12.8M): dead by fc1
static const size_t OFF_H1B    = 14086976;    // N*64 bf16 -> 17,286,976
static const size_t OFF_Z2     = 14086976;    // aliases h1b -> 20,486,976
static const size_t OFF_BUKCNT = 20486976;    // 256 ints
static const size_t OFF_STATS1 = 20487232;    // 256
static const size_t OFF_STATS2 = 20487488;    // 128
static const size_t OFF_COEF1  = 20487616;    // 256
static const size_t OFF_COEF2  = 20487872;    // 128
static const size_t OFF_WSPL   = 20488000;    // 57,344 ushorts
static const size_t ZERO_START = 20486976;    // bukcnt + stats1 + stats2
static const size_t ZERO_INTS  = 640;

// split-weight plane offsets (ushort units within WSPL)
#define WL1_HI 0
#define WL1_LO 2048
#define WR1_HI 4096
#define WR1_LO 6144
#define WL2_HI 8192
#define WL2_LO 12288
#define WR2_HI 16384
#define WR2_LO 20480
#define F1_HI  24576
#define F1_LO  32768
#define F2_HI  40960
#define F2_LO  49152

#define NBUK 256
#define BSHIFT 9                              // 512 nodes per bucket
#define BCAP 10496                            // mean 8192 + 25 sigma
#define CHUNK 2048

typedef __attribute__((ext_vector_type(8))) short short8;
typedef __attribute__((ext_vector_type(4))) float f32x4;

#define MFMA_16x16x32(a, b, c) __builtin_amdgcn_mfma_f32_16x16x32_bf16(a, b, c, 0, 0, 0)

// f32 -> bf16 (RNE) at bit level
__device__ inline unsigned short f2bf(float f) {
  unsigned u = __builtin_bit_cast(unsigned, f);
  unsigned r = (u + 0x7fffu + ((u >> 16) & 1u)) >> 16;
  return (unsigned short)r;
}
__device__ inline float bf2f(unsigned short h) {
  unsigned u = ((unsigned)h) << 16;
  return __builtin_bit_cast(float, u);
}

// load 8 contiguous f32 (optionally BN+relu transformed), split into hi/lo bf16
template<bool BNIN>
__device__ inline void load_split(const float* __restrict__ p,
                                  const float* __restrict__ ca,
                                  const float* __restrict__ cc,
                                  short8& hi, short8& lo) {
  #pragma unroll
  for (int j = 0; j < 8; ++j) {
    float v = p[j];
    if (BNIN) v = fmaxf(v * ca[j] + cc[j], 0.f);
    unsigned short h = f2bf(v);
    hi[j] = (short)h;
    lo[j] = (short)f2bf(v - bf2f(h));
  }
}

// ---- one-shot: split all 6 weight matrices into hi/lo bf16 planes ----
struct WsplitArgs {
  const float* src[6];
  unsigned short* dhi[6];
  unsigned short* dlo[6];
  int n[6];
};
__global__ __launch_bounds__(256) void wsplit_k(WsplitArgs a) {
  int m = blockIdx.y;
  int n = a.n[m];
  for (int i = blockIdx.x * 256 + threadIdx.x; i < n; i += gridDim.x * 256) {
    float v = a.src[m][i];
    unsigned short h = f2bf(v);
    a.dhi[m][i] = h;
    a.dlo[m][i] = f2bf(v - bf2f(h));
  }
}

// ---- convert f32 plane -> bf16 plane (for cheap gathers) ----
__global__ __launch_bounds__(256) void cvt_bf_k(const float* __restrict__ in,
                                                unsigned short* __restrict__ out,
                                                int n8) {
  int t = blockIdx.x * 256 + threadIdx.x;
  if (t >= n8) return;
  const float4* p = (const float4*)(in + (size_t)t * 8);
  float4 a = p[0], b = p[1];
  ushort4 u0, u1;
  u0.x = f2bf(a.x); u0.y = f2bf(a.y); u0.z = f2bf(a.z); u0.w = f2bf(a.w);
  u1.x = f2bf(b.x); u1.y = f2bf(b.y); u1.z = f2bf(b.z); u1.w = f2bf(b.w);
  ((ushort4*)(out + (size_t)t * 8))[0] = u0;
  ((ushort4*)(out + (size_t)t * 8))[1] = u1;
}

// ---- build 1: partition edges into fixed-capacity bucket pair arrays ----
__global__ __launch_bounds__(256) void bpart2_k(const int* __restrict__ ei, int E,
                                                int* __restrict__ bukcnt,
                                                int2* __restrict__ pairs) {
  __shared__ int h[NBUK], wb[NBUK], cur[NBUK];
  int tid = threadIdx.x;
  h[tid] = 0; cur[tid] = 0;
  __syncthreads();
  int lo = blockIdx.x * CHUNK, hi = min(lo + CHUNK, E);
  for (int e = lo + tid; e < hi; e += 256) {
    int t = ei[E + e];
    if ((unsigned)t < NN) atomicAdd(&h[t >> BSHIFT], 1);
  }
  __syncthreads();
  wb[tid] = h[tid] ? atomicAdd(&bukcnt[tid], h[tid]) : 0;
  __syncthreads();
  for (int e = lo + tid; e < hi; e += 256) {
    int s = ei[e], t = ei[E + e];
    if ((unsigned)t >= NN) continue;
    if ((unsigned)s >= NN) s = 0;            // clamp (keeps count/write in sync)
    int b = t >> BSHIFT;
    int off = atomicAdd(&cur[b], 1);
    pairs[(size_t)b * BCAP + wb[b] + off] = make_int2(s, t);
  }
}

// ---- build 2: per-bucket LDS histogram + scan -> rowstart/rowend + adj fill ----
__global__ __launch_bounds__(256) void bfill2_k(const int2* __restrict__ pairs,
                                                const int* __restrict__ bukcnt,
                                                int* __restrict__ rowstart,
                                                int* __restrict__ rowend,
                                                int* __restrict__ adj) {
  __shared__ int d[512];
  __shared__ int part[256];
  int b = blockIdx.x;
  int t = threadIdx.x;
  int base = b * BCAP, cnt = bukcnt[b];
  d[t] = 0; d[t + 256] = 0;
  __syncthreads();
  for (int p = base + t; p < base + cnt; p += 256)
    atomicAdd(&d[pairs[p].y & 511], 1);
  __syncthreads();
  int d0 = d[2 * t], d1 = d[2 * t + 1];
  part[t] = d0 + d1;
  __syncthreads();
  for (int o = 1; o < 256; o <<= 1) {
    int u = (t >= o) ? part[t - o] : 0;
    __syncthreads();
    part[t] += u;
    __syncthreads();
  }
  int e0 = (t > 0) ? part[t - 1] : 0;
  int e1 = e0 + d0;
  d[2 * t] = e0;            // becomes LDS cursor
  d[2 * t + 1] = e1;
  int n0 = (b << BSHIFT) + 2 * t;
  if (n0 < NN)     { rowstart[n0]     = base + e0; rowend[n0]     = base + e1; }
  if (n0 + 1 < NN) { rowstart[n0 + 1] = base + e1; rowend[n0 + 1] = base + e1 + d1; }
  __syncthreads();
  for (int p = base + t; p < base + cnt; p += 256) {
    int2 pr = pairs[p];
    int pos = atomicAdd(&d[pr.y & 511], 1);
    adj[base + pos] = pr.x;
  }
}

// ---- gather-side mean aggregation, ushort4-vectorized: K/4 lanes per node ----
template<int K>
__global__ __launch_bounds__(256) void aggregate_bf(const unsigned short* __restrict__ xb,
                                                    const int* __restrict__ rowstart,
                                                    const int* __restrict__ rowend,
                                                    const int* __restrict__ adj,
                                                    float* __restrict__ agg) {
  constexpr int GL = K / 4;                   // lanes per node
  constexpr int NPB = 256 / GL;
  int lg = threadIdx.x & (GL - 1);
  int node = blockIdx.x * NPB + (threadIdx.x / GL);
  if (node >= NN) return;
  int s0 = rowstart[node], s1 = rowend[node];
  float4 a0 = {0,0,0,0}, a1 = {0,0,0,0}, a2 = {0,0,0,0}, a3 = {0,0,0,0};
  int e = s0;
  for (; e + 3 < s1; e += 4) {                // 4 independent chains
    int i0 = adj[e], i1 = adj[e+1], i2 = adj[e+2], i3 = adj[e+3];
    ushort4 u0 = *(const ushort4*)(xb + (size_t)i0 * K + lg * 4);
    ushort4 u1 = *(const ushort4*)(xb + (size_t)i1 * K + lg * 4);
    ushort4 u2 = *(const ushort4*)(xb + (size_t)i2 * K + lg * 4);
    ushort4 u3 = *(const ushort4*)(xb + (size_t)i3 * K + lg * 4);
    a0.x += bf2f(u0.x); a0.y += bf2f(u0.y); a0.z += bf2f(u0.z); a0.w += bf2f(u0.w);
    a1.x += bf2f(u1.x); a1.y += bf2f(u1.y); a1.z += bf2f(u1.z); a1.w += bf2f(u1.w);
    a2.x += bf2f(u2.x); a2.y += bf2f(u2.y); a2.z += bf2f(u2.z); a2.w += bf2f(u2.w);
    a3.x += bf2f(u3.x); a3.y += bf2f(u3.y); a3.z += bf2f(u3.z); a3.w += bf2f(u3.w);
  }
  for (; e < s1; ++e) {
    ushort4 u = *(const ushort4*)(xb + (size_t)adj[e] * K + lg * 4);
    a0.x += bf2f(u.x); a0.y += bf2f(u.y); a0.z += bf2f(u.z); a0.w += bf2f(u.w);
  }
  float inv = 1.0f / fmaxf((float)(s1 - s0), 1.0f);
  float4 r;
  r.x = (a0.x + a1.x + a2.x + a3.x) * inv;
  r.y = (a0.y + a1.y + a2.y + a3.y) * inv;
  r.z = (a0.z + a1.z + a2.z + a3.z) * inv;
  r.w = (a0.w + a1.w + a2.w + a3.w) * inv;
  *(float4*)(agg + (size_t)node * K + lg * 4) = r;
}

// ---- MFMA dense layer; weights pre-split + staged in LDS (XOR-swizzled) ----
// Optional fused column-stats (sum, sumsq) into `stats` (for BN two-pass).
template<int K, int C, bool SAGE, bool BNIN, bool RELU, bool BFOUT, bool STATS>
__global__ __launch_bounds__(256) void mfma_dense(const float* __restrict__ inA,
                                                  const float* __restrict__ inB,
                                                  const unsigned short* __restrict__ whiA,
                                                  const unsigned short* __restrict__ wloA,
                                                  const unsigned short* __restrict__ whiB,
                                                  const unsigned short* __restrict__ wloB,
                                                  const float* __restrict__ bias,
                                                  const float* __restrict__ coef,
                                                  float* __restrict__ out,
                                                  unsigned short* __restrict__ outb,
                                                  float* __restrict__ stats) {
  constexpr int KF = K / 32;
  constexpr int KC = K / 8;                   // 16B chunks per weight row
  constexpr int SWZ = (KC < 8 ? KC : 8) - 1;  // xor-swizzle mask (T2)
  __shared__ unsigned short swhiA[C * K], swloA[C * K];
  __shared__ unsigned short swhiB[SAGE ? C * K : 8], swloB[SAGE ? C * K : 8];
  __shared__ float ls[STATS ? C : 1], lq[STATS ? C : 1];

  int tid = threadIdx.x;
  // cooperative swizzled staging of weight planes
  for (int i = tid; i < C * KC; i += 256) {
    int col = i / KC, c = i % KC;
    int pos = col * KC + (c ^ (col & SWZ));
    ((short8*)swhiA)[pos] = ((const short8*)whiA)[i];
    ((short8*)swloA)[pos] = ((const short8*)wloA)[i];
    if (SAGE) {
      ((short8*)swhiB)[pos] = ((const short8*)whiB)[i];
      ((short8*)swloB)[pos] = ((const short8*)wloB)[i];
    }
  }
  if (STATS) {
    for (int i = tid; i < C; i += 256) { ls[i] = 0.f; lq[i] = 0.f; }
  }
  __syncthreads();

  int wid  = tid >> 6;
  int lane = tid & 63;
  int row0 = blockIdx.x * 64 + wid * 16;
  int r = lane & 15, g = lane >> 4;
  int arow = row0 + r; if (arow > NN - 1) arow = NN - 1;   // clamp tail reads
  int koff = g * 8;

  short8 ahi[KF], alo[KF];
  short8 a2hi[SAGE ? KF : 1], a2lo[SAGE ? KF : 1];
  #pragma unroll
  for (int kf = 0; kf < KF; ++kf) {
    const float* p = inA + (size_t)arow * K + kf * 32 + koff;
    load_split<BNIN>(p, coef + kf * 32 + koff, coef + K + kf * 32 + koff,
                     ahi[kf], alo[kf]);
  }
  if (SAGE) {
    #pragma unroll
    for (int kf = 0; kf < KF; ++kf) {
      const float* p = inB + (size_t)arow * K + kf * 32 + koff;
      load_split<false>(p, nullptr, nullptr, a2hi[kf], a2lo[kf]);
    }
  }

  #pragma unroll
  for (int cf = 0; cf < C / 16; ++cf) {
    int col = cf * 16 + r;
    float bv = bias[col];
    f32x4 acc = {bv, bv, bv, bv};
    #pragma unroll
    for (int kf = 0; kf < KF; ++kf) {
      int c = kf * 4 + g;
      int pos = col * KC + (c ^ (col & SWZ));
      short8 whi = ((const short8*)swhiA)[pos];
      short8 wlo = ((const short8*)swloA)[pos];
      acc = MFMA_16x16x32(ahi[kf], whi, acc);
      acc = MFMA_16x16x32(ahi[kf], wlo, acc);
      acc = MFMA_16x16x32(alo[kf], whi, acc);
      if (SAGE) {
        short8 vhi = ((const short8*)swhiB)[pos];
        short8 vlo = ((const short8*)swloB)[pos];
        acc = MFMA_16x16x32(a2hi[kf], vhi, acc);
        acc = MFMA_16x16x32(a2hi[kf], vlo, acc);
        acc = MFMA_16x16x32(a2lo[kf], vhi, acc);
      }
    }
    if (STATS) {
      float s = 0.f, q = 0.f;
      #pragma unroll
      for (int j = 0; j < 4; ++j) {
        if (row0 + g * 4 + j < NN) {
          float v = acc[j];
          s += v; q += v * v;
        }
      }
      s += __shfl_xor(s, 16, 64); s += __shfl_xor(s, 32, 64);
      q += __shfl_xor(q, 16, 64); q += __shfl_xor(q, 32, 64);
      if (g == 0) { atomicAdd(&ls[col], s); atomicAdd(&lq[col], q); }
    }
    #pragma unroll
    for (int j = 0; j < 4; ++j) {
      int orow = row0 + g * 4 + j;
      if (orow < NN) {
        float v = acc[j];
        if (RELU) v = fmaxf(v, 0.f);
        out[(size_t)orow * C + col] = v;
        if (BFOUT) outb[(size_t)orow * C + col] = f2bf(v);
      }
    }
  }
  if (STATS) {
    __syncthreads();
    for (int i = tid; i < C; i += 256) {
      atomicAdd(&stats[i], ls[i]);
      atomicAdd(&stats[C + i], lq[i]);
    }
  }
}

// ---- stats -> affine coefs: y = v*a + c ----
__global__ void bncoef(const float* __restrict__ stats, const float* __restrict__ g,
                       const float* __restrict__ b, float* __restrict__ coef, int C) {
  int j = threadIdx.x;
  if (j >= C) return;
  float mu  = stats[j] * (1.0f / NN);
  float var = stats[C + j] * (1.0f / NN) - mu * mu;
  float a = g[j] * rsqrtf(var + EPS);
  coef[j] = a;
  coef[C + j] = b[j] - mu * a;
}

// ---- final: out[i] = sum_j relu(z2[i][j]*a+c) * fc3w[j] + fc3b ----
__global__ __launch_bounds__(256) void final_k(const float* __restrict__ z2,
                                               const float* __restrict__ coef,
                                               const float* __restrict__ fc3w,
                                               const float* __restrict__ fc3b,
                                               float* __restrict__ out) {
  int t = blockIdx.x * 256 + threadIdx.x;
  int i = t >> 6;
  int j = t & 63;
  if (i >= NN) return;
  float v = z2[(size_t)i * 64 + j];
  float p = fmaxf(v * coef[j] + coef[64 + j], 0.f) * fc3w[j];
  #pragma unroll
  for (int o = 32; o > 0; o >>= 1) p += __shfl_xor(p, o, 64);
  if (j == 0) out[i] = p + fc3b[0];
}

extern "C" void kernel_launch(void* const* d_in, const int* in_sizes, int n_in,
                              void* d_out, int out_size, void* d_ws, size_t ws_size,
                              hipStream_t stream) {
  const float* x     = (const float*)d_in[0];
  const int*   ei    = (const int*)d_in[1];
  const float* w_l1  = (const float*)d_in[2];
  const float* b_l1  = (const float*)d_in[3];
  const float* w_r1  = (const float*)d_in[4];
  const float* w_l2  = (const float*)d_in[5];
  const float* b_l2  = (const float*)d_in[6];
  const float* w_r2  = (const float*)d_in[7];
  const float* fc1_w = (const float*)d_in[8];
  const float* fc1_b = (const float*)d_in[9];
  const float* bn1_g = (const float*)d_in[10];
  const float* bn1_b = (const float*)d_in[11];
  const float* fc2_w = (const float*)d_in[12];
  const float* fc2_b = (const float*)d_in[13];
  const float* bn2_g = (const float*)d_in[14];
  const float* bn2_b = (const float*)d_in[15];
  const float* fc3_w = (const float*)d_in[16];
  const float* fc3_b = (const float*)d_in[17];

  const int E = in_sizes[1] / 2;

  float* ws       = (float*)d_ws;
  int*   rowstart = (int*)(ws + OFF_ROWST);
  int*   rowend   = (int*)(ws + OFF_ROWEN);
  int*   adj      = (int*)(ws + OFF_ADJ);
  float* agg1     = ws + OFF_AGG1;
  float* agg2     = ws + OFF_AGG2;
  unsigned short* xb  = (unsigned short*)(ws + OFF_XB);
  unsigned short* h1b = (unsigned short*)(ws + OFF_H1B);
  float* z1       = ws + OFF_Z1;
  float* z2       = ws + OFF_Z2;
  int*   bukcnt   = (int*)(ws + OFF_BUKCNT);
  float* stats1   = ws + OFF_STATS1;
  float* stats2   = ws + OFF_STATS2;
  float* coef1    = ws + OFF_COEF1;
  float* coef2    = ws + OFF_COEF2;
  int2*  pairs    = (int2*)(ws + OFF_PAIRS);
  unsigned short* wspl = (unsigned short*)(ws + OFF_WSPL);

  float* outv = (float*)d_out;             // [NN]
  float* h1   = outv + NN;                 // [NN,64]
  float* h2   = h1 + (size_t)NN * 64;      // [NN,64]

  hipMemsetAsync(ws + ZERO_START, 0, ZERO_INTS * sizeof(float), stream);

  // one-shot weight splits (hi/lo bf16 planes)
  WsplitArgs wa;
  wa.src[0] = w_l1;  wa.dhi[0] = wspl + WL1_HI; wa.dlo[0] = wspl + WL1_LO; wa.n[0] = 64 * 32;
  wa.src[1] = w_r1;  wa.dhi[1] = wspl + WR1_HI; wa.dlo[1] = wspl + WR1_LO; wa.n[1] = 64 * 32;
  wa.src[2] = w_l2;  wa.dhi[2] = wspl + WL2_HI; wa.dlo[2] = wspl + WL2_LO; wa.n[2] = 64 * 64;
  wa.src[3] = w_r2;  wa.dhi[3] = wspl + WR2_HI; wa.dlo[3] = wspl + WR2_LO; wa.n[3] = 64 * 64;
  wa.src[4] = fc1_w; wa.dhi[4] = wspl + F1_HI;  wa.dlo[4] = wspl + F1_LO;  wa.n[4] = 128 * 64;
  wa.src[5] = fc2_w; wa.dhi[5] = wspl + F2_HI;  wa.dlo[5] = wspl + F2_LO;  wa.n[5] = 64 * 128;
  wsplit_k<<<dim3(8, 6), 256, 0, stream>>>(wa);

  // bf16 copy of x for cheap gathering
  cvt_bf_k<<<(NN * 32 / 8 + 255) / 256, 256, 0, stream>>>(x, xb, NN * 32 / 8);

  // CSR build — fixed-capacity bucket partition, per-node work in LDS
  const int NCH = (E + CHUNK - 1) / CHUNK;
  bpart2_k<<<NCH, 256, 0, stream>>>(ei, E, bukcnt, pairs);
  bfill2_k<<<NBUK, 256, 0, stream>>>(pairs, bukcnt, rowstart, rowend, adj);

  const int MB = (NN + 63) / 64;   // MFMA dense grid: 64 rows per block

  // layer 1 (gather bf16 x; dense emits h1 f32 + h1b bf16 for next gather)
  aggregate_bf<32><<<(NN + 31) / 32, 256, 0, stream>>>(xb, rowstart, rowend, adj, agg1);
  mfma_dense<32, 64, true, false, true, true, false><<<MB, 256, 0, stream>>>(
      agg1, x, wspl + WL1_HI, wspl + WL1_LO, wspl + WR1_HI, wspl + WR1_LO,
      b_l1, nullptr, h1, h1b, nullptr);

  // layer 2
  aggregate_bf<64><<<(NN + 15) / 16, 256, 0, stream>>>(h1b, rowstart, rowend, adj, agg2);
  mfma_dense<64, 64, true, false, true, false, false><<<MB, 256, 0, stream>>>(
      agg2, h1, wspl + WL2_HI, wspl + WL2_LO, wspl + WR2_HI, wspl + WR2_LO,
      b_l2, nullptr, h2, nullptr, nullptr);

  // fc1 -> z1 (raw, pre-BN) with fused column stats
  mfma_dense<64, 128, false, false, false, false, true><<<MB, 256, 0, stream>>>(
      h2, nullptr, wspl + F1_HI, wspl + F1_LO, nullptr, nullptr,
      fc1_b, nullptr, z1, nullptr, stats1);
  bncoef<<<1, 128, 0, stream>>>(stats1, bn1_g, bn1_b, coef1, 128);

  // fc2 with fused bn1+relu on input -> z2 (raw, pre-BN) with fused stats
  mfma_dense<128, 64, false, true, false, false, true><<<MB, 256, 0, stream>>>(
      z1, nullptr, wspl + F2_HI, wspl + F2_LO, nullptr, nullptr,
      fc2_b, coef1, z2, nullptr, stats2);
  bncoef<<<1, 64, 0, stream>>>(stats2, bn2_g, bn2_b, coef2, 64);

  // bn2 + relu + fc3 fused
  final_k<<<(NN * 64 + 255) / 256, 256, 0, stream>>>(z2, coef2, fc3_w, fc3_b, outv);
}

// Round 14
// 245.703 us; speedup vs baseline: 14.7973x; 1.1490x over previous
//
#include <hip/hip_runtime.h>

#define NN 100000
#define EPS 1e-5f

// ---- workspace layout (4-byte units), ~82MB total ----
static const size_t OFF_ROWST  = 0;           // rowstart [100k]
static const size_t OFF_ROWEN  = 100000;      // rowend   [100k]
static const size_t OFF_ADJ    = 200000;      // adj [256*10496] -> 2,886,976
static const size_t OFF_AGG1   = 2886976;     // N*32 f32 -> 6,086,976
static const size_t OFF_AGG2   = 6086976;     // N*64 f32 -> 12,486,976
static const size_t OFF_PAIRS  = 2886976;     // aliases agg1+agg2 (dead before agg1 written)
static const size_t OFF_XB     = 12486976;    // N*32 bf16 -> 14,086,976
static const size_t OFF_Z1     = 0;           // N*128 f32 [0..12.8M): dead by fc1
static const size_t OFF_H1B    = 14086976;    // N*64 bf16 -> 17,286,976
static const size_t OFF_Z2     = 14086976;    // aliases h1b -> 20,486,976
static const size_t OFF_WSPL   = 20487000;    // 57,344 ushorts = 28,672 floats -> 20,515,672
static const size_t OFF_BUKCNT = 20515712;    // 256 ints
static const size_t OFF_STATS1 = 20515968;    // 128 slots * 256 = 32,768 -> 20,548,736
static const size_t OFF_STATS2 = 20548736;    // 128 slots * 128 = 16,384 -> 20,565,120
static const size_t OFF_COEF1  = 20565120;    // 256
static const size_t OFF_COEF2  = 20565376;    // 128
static const size_t ZERO_START = 20515712;    // bukcnt + both slotted stats
static const size_t ZERO_INTS  = 49664;

#define NSLOT 128                             // stats slots (atomic-contention spreader)

// split-weight plane offsets (ushort units within WSPL)
#define WL1_HI 0
#define WL1_LO 2048
#define WR1_HI 4096
#define WR1_LO 6144
#define WL2_HI 8192
#define WL2_LO 12288
#define WR2_HI 16384
#define WR2_LO 20480
#define F1_HI  24576
#define F1_LO  32768
#define F2_HI  40960
#define F2_LO  49152

#define NBUK 256
#define BSHIFT 9                              // 512 nodes per bucket
#define BCAP 10496                            // mean 8192 + 25 sigma
#define CHUNK 2048

typedef __attribute__((ext_vector_type(8))) short short8;
typedef __attribute__((ext_vector_type(4))) float f32x4;

#define MFMA_16x16x32(a, b, c) __builtin_amdgcn_mfma_f32_16x16x32_bf16(a, b, c, 0, 0, 0)

// f32 -> bf16 (RNE) at bit level
__device__ inline unsigned short f2bf(float f) {
  unsigned u = __builtin_bit_cast(unsigned, f);
  unsigned r = (u + 0x7fffu + ((u >> 16) & 1u)) >> 16;
  return (unsigned short)r;
}
__device__ inline float bf2f(unsigned short h) {
  unsigned u = ((unsigned)h) << 16;
  return __builtin_bit_cast(float, u);
}

// load 8 contiguous f32 (optionally BN+relu transformed), split into hi/lo bf16
template<bool BNIN>
__device__ inline void load_split(const float* __restrict__ p,
                                  const float* __restrict__ ca,
                                  const float* __restrict__ cc,
                                  short8& hi, short8& lo) {
  #pragma unroll
  for (int j = 0; j < 8; ++j) {
    float v = p[j];
    if (BNIN) v = fmaxf(v * ca[j] + cc[j], 0.f);
    unsigned short h = f2bf(v);
    hi[j] = (short)h;
    lo[j] = (short)f2bf(v - bf2f(h));
  }
}

// ---- one-shot: split all 6 weight matrices into hi/lo bf16 planes ----
struct WsplitArgs {
  const float* src[6];
  unsigned short* dhi[6];
  unsigned short* dlo[6];
  int n[6];
};
__global__ __launch_bounds__(256) void wsplit_k(WsplitArgs a) {
  int m = blockIdx.y;
  int n = a.n[m];
  for (int i = blockIdx.x * 256 + threadIdx.x; i < n; i += gridDim.x * 256) {
    float v = a.src[m][i];
    unsigned short h = f2bf(v);
    a.dhi[m][i] = h;
    a.dlo[m][i] = f2bf(v - bf2f(h));
  }
}

// ---- convert f32 plane -> bf16 plane (for cheap gathers) ----
__global__ __launch_bounds__(256) void cvt_bf_k(const float* __restrict__ in,
                                                unsigned short* __restrict__ out,
                                                int n8) {
  int t = blockIdx.x * 256 + threadIdx.x;
  if (t >= n8) return;
  const float4* p = (const float4*)(in + (size_t)t * 8);
  float4 a = p[0], b = p[1];
  ushort4 u0, u1;
  u0.x = f2bf(a.x); u0.y = f2bf(a.y); u0.z = f2bf(a.z); u0.w = f2bf(a.w);
  u1.x = f2bf(b.x); u1.y = f2bf(b.y); u1.z = f2bf(b.z); u1.w = f2bf(b.w);
  ((ushort4*)(out + (size_t)t * 8))[0] = u0;
  ((ushort4*)(out + (size_t)t * 8))[1] = u1;
}

// ---- build 1: partition edges into fixed-capacity bucket pair arrays ----
__global__ __launch_bounds__(256) void bpart2_k(const int* __restrict__ ei, int E,
                                                int* __restrict__ bukcnt,
                                                int2* __restrict__ pairs) {
  __shared__ int h[NBUK], wb[NBUK], cur[NBUK];
  int tid = threadIdx.x;
  h[tid] = 0; cur[tid] = 0;
  __syncthreads();
  int lo = blockIdx.x * CHUNK, hi = min(lo + CHUNK, E);
  for (int e = lo + tid; e < hi; e += 256) {
    int t = ei[E + e];
    if ((unsigned)t < NN) atomicAdd(&h[t >> BSHIFT], 1);
  }
  __syncthreads();
  wb[tid] = h[tid] ? atomicAdd(&bukcnt[tid], h[tid]) : 0;
  __syncthreads();
  for (int e = lo + tid; e < hi; e += 256) {
    int s = ei[e], t = ei[E + e];
    if ((unsigned)t >= NN) continue;
    if ((unsigned)s >= NN) s = 0;            // clamp (keeps count/write in sync)
    int b = t >> BSHIFT;
    int off = atomicAdd(&cur[b], 1);
    pairs[(size_t)b * BCAP + wb[b] + off] = make_int2(s, t);
  }
}

// ---- build 2: per-bucket LDS histogram + scan -> rowstart/rowend + adj fill ----
__global__ __launch_bounds__(256) void bfill2_k(const int2* __restrict__ pairs,
                                                const int* __restrict__ bukcnt,
                                                int* __restrict__ rowstart,
                                                int* __restrict__ rowend,
                                                int* __restrict__ adj) {
  __shared__ int d[512];
  __shared__ int part[256];
  int b = blockIdx.x;
  int t = threadIdx.x;
  int base = b * BCAP, cnt = bukcnt[b];
  d[t] = 0; d[t + 256] = 0;
  __syncthreads();
  for (int p = base + t; p < base + cnt; p += 256)
    atomicAdd(&d[pairs[p].y & 511], 1);
  __syncthreads();
  int d0 = d[2 * t], d1 = d[2 * t + 1];
  part[t] = d0 + d1;
  __syncthreads();
  for (int o = 1; o < 256; o <<= 1) {
    int u = (t >= o) ? part[t - o] : 0;
    __syncthreads();
    part[t] += u;
    __syncthreads();
  }
  int e0 = (t > 0) ? part[t - 1] : 0;
  int e1 = e0 + d0;
  d[2 * t] = e0;            // becomes LDS cursor
  d[2 * t + 1] = e1;
  int n0 = (b << BSHIFT) + 2 * t;
  if (n0 < NN)     { rowstart[n0]     = base + e0; rowend[n0]     = base + e1; }
  if (n0 + 1 < NN) { rowstart[n0 + 1] = base + e1; rowend[n0 + 1] = base + e1 + d1; }
  __syncthreads();
  for (int p = base + t; p < base + cnt; p += 256) {
    int2 pr = pairs[p];
    int pos = atomicAdd(&d[pr.y & 511], 1);
    adj[base + pos] = pr.x;
  }
}

// ---- gather-side mean aggregation, ushort4-vectorized: K/4 lanes per node ----
template<int K>
__global__ __launch_bounds__(256) void aggregate_bf(const unsigned short* __restrict__ xb,
                                                    const int* __restrict__ rowstart,
                                                    const int* __restrict__ rowend,
                                                    const int* __restrict__ adj,
                                                    float* __restrict__ agg) {
  constexpr int GL = K / 4;                   // lanes per node
  constexpr int NPB = 256 / GL;
  int lg = threadIdx.x & (GL - 1);
  int node = blockIdx.x * NPB + (threadIdx.x / GL);
  if (node >= NN) return;
  int s0 = rowstart[node], s1 = rowend[node];
  float4 a0 = {0,0,0,0}, a1 = {0,0,0,0}, a2 = {0,0,0,0}, a3 = {0,0,0,0};
  int e = s0;
  for (; e + 3 < s1; e += 4) {                // 4 independent chains
    int i0 = adj[e], i1 = adj[e+1], i2 = adj[e+2], i3 = adj[e+3];
    ushort4 u0 = *(const ushort4*)(xb + (size_t)i0 * K + lg * 4);
    ushort4 u1 = *(const ushort4*)(xb + (size_t)i1 * K + lg * 4);
    ushort4 u2 = *(const ushort4*)(xb + (size_t)i2 * K + lg * 4);
    ushort4 u3 = *(const ushort4*)(xb + (size_t)i3 * K + lg * 4);
    a0.x += bf2f(u0.x); a0.y += bf2f(u0.y); a0.z += bf2f(u0.z); a0.w += bf2f(u0.w);
    a1.x += bf2f(u1.x); a1.y += bf2f(u1.y); a1.z += bf2f(u1.z); a1.w += bf2f(u1.w);
    a2.x += bf2f(u2.x); a2.y += bf2f(u2.y); a2.z += bf2f(u2.z); a2.w += bf2f(u2.w);
    a3.x += bf2f(u3.x); a3.y += bf2f(u3.y); a3.z += bf2f(u3.z); a3.w += bf2f(u3.w);
  }
  for (; e < s1; ++e) {
    ushort4 u = *(const ushort4*)(xb + (size_t)adj[e] * K + lg * 4);
    a0.x += bf2f(u.x); a0.y += bf2f(u.y); a0.z += bf2f(u.z); a0.w += bf2f(u.w);
  }
  float inv = 1.0f / fmaxf((float)(s1 - s0), 1.0f);
  float4 r;
  r.x = (a0.x + a1.x + a2.x + a3.x) * inv;
  r.y = (a0.y + a1.y + a2.y + a3.y) * inv;
  r.z = (a0.z + a1.z + a2.z + a3.z) * inv;
  r.w = (a0.w + a1.w + a2.w + a3.w) * inv;
  *(float4*)(agg + (size_t)node * K + lg * 4) = r;
}

// ---- MFMA dense layer; weights pre-split + staged in LDS (XOR-swizzled) ----
// Optional fused column-stats into SLOTTED global stats (slot = bid & (NSLOT-1)).
template<int K, int C, bool SAGE, bool BNIN, bool RELU, bool BFOUT, bool STATS>
__global__ __launch_bounds__(256) void mfma_dense(const float* __restrict__ inA,
                                                  const float* __restrict__ inB,
                                                  const unsigned short* __restrict__ whiA,
                                                  const unsigned short* __restrict__ wloA,
                                                  const unsigned short* __restrict__ whiB,
                                                  const unsigned short* __restrict__ wloB,
                                                  const float* __restrict__ bias,
                                                  const float* __restrict__ coef,
                                                  float* __restrict__ out,
                                                  unsigned short* __restrict__ outb,
                                                  float* __restrict__ stats) {
  constexpr int KF = K / 32;
  constexpr int KC = K / 8;                   // 16B chunks per weight row
  constexpr int SWZ = (KC < 8 ? KC : 8) - 1;  // xor-swizzle mask (T2)
  __shared__ unsigned short swhiA[C * K], swloA[C * K];
  __shared__ unsigned short swhiB[SAGE ? C * K : 8], swloB[SAGE ? C * K : 8];
  __shared__ float ls[STATS ? C : 1], lq[STATS ? C : 1];

  int tid = threadIdx.x;
  // cooperative swizzled staging of weight planes
  for (int i = tid; i < C * KC; i += 256) {
    int col = i / KC, c = i % KC;
    int pos = col * KC + (c ^ (col & SWZ));
    ((short8*)swhiA)[pos] = ((const short8*)whiA)[i];
    ((short8*)swloA)[pos] = ((const short8*)wloA)[i];
    if (SAGE) {
      ((short8*)swhiB)[pos] = ((const short8*)whiB)[i];
      ((short8*)swloB)[pos] = ((const short8*)wloB)[i];
    }
  }
  if (STATS) {
    for (int i = tid; i < C; i += 256) { ls[i] = 0.f; lq[i] = 0.f; }
  }
  __syncthreads();

  int wid  = tid >> 6;
  int lane = tid & 63;
  int row0 = blockIdx.x * 64 + wid * 16;
  int r = lane & 15, g = lane >> 4;
  int arow = row0 + r; if (arow > NN - 1) arow = NN - 1;   // clamp tail reads
  int koff = g * 8;

  short8 ahi[KF], alo[KF];
  short8 a2hi[SAGE ? KF : 1], a2lo[SAGE ? KF : 1];
  #pragma unroll
  for (int kf = 0; kf < KF; ++kf) {
    const float* p = inA + (size_t)arow * K + kf * 32 + koff;
    load_split<BNIN>(p, coef + kf * 32 + koff, coef + K + kf * 32 + koff,
                     ahi[kf], alo[kf]);
  }
  if (SAGE) {
    #pragma unroll
    for (int kf = 0; kf < KF; ++kf) {
      const float* p = inB + (size_t)arow * K + kf * 32 + koff;
      load_split<false>(p, nullptr, nullptr, a2hi[kf], a2lo[kf]);
    }
  }

  #pragma unroll
  for (int cf = 0; cf < C / 16; ++cf) {
    int col = cf * 16 + r;
    float bv = bias[col];
    f32x4 acc = {bv, bv, bv, bv};
    #pragma unroll
    for (int kf = 0; kf < KF; ++kf) {
      int c = kf * 4 + g;
      int pos = col * KC + (c ^ (col & SWZ));
      short8 whi = ((const short8*)swhiA)[pos];
      short8 wlo = ((const short8*)swloA)[pos];
      acc = MFMA_16x16x32(ahi[kf], whi, acc);
      acc = MFMA_16x16x32(ahi[kf], wlo, acc);
      acc = MFMA_16x16x32(alo[kf], whi, acc);
      if (SAGE) {
        short8 vhi = ((const short8*)swhiB)[pos];
        short8 vlo = ((const short8*)swloB)[pos];
        acc = MFMA_16x16x32(a2hi[kf], vhi, acc);
        acc = MFMA_16x16x32(a2hi[kf], vlo, acc);
        acc = MFMA_16x16x32(a2lo[kf], vhi, acc);
      }
    }
    if (STATS) {
      float s = 0.f, q = 0.f;
      #pragma unroll
      for (int j = 0; j < 4; ++j) {
        if (row0 + g * 4 + j < NN) {
          float v = acc[j];
          s += v; q += v * v;
        }
      }
      s += __shfl_xor(s, 16, 64); s += __shfl_xor(s, 32, 64);
      q += __shfl_xor(q, 16, 64); q += __shfl_xor(q, 32, 64);
      if (g == 0) { atomicAdd(&ls[col], s); atomicAdd(&lq[col], q); }
    }
    #pragma unroll
    for (int j = 0; j < 4; ++j) {
      int orow = row0 + g * 4 + j;
      if (orow < NN) {
        float v = acc[j];
        if (RELU) v = fmaxf(v, 0.f);
        out[(size_t)orow * C + col] = v;
        if (BFOUT) outb[(size_t)orow * C + col] = f2bf(v);
      }
    }
  }
  if (STATS) {
    __syncthreads();
    float* sl = stats + (size_t)(blockIdx.x & (NSLOT - 1)) * 2 * C;
    for (int i = tid; i < C; i += 256) {
      atomicAdd(&sl[i], ls[i]);
      atomicAdd(&sl[C + i], lq[i]);
    }
  }
}

// ---- slotted stats -> affine coefs: y = v*a + c ----
__global__ void bncoef(const float* __restrict__ stats, const float* __restrict__ g,
                       const float* __restrict__ b, float* __restrict__ coef, int C) {
  int j = threadIdx.x;
  if (j >= C) return;
  float s = 0.f, q = 0.f;
  for (int sl = 0; sl < NSLOT; ++sl) {
    s += stats[(size_t)sl * 2 * C + j];
    q += stats[(size_t)sl * 2 * C + C + j];
  }
  float mu  = s * (1.0f / NN);
  float var = q * (1.0f / NN) - mu * mu;
  float a = g[j] * rsqrtf(var + EPS);
  coef[j] = a;
  coef[C + j] = b[j] - mu * a;
}

// ---- final: out[i] = sum_j relu(z2[i][j]*a+c) * fc3w[j] + fc3b ----
__global__ __launch_bounds__(256) void final_k(const float* __restrict__ z2,
                                               const float* __restrict__ coef,
                                               const float* __restrict__ fc3w,
                                               const float* __restrict__ fc3b,
                                               float* __restrict__ out) {
  int t = blockIdx.x * 256 + threadIdx.x;
  int i = t >> 6;
  int j = t & 63;
  if (i >= NN) return;
  float v = z2[(size_t)i * 64 + j];
  float p = fmaxf(v * coef[j] + coef[64 + j], 0.f) * fc3w[j];
  #pragma unroll
  for (int o = 32; o > 0; o >>= 1) p += __shfl_xor(p, o, 64);
  if (j == 0) out[i] = p + fc3b[0];
}

extern "C" void kernel_launch(void* const* d_in, const int* in_sizes, int n_in,
                              void* d_out, int out_size, void* d_ws, size_t ws_size,
                              hipStream_t stream) {
  const float* x     = (const float*)d_in[0];
  const int*   ei    = (const int*)d_in[1];
  const float* w_l1  = (const float*)d_in[2];
  const float* b_l1  = (const float*)d_in[3];
  const float* w_r1  = (const float*)d_in[4];
  const float* w_l2  = (const float*)d_in[5];
  const float* b_l2  = (const float*)d_in[6];
  const float* w_r2  = (const float*)d_in[7];
  const float* fc1_w = (const float*)d_in[8];
  const float* fc1_b = (const float*)d_in[9];
  const float* bn1_g = (const float*)d_in[10];
  const float* bn1_b = (const float*)d_in[11];
  const float* fc2_w = (const float*)d_in[12];
  const float* fc2_b = (const float*)d_in[13];
  const float* bn2_g = (const float*)d_in[14];
  const float* bn2_b = (const float*)d_in[15];
  const float* fc3_w = (const float*)d_in[16];
  const float* fc3_b = (const float*)d_in[17];

  const int E = in_sizes[1] / 2;

  float* ws       = (float*)d_ws;
  int*   rowstart = (int*)(ws + OFF_ROWST);
  int*   rowend   = (int*)(ws + OFF_ROWEN);
  int*   adj      = (int*)(ws + OFF_ADJ);
  float* agg1     = ws + OFF_AGG1;
  float* agg2     = ws + OFF_AGG2;
  unsigned short* xb  = (unsigned short*)(ws + OFF_XB);
  unsigned short* h1b = (unsigned short*)(ws + OFF_H1B);
  float* z1       = ws + OFF_Z1;
  float* z2       = ws + OFF_Z2;
  int*   bukcnt   = (int*)(ws + OFF_BUKCNT);
  float* stats1   = ws + OFF_STATS1;
  float* stats2   = ws + OFF_STATS2;
  float* coef1    = ws + OFF_COEF1;
  float* coef2    = ws + OFF_COEF2;
  int2*  pairs    = (int2*)(ws + OFF_PAIRS);
  unsigned short* wspl = (unsigned short*)(ws + OFF_WSPL);

  float* outv = (float*)d_out;             // [NN]
  float* h1   = outv + NN;                 // [NN,64]
  float* h2   = h1 + (size_t)NN * 64;      // [NN,64]

  hipMemsetAsync(ws + ZERO_START, 0, ZERO_INTS * sizeof(float), stream);

  // one-shot weight splits (hi/lo bf16 planes)
  WsplitArgs wa;
  wa.src[0] = w_l1;  wa.dhi[0] = wspl + WL1_HI; wa.dlo[0] = wspl + WL1_LO; wa.n[0] = 64 * 32;
  wa.src[1] = w_r1;  wa.dhi[1] = wspl + WR1_HI; wa.dlo[1] = wspl + WR1_LO; wa.n[1] = 64 * 32;
  wa.src[2] = w_l2;  wa.dhi[2] = wspl + WL2_HI; wa.dlo[2] = wspl + WL2_LO; wa.n[2] = 64 * 64;
  wa.src[3] = w_r2;  wa.dhi[3] = wspl + WR2_HI; wa.dlo[3] = wspl + WR2_LO; wa.n[3] = 64 * 64;
  wa.src[4] = fc1_w; wa.dhi[4] = wspl + F1_HI;  wa.dlo[4] = wspl + F1_LO;  wa.n[4] = 128 * 64;
  wa.src[5] = fc2_w; wa.dhi[5] = wspl + F2_HI;  wa.dlo[5] = wspl + F2_LO;  wa.n[5] = 64 * 128;
  wsplit_k<<<dim3(8, 6), 256, 0, stream>>>(wa);

  // bf16 copy of x for cheap gathering
  cvt_bf_k<<<(NN * 32 / 8 + 255) / 256, 256, 0, stream>>>(x, xb, NN * 32 / 8);

  // CSR build — fixed-capacity bucket partition, per-node work in LDS
  const int NCH = (E + CHUNK - 1) / CHUNK;
  bpart2_k<<<NCH, 256, 0, stream>>>(ei, E, bukcnt, pairs);
  bfill2_k<<<NBUK, 256, 0, stream>>>(pairs, bukcnt, rowstart, rowend, adj);

  const int MB = (NN + 63) / 64;   // MFMA dense grid: 64 rows per block

  // layer 1 (gather bf16 x; dense emits h1 f32 + h1b bf16 for next gather)
  aggregate_bf<32><<<(NN + 31) / 32, 256, 0, stream>>>(xb, rowstart, rowend, adj, agg1);
  mfma_dense<32, 64, true, false, true, true, false><<<MB, 256, 0, stream>>>(
      agg1, x, wspl + WL1_HI, wspl + WL1_LO, wspl + WR1_HI, wspl + WR1_LO,
      b_l1, nullptr, h1, h1b, nullptr);

  // layer 2
  aggregate_bf<64><<<(NN + 15) / 16, 256, 0, stream>>>(h1b, rowstart, rowend, adj, agg2);
  mfma_dense<64, 64, true, false, true, false, false><<<MB, 256, 0, stream>>>(
      agg2, h1, wspl + WL2_HI, wspl + WL2_LO, wspl + WR2_HI, wspl + WR2_LO,
      b_l2, nullptr, h2, nullptr, nullptr);

  // fc1 -> z1 (raw, pre-BN) with fused slotted column stats
  mfma_dense<64, 128, false, false, false, false, true><<<MB, 256, 0, stream>>>(
      h2, nullptr, wspl + F1_HI, wspl + F1_LO, nullptr, nullptr,
      fc1_b, nullptr, z1, nullptr, stats1);
  bncoef<<<1, 128, 0, stream>>>(stats1, bn1_g, bn1_b, coef1, 128);

  // fc2 with fused bn1+relu on input -> z2 (raw, pre-BN) with fused stats
  mfma_dense<128, 64, false, true, false, false, true><<<MB, 256, 0, stream>>>(
      z1, nullptr, wspl + F2_HI, wspl + F2_LO, nullptr, nullptr,
      fc2_b, coef1, z2, nullptr, stats2);
  bncoef<<<1, 64, 0, stream>>>(stats2, bn2_g, bn2_b, coef2, 64);

  // bn2 + relu + fc3 fused
  final_k<<<(NN * 64 + 255) / 256, 256, 0, stream>>>(z2, coef2, fc3_w, fc3_b, outv);
}

// Round 15
// 241.888 us; speedup vs baseline: 15.0307x; 1.0158x over previous
//
#include <hip/hip_runtime.h>

#define NN 100000
#define EPS 1e-5f

// ---- workspace layout (4-byte units), ~83MB total ----
static const size_t OFF_ROWST  = 0;           // rowstart [100k]
static const size_t OFF_ROWEN  = 100000;      // rowend   [100k]
static const size_t OFF_ADJ    = 200000;      // adj [256*10496] -> 2,886,976
static const size_t OFF_AGG1   = 2886976;     // N*32 f32 -> 6,086,976
static const size_t OFF_AGG2   = 6086976;     // N*64 f32 -> 12,486,976
static const size_t OFF_PAIRS  = 2886976;     // u32 [256*10496] aliases agg (dead before agg1)
static const size_t OFF_XB     = 12486976;    // N*32 bf16 -> 14,086,976
static const size_t OFF_Z1     = 0;           // N*128 f32 [0..12.8M): dead by fc1
static const size_t OFF_H1B    = 14086976;    // N*64 bf16 -> 17,286,976
static const size_t OFF_Z2     = 14086976;    // aliases h1b -> 20,486,976
static const size_t OFF_WSPL   = 20487000;    // 57,344 ushorts -> 20,515,672
static const size_t OFF_BUKCNT = 20515712;    // 256 ints
static const size_t OFF_STATS1 = 20515968;    // 128 slots * 256 -> 20,548,736
static const size_t OFF_STATS2 = 20548736;    // 128 slots * 128 -> 20,565,120
static const size_t OFF_COEF1  = 20565120;    // 256
static const size_t OFF_COEF2  = 20565376;    // 128
static const size_t OFF_BHIST  = 20565504;    // NCH_MAX*256 ints -> 20,765,696
static const size_t ZERO_START = 20515968;    // slotted stats only
static const size_t ZERO_INTS  = 49152;

#define NSLOT 128                             // stats slots (atomic-contention spreader)

// split-weight plane offsets (ushort units within WSPL)
#define WL1_HI 0
#define WL1_LO 2048
#define WR1_HI 4096
#define WR1_LO 6144
#define WL2_HI 8192
#define WL2_LO 12288
#define WR2_HI 16384
#define WR2_LO 20480
#define F1_HI  24576
#define F1_LO  32768
#define F2_HI  40960
#define F2_LO  49152

#define NBUK 256
#define BSHIFT 9                              // 512 nodes per bucket
#define BCAP 10496                            // mean 8192 + 25 sigma
#define CHUNK 2048

typedef __attribute__((ext_vector_type(8))) short short8;
typedef __attribute__((ext_vector_type(4))) float f32x4;

#define MFMA_16x16x32(a, b, c) __builtin_amdgcn_mfma_f32_16x16x32_bf16(a, b, c, 0, 0, 0)

// f32 -> bf16 (RNE) at bit level
__device__ inline unsigned short f2bf(float f) {
  unsigned u = __builtin_bit_cast(unsigned, f);
  unsigned r = (u + 0x7fffu + ((u >> 16) & 1u)) >> 16;
  return (unsigned short)r;
}
__device__ inline float bf2f(unsigned short h) {
  unsigned u = ((unsigned)h) << 16;
  return __builtin_bit_cast(float, u);
}

// load 8 contiguous f32 (optionally BN+relu transformed), split into hi/lo bf16
template<bool BNIN>
__device__ inline void load_split(const float* __restrict__ p,
                                  const float* __restrict__ ca,
                                  const float* __restrict__ cc,
                                  short8& hi, short8& lo) {
  #pragma unroll
  for (int j = 0; j < 8; ++j) {
    float v = p[j];
    if (BNIN) v = fmaxf(v * ca[j] + cc[j], 0.f);
    unsigned short h = f2bf(v);
    hi[j] = (short)h;
    lo[j] = (short)f2bf(v - bf2f(h));
  }
}

// ---- one-shot: split all 6 weight matrices into hi/lo bf16 planes ----
struct WsplitArgs {
  const float* src[6];
  unsigned short* dhi[6];
  unsigned short* dlo[6];
  int n[6];
};
__global__ __launch_bounds__(256) void wsplit_k(WsplitArgs a) {
  int m = blockIdx.y;
  int n = a.n[m];
  for (int i = blockIdx.x * 256 + threadIdx.x; i < n; i += gridDim.x * 256) {
    float v = a.src[m][i];
    unsigned short h = f2bf(v);
    a.dhi[m][i] = h;
    a.dlo[m][i] = f2bf(v - bf2f(h));
  }
}

// ---- convert f32 plane -> bf16 plane (for cheap gathers) ----
__global__ __launch_bounds__(256) void cvt_bf_k(const float* __restrict__ in,
                                                unsigned short* __restrict__ out,
                                                int n8) {
  int t = blockIdx.x * 256 + threadIdx.x;
  if (t >= n8) return;
  const float4* p = (const float4*)(in + (size_t)t * 8);
  float4 a = p[0], b = p[1];
  ushort4 u0, u1;
  u0.x = f2bf(a.x); u0.y = f2bf(a.y); u0.z = f2bf(a.z); u0.w = f2bf(a.w);
  u1.x = f2bf(b.x); u1.y = f2bf(b.y); u1.z = f2bf(b.z); u1.w = f2bf(b.w);
  ((ushort4*)(out + (size_t)t * 8))[0] = u0;
  ((ushort4*)(out + (size_t)t * 8))[1] = u1;
}

// ---- build A: per-chunk bucket histogram (no global atomics) ----
__global__ __launch_bounds__(256) void hista_k(const int* __restrict__ ei, int E,
                                               int* __restrict__ blockhist) {
  __shared__ int h[NBUK];
  int tid = threadIdx.x;
  h[tid] = 0;
  __syncthreads();
  int lo = blockIdx.x * CHUNK, hi = min(lo + CHUNK, E);
  for (int e = lo + tid; e < hi; e += 256) {
    int t = ei[E + e];
    if ((unsigned)t < NN) atomicAdd(&h[t >> BSHIFT], 1);
  }
  __syncthreads();
  blockhist[(size_t)blockIdx.x * NBUK + tid] = h[tid];   // coalesced, non-atomic
}

// ---- build B: per-bucket exclusive scan over chunks (in place) + totals ----
__global__ __launch_bounds__(256) void scanb_k(int* __restrict__ blockhist, int nch,
                                               int* __restrict__ bukcnt) {
  __shared__ int sh[256];
  int b = blockIdx.x, t = threadIdx.x;
  int run = 0;
  for (int base = 0; base < nch; base += 256) {
    int c = base + t;
    int v = (c < nch) ? blockhist[(size_t)c * NBUK + b] : 0;
    sh[t] = v;
    __syncthreads();
    for (int o = 1; o < 256; o <<= 1) {
      int u = (t >= o) ? sh[t - o] : 0;
      __syncthreads();
      sh[t] += u;
      __syncthreads();
    }
    if (c < nch) blockhist[(size_t)c * NBUK + b] = run + sh[t] - v;
    int tot = sh[255];
    __syncthreads();
    run += tot;
  }
  if (t == 0) bukcnt[b] = run;
}

// ---- build C: scatter edges into bucket-padded packed pairs (LDS cursors only) ----
__global__ __launch_bounds__(256) void scat_k(const int* __restrict__ ei, int E,
                                              const int* __restrict__ blockhist,
                                              unsigned* __restrict__ pairs) {
  __shared__ int wb[NBUK], cur[NBUK];
  int tid = threadIdx.x;
  wb[tid] = blockhist[(size_t)blockIdx.x * NBUK + tid];
  cur[tid] = 0;
  __syncthreads();
  int lo = blockIdx.x * CHUNK, hi = min(lo + CHUNK, E);
  for (int e = lo + tid; e < hi; e += 256) {
    int s = ei[e], t = ei[E + e];
    if ((unsigned)t >= NN) continue;
    if ((unsigned)s >= NN) s = 0;            // clamp (keeps count/write in sync)
    int b = t >> BSHIFT;
    int off = atomicAdd(&cur[b], 1);
    pairs[(size_t)b * BCAP + wb[b] + off] = ((unsigned)s << 9) | (unsigned)(t & 511);
  }
}

// ---- build D: per-bucket LDS histogram + scan -> rowstart/rowend + adj fill ----
__global__ __launch_bounds__(256) void bfill2_k(const unsigned* __restrict__ pairs,
                                                const int* __restrict__ bukcnt,
                                                int* __restrict__ rowstart,
                                                int* __restrict__ rowend,
                                                int* __restrict__ adj) {
  __shared__ int d[512];
  __shared__ int part[256];
  int b = blockIdx.x;
  int t = threadIdx.x;
  int base = b * BCAP, cnt = bukcnt[b];
  d[t] = 0; d[t + 256] = 0;
  __syncthreads();
  for (int p = base + t; p < base + cnt; p += 256)
    atomicAdd(&d[pairs[p] & 511], 1);
  __syncthreads();
  int d0 = d[2 * t], d1 = d[2 * t + 1];
  part[t] = d0 + d1;
  __syncthreads();
  for (int o = 1; o < 256; o <<= 1) {
    int u = (t >= o) ? part[t - o] : 0;
    __syncthreads();
    part[t] += u;
    __syncthreads();
  }
  int e0 = (t > 0) ? part[t - 1] : 0;
  int e1 = e0 + d0;
  d[2 * t] = e0;            // becomes LDS cursor
  d[2 * t + 1] = e1;
  int n0 = (b << BSHIFT) + 2 * t;
  if (n0 < NN)     { rowstart[n0]     = base + e0; rowend[n0]     = base + e1; }
  if (n0 + 1 < NN) { rowstart[n0 + 1] = base + e1; rowend[n0 + 1] = base + e1 + d1; }
  __syncthreads();
  for (int p = base + t; p < base + cnt; p += 256) {
    unsigned pr = pairs[p];
    int pos = atomicAdd(&d[pr & 511], 1);
    adj[base + pos] = (int)(pr >> 9);
  }
}

// ---- gather-side mean aggregation, ushort4-vectorized: K/4 lanes per node ----
template<int K>
__global__ __launch_bounds__(256) void aggregate_bf(const unsigned short* __restrict__ xb,
                                                    const int* __restrict__ rowstart,
                                                    const int* __restrict__ rowend,
                                                    const int* __restrict__ adj,
                                                    float* __restrict__ agg) {
  constexpr int GL = K / 4;                   // lanes per node
  constexpr int NPB = 256 / GL;
  int lg = threadIdx.x & (GL - 1);
  int node = blockIdx.x * NPB + (threadIdx.x / GL);
  if (node >= NN) return;
  int s0 = rowstart[node], s1 = rowend[node];
  float4 a0 = {0,0,0,0}, a1 = {0,0,0,0}, a2 = {0,0,0,0}, a3 = {0,0,0,0};
  int e = s0;
  for (; e + 3 < s1; e += 4) {                // 4 independent chains
    int i0 = adj[e], i1 = adj[e+1], i2 = adj[e+2], i3 = adj[e+3];
    ushort4 u0 = *(const ushort4*)(xb + (size_t)i0 * K + lg * 4);
    ushort4 u1 = *(const ushort4*)(xb + (size_t)i1 * K + lg * 4);
    ushort4 u2 = *(const ushort4*)(xb + (size_t)i2 * K + lg * 4);
    ushort4 u3 = *(const ushort4*)(xb + (size_t)i3 * K + lg * 4);
    a0.x += bf2f(u0.x); a0.y += bf2f(u0.y); a0.z += bf2f(u0.z); a0.w += bf2f(u0.w);
    a1.x += bf2f(u1.x); a1.y += bf2f(u1.y); a1.z += bf2f(u1.z); a1.w += bf2f(u1.w);
    a2.x += bf2f(u2.x); a2.y += bf2f(u2.y); a2.z += bf2f(u2.z); a2.w += bf2f(u2.w);
    a3.x += bf2f(u3.x); a3.y += bf2f(u3.y); a3.z += bf2f(u3.z); a3.w += bf2f(u3.w);
  }
  for (; e < s1; ++e) {
    ushort4 u = *(const ushort4*)(xb + (size_t)adj[e] * K + lg * 4);
    a0.x += bf2f(u.x); a0.y += bf2f(u.y); a0.z += bf2f(u.z); a0.w += bf2f(u.w);
  }
  float inv = 1.0f / fmaxf((float)(s1 - s0), 1.0f);
  float4 r;
  r.x = (a0.x + a1.x + a2.x + a3.x) * inv;
  r.y = (a0.y + a1.y + a2.y + a3.y) * inv;
  r.z = (a0.z + a1.z + a2.z + a3.z) * inv;
  r.w = (a0.w + a1.w + a2.w + a3.w) * inv;
  *(float4*)(agg + (size_t)node * K + lg * 4) = r;
}

// ---- MFMA dense layer; weights pre-split + staged in LDS (XOR-swizzled) ----
// Optional fused column-stats into SLOTTED global stats (slot = bid & (NSLOT-1)).
template<int K, int C, bool SAGE, bool BNIN, bool RELU, bool BFOUT, bool STATS>
__global__ __launch_bounds__(256) void mfma_dense(const float* __restrict__ inA,
                                                  const float* __restrict__ inB,
                                                  const unsigned short* __restrict__ whiA,
                                                  const unsigned short* __restrict__ wloA,
                                                  const unsigned short* __restrict__ whiB,
                                                  const unsigned short* __restrict__ wloB,
                                                  const float* __restrict__ bias,
                                                  const float* __restrict__ coef,
                                                  float* __restrict__ out,
                                                  unsigned short* __restrict__ outb,
                                                  float* __restrict__ stats) {
  constexpr int KF = K / 32;
  constexpr int KC = K / 8;                   // 16B chunks per weight row
  constexpr int SWZ = (KC < 8 ? KC : 8) - 1;  // xor-swizzle mask (T2)
  __shared__ unsigned short swhiA[C * K], swloA[C * K];
  __shared__ unsigned short swhiB[SAGE ? C * K : 8], swloB[SAGE ? C * K : 8];
  __shared__ float ls[STATS ? C : 1], lq[STATS ? C : 1];

  int tid = threadIdx.x;
  // cooperative swizzled staging of weight planes
  for (int i = tid; i < C * KC; i += 256) {
    int col = i / KC, c = i % KC;
    int pos = col * KC + (c ^ (col & SWZ));
    ((short8*)swhiA)[pos] = ((const short8*)whiA)[i];
    ((short8*)swloA)[pos] = ((const short8*)wloA)[i];
    if (SAGE) {
      ((short8*)swhiB)[pos] = ((const short8*)whiB)[i];
      ((short8*)swloB)[pos] = ((const short8*)wloB)[i];
    }
  }
  if (STATS) {
    for (int i = tid; i < C; i += 256) { ls[i] = 0.f; lq[i] = 0.f; }
  }
  __syncthreads();

  int wid  = tid >> 6;
  int lane = tid & 63;
  int row0 = blockIdx.x * 64 + wid * 16;
  int r = lane & 15, g = lane >> 4;
  int arow = row0 + r; if (arow > NN - 1) arow = NN - 1;   // clamp tail reads
  int koff = g * 8;

  short8 ahi[KF], alo[KF];
  short8 a2hi[SAGE ? KF : 1], a2lo[SAGE ? KF : 1];
  #pragma unroll
  for (int kf = 0; kf < KF; ++kf) {
    const float* p = inA + (size_t)arow * K + kf * 32 + koff;
    load_split<BNIN>(p, coef + kf * 32 + koff, coef + K + kf * 32 + koff,
                     ahi[kf], alo[kf]);
  }
  if (SAGE) {
    #pragma unroll
    for (int kf = 0; kf < KF; ++kf) {
      const float* p = inB + (size_t)arow * K + kf * 32 + koff;
      load_split<false>(p, nullptr, nullptr, a2hi[kf], a2lo[kf]);
    }
  }

  #pragma unroll
  for (int cf = 0; cf < C / 16; ++cf) {
    int col = cf * 16 + r;
    float bv = bias[col];
    f32x4 acc = {bv, bv, bv, bv};
    #pragma unroll
    for (int kf = 0; kf < KF; ++kf) {
      int c = kf * 4 + g;
      int pos = col * KC + (c ^ (col & SWZ));
      short8 whi = ((const short8*)swhiA)[pos];
      short8 wlo = ((const short8*)swloA)[pos];
      acc = MFMA_16x16x32(ahi[kf], whi, acc);
      acc = MFMA_16x16x32(ahi[kf], wlo, acc);
      acc = MFMA_16x16x32(alo[kf], whi, acc);
      if (SAGE) {
        short8 vhi = ((const short8*)swhiB)[pos];
        short8 vlo = ((const short8*)swloB)[pos];
        acc = MFMA_16x16x32(a2hi[kf], vhi, acc);
        acc = MFMA_16x16x32(a2hi[kf], vlo, acc);
        acc = MFMA_16x16x32(a2lo[kf], vhi, acc);
      }
    }
    if (STATS) {
      float s = 0.f, q = 0.f;
      #pragma unroll
      for (int j = 0; j < 4; ++j) {
        if (row0 + g * 4 + j < NN) {
          float v = acc[j];
          s += v; q += v * v;
        }
      }
      s += __shfl_xor(s, 16, 64); s += __shfl_xor(s, 32, 64);
      q += __shfl_xor(q, 16, 64); q += __shfl_xor(q, 32, 64);
      if (g == 0) { atomicAdd(&ls[col], s); atomicAdd(&lq[col], q); }
    }
    #pragma unroll
    for (int j = 0; j < 4; ++j) {
      int orow = row0 + g * 4 + j;
      if (orow < NN) {
        float v = acc[j];
        if (RELU) v = fmaxf(v, 0.f);
        out[(size_t)orow * C + col] = v;
        if (BFOUT) outb[(size_t)orow * C + col] = f2bf(v);
      }
    }
  }
  if (STATS) {
    __syncthreads();
    float* sl = stats + (size_t)(blockIdx.x & (NSLOT - 1)) * 2 * C;
    for (int i = tid; i < C; i += 256) {
      atomicAdd(&sl[i], ls[i]);
      atomicAdd(&sl[C + i], lq[i]);
    }
  }
}

// ---- slotted stats -> affine coefs: y = v*a + c ----
__global__ void bncoef(const float* __restrict__ stats, const float* __restrict__ g,
                       const float* __restrict__ b, float* __restrict__ coef, int C) {
  int j = threadIdx.x;
  if (j >= C) return;
  float s = 0.f, q = 0.f;
  for (int sl = 0; sl < NSLOT; ++sl) {
    s += stats[(size_t)sl * 2 * C + j];
    q += stats[(size_t)sl * 2 * C + C + j];
  }
  float mu  = s * (1.0f / NN);
  float var = q * (1.0f / NN) - mu * mu;
  float a = g[j] * rsqrtf(var + EPS);
  coef[j] = a;
  coef[C + j] = b[j] - mu * a;
}

// ---- final: out[i] = sum_j relu(z2[i][j]*a+c) * fc3w[j] + fc3b ----
__global__ __launch_bounds__(256) void final_k(const float* __restrict__ z2,
                                               const float* __restrict__ coef,
                                               const float* __restrict__ fc3w,
                                               const float* __restrict__ fc3b,
                                               float* __restrict__ out) {
  int t = blockIdx.x * 256 + threadIdx.x;
  int i = t >> 6;
  int j = t & 63;
  if (i >= NN) return;
  float v = z2[(size_t)i * 64 + j];
  float p = fmaxf(v * coef[j] + coef[64 + j], 0.f) * fc3w[j];
  #pragma unroll
  for (int o = 32; o > 0; o >>= 1) p += __shfl_xor(p, o, 64);
  if (j == 0) out[i] = p + fc3b[0];
}

extern "C" void kernel_launch(void* const* d_in, const int* in_sizes, int n_in,
                              void* d_out, int out_size, void* d_ws, size_t ws_size,
                              hipStream_t stream) {
  const float* x     = (const float*)d_in[0];
  const int*   ei    = (const int*)d_in[1];
  const float* w_l1  = (const float*)d_in[2];
  const float* b_l1  = (const float*)d_in[3];
  const float* w_r1  = (const float*)d_in[4];
  const float* w_l2  = (const float*)d_in[5];
  const float* b_l2  = (const float*)d_in[6];
  const float* w_r2  = (const float*)d_in[7];
  const float* fc1_w = (const float*)d_in[8];
  const float* fc1_b = (const float*)d_in[9];
  const float* bn1_g = (const float*)d_in[10];
  const float* bn1_b = (const float*)d_in[11];
  const float* fc2_w = (const float*)d_in[12];
  const float* fc2_b = (const float*)d_in[13];
  const float* bn2_g = (const float*)d_in[14];
  const float* bn2_b = (const float*)d_in[15];
  const float* fc3_w = (const float*)d_in[16];
  const float* fc3_b = (const float*)d_in[17];

  const int E = in_sizes[1] / 2;

  float* ws       = (float*)d_ws;
  int*   rowstart = (int*)(ws + OFF_ROWST);
  int*   rowend   = (int*)(ws + OFF_ROWEN);
  int*   adj      = (int*)(ws + OFF_ADJ);
  float* agg1     = ws + OFF_AGG1;
  float* agg2     = ws + OFF_AGG2;
  unsigned short* xb  = (unsigned short*)(ws + OFF_XB);
  unsigned short* h1b = (unsigned short*)(ws + OFF_H1B);
  float* z1       = ws + OFF_Z1;
  float* z2       = ws + OFF_Z2;
  int*   bukcnt   = (int*)(ws + OFF_BUKCNT);
  float* stats1   = ws + OFF_STATS1;
  float* stats2   = ws + OFF_STATS2;
  float* coef1    = ws + OFF_COEF1;
  float* coef2    = ws + OFF_COEF2;
  unsigned* pairs = (unsigned*)(ws + OFF_PAIRS);
  int*   bhist    = (int*)(ws + OFF_BHIST);
  unsigned short* wspl = (unsigned short*)(ws + OFF_WSPL);

  float* outv = (float*)d_out;             // [NN]
  float* h1   = outv + NN;                 // [NN,64]
  float* h2   = h1 + (size_t)NN * 64;      // [NN,64]

  hipMemsetAsync(ws + ZERO_START, 0, ZERO_INTS * sizeof(float), stream);

  // one-shot weight splits (hi/lo bf16 planes)
  WsplitArgs wa;
  wa.src[0] = w_l1;  wa.dhi[0] = wspl + WL1_HI; wa.dlo[0] = wspl + WL1_LO; wa.n[0] = 64 * 32;
  wa.src[1] = w_r1;  wa.dhi[1] = wspl + WR1_HI; wa.dlo[1] = wspl + WR1_LO; wa.n[1] = 64 * 32;
  wa.src[2] = w_l2;  wa.dhi[2] = wspl + WL2_HI; wa.dlo[2] = wspl + WL2_LO; wa.n[2] = 64 * 64;
  wa.src[3] = w_r2;  wa.dhi[3] = wspl + WR2_HI; wa.dlo[3] = wspl + WR2_LO; wa.n[3] = 64 * 64;
  wa.src[4] = fc1_w; wa.dhi[4] = wspl + F1_HI;  wa.dlo[4] = wspl + F1_LO;  wa.n[4] = 128 * 64;
  wa.src[5] = fc2_w; wa.dhi[5] = wspl + F2_HI;  wa.dlo[5] = wspl + F2_LO;  wa.n[5] = 64 * 128;
  wsplit_k<<<dim3(8, 6), 256, 0, stream>>>(wa);

  // bf16 copy of x for cheap gathering
  cvt_bf_k<<<(NN * 32 / 8 + 255) / 256, 256, 0, stream>>>(x, xb, NN * 32 / 8);

  // CSR build — deterministic partition: hist -> scan -> scatter -> fill
  const int NCH = (E + CHUNK - 1) / CHUNK;
  hista_k<<<NCH, 256, 0, stream>>>(ei, E, bhist);
  scanb_k<<<NBUK, 256, 0, stream>>>(bhist, NCH, bukcnt);
  scat_k<<<NCH, 256, 0, stream>>>(ei, E, bhist, pairs);
  bfill2_k<<<NBUK, 256, 0, stream>>>(pairs, bukcnt, rowstart, rowend, adj);

  const int MB = (NN + 63) / 64;   // MFMA dense grid: 64 rows per block

  // layer 1 (gather bf16 x; dense emits h1 f32 + h1b bf16 for next gather)
  aggregate_bf<32><<<(NN + 31) / 32, 256, 0, stream>>>(xb, rowstart, rowend, adj, agg1);
  mfma_dense<32, 64, true, false, true, true, false><<<MB, 256, 0, stream>>>(
      agg1, x, wspl + WL1_HI, wspl + WL1_LO, wspl + WR1_HI, wspl + WR1_LO,
      b_l1, nullptr, h1, h1b, nullptr);

  // layer 2
  aggregate_bf<64><<<(NN + 15) / 16, 256, 0, stream>>>(h1b, rowstart, rowend, adj, agg2);
  mfma_dense<64, 64, true, false, true, false, false><<<MB, 256, 0, stream>>>(
      agg2, h1, wspl + WL2_HI, wspl + WL2_LO, wspl + WR2_HI, wspl + WR2_LO,
      b_l2, nullptr, h2, nullptr, nullptr);

  // fc1 -> z1 (raw, pre-BN) with fused slotted column stats
  mfma_dense<64, 128, false, false, false, false, true><<<MB, 256, 0, stream>>>(
      h2, nullptr, wspl + F1_HI, wspl + F1_LO, nullptr, nullptr,
      fc1_b, nullptr, z1, nullptr, stats1);
  bncoef<<<1, 128, 0, stream>>>(stats1, bn1_g, bn1_b, coef1, 128);

  // fc2 with fused bn1+relu on input -> z2 (raw, pre-BN) with fused stats
  mfma_dense<128, 64, false, true, false, false, true><<<MB, 256, 0, stream>>>(
      z1, nullptr, wspl + F2_HI, wspl + F2_LO, nullptr, nullptr,
      fc2_b, coef1, z2, nullptr, stats2);
  bncoef<<<1, 64, 0, stream>>>(stats2, bn2_g, bn2_b, coef2, 64);

  // bn2 + relu + fc3 fused
  final_k<<<(NN * 64 + 255) / 256, 256, 0, stream>>>(z2, coef2, fc3_w, fc3_b, outv);
}